// Round 1
// baseline (3280.849 us; speedup 1.0000x reference)
//
#include <hip/hip_runtime.h>

typedef unsigned short u16;
typedef __bf16 bf16x8_t __attribute__((ext_vector_type(8)));
typedef float f32x4_t __attribute__((ext_vector_type(4)));

__device__ __forceinline__ float bf2f(u16 u) {
    union { unsigned u; float f; } c; c.u = ((unsigned)u) << 16; return c.f;
}
__device__ __forceinline__ u16 f2bf(float f) {
    union { float f; unsigned u; } c; c.f = f;
    unsigned u = c.u;
    unsigned r = (u + 0x7FFFu + ((u >> 16) & 1u)) >> 16;
    return (u16)r;
}

__device__ __forceinline__ void block_sum2(float& s, float& sq) {
    for (int o = 32; o > 0; o >>= 1) { s += __shfl_xor(s, o); sq += __shfl_xor(sq, o); }
    __shared__ float sh[8];
    int wid = threadIdx.x >> 6;
    if ((threadIdx.x & 63) == 0) { sh[wid] = s; sh[4 + wid] = sq; }
    __syncthreads();
    s  = sh[0] + sh[1] + sh[2] + sh[3];
    sq = sh[4] + sh[5] + sh[6] + sh[7];
}

// ---- LN1 + window partition, per chunk: fp32 x -> bf16 window rows ---------
__global__ __launch_bounds__(256) void ln1_window(
    const float* __restrict__ x, const float* __restrict__ w, const float* __restrict__ b,
    u16* __restrict__ out, int row0)
{
    int lrow = blockIdx.x, tid = threadIdx.x;
    int wr = row0 + lrow;
    int wb = wr / 196, t = wr % 196;
    int gh = ((wb % 25) / 5) * 14 + t / 14;
    int gw = (wb % 5) * 14 + t % 14;
    size_t orow = (size_t)lrow * 768;
    if (gh >= 64 || gw >= 64) {
        out[orow + tid] = 0; out[orow + tid + 256] = 0; out[orow + tid + 512] = 0;
        return;
    }
    size_t base = (size_t)(((wb / 25) * 64 + gh) * 64 + gw) * 768;
    float v0 = x[base + tid], v1 = x[base + tid + 256], v2 = x[base + tid + 512];
    float s = v0 + v1 + v2, sq = v0 * v0 + v1 * v1 + v2 * v2;
    block_sum2(s, sq);
    float mean = s * (1.0f / 768.0f);
    float var  = sq * (1.0f / 768.0f) - mean * mean;
    float inv  = rsqrtf(var + 1e-5f);
    out[orow + tid]       = f2bf((v0 - mean) * inv * w[tid]       + b[tid]);
    out[orow + tid + 256] = f2bf((v1 - mean) * inv * w[tid + 256] + b[tid + 256]);
    out[orow + tid + 512] = f2bf((v2 - mean) * inv * w[tid + 512] + b[tid + 512]);
}

// ---- LN2 chunk: fp32 x1 rows (pre-offset into d_out) -> bf16 ---------------
__global__ __launch_bounds__(256) void ln2_chunk(
    const float* __restrict__ xin, const float* __restrict__ w, const float* __restrict__ b,
    u16* __restrict__ out)
{
    int row = blockIdx.x, tid = threadIdx.x;
    size_t base = (size_t)row * 768;
    float v0 = xin[base + tid], v1 = xin[base + tid + 256], v2 = xin[base + tid + 512];
    float s = v0 + v1 + v2, sq = v0 * v0 + v1 * v1 + v2 * v2;
    block_sum2(s, sq);
    float mean = s * (1.0f / 768.0f);
    float var  = sq * (1.0f / 768.0f) - mean * mean;
    float inv  = rsqrtf(var + 1e-5f);
    out[base + tid]       = f2bf((v0 - mean) * inv * w[tid]       + b[tid]);
    out[base + tid + 256] = f2bf((v1 - mean) * inv * w[tid + 256] + b[tid + 256]);
    out[base + tid + 512] = f2bf((v2 - mean) * inv * w[tid + 512] + b[tid + 512]);
}

// ------------- weight transpose + cast: fp32 in[K][N] -> bf16 out[N][K] -----
__global__ __launch_bounds__(256) void transpose_wf(
    const float* __restrict__ in, u16* __restrict__ out, int K, int N)
{
    __shared__ u16 t[32][33];
    int n0 = blockIdx.x * 32, k0 = blockIdx.y * 32;
    int tx = threadIdx.x & 31, ty = threadIdx.x >> 5;
    for (int q = 0; q < 4; q++) {
        int k = k0 + ty + q * 8, n = n0 + tx;
        t[ty + q * 8][tx] = (k < K && n < N) ? f2bf(in[(size_t)k * N + n]) : (u16)0;
    }
    __syncthreads();
    for (int q = 0; q < 4; q++) {
        int n = n0 + ty + q * 8, k = k0 + tx;
        if (n < N && k < K) out[(size_t)n * K + k] = t[tx][ty + q * 8];
    }
}

// ------- build V^T per (local window, head): vt[z][d][m], m padded to 224 ---
__global__ __launch_bounds__(256) void build_vt(
    const u16* __restrict__ qkvc, u16* __restrict__ vt)
{
    int z = blockIdx.x;
    int wb = z / 12, h = z % 12;
    __shared__ u16 t[64][226];   // +2 pad: conflict-light transpose
    int tid = threadIdx.x;
    for (int base = 0; base < 196; base += 4) {
        int m = base + (tid >> 6);
        int d = tid & 63;
        t[d][m] = qkvc[(size_t)(wb * 196 + m) * 2304 + 1536 + h * 64 + d];
    }
    for (int idx = tid; idx < 28 * 64; idx += 256) {
        int m = 196 + idx / 64, d = idx % 64;
        t[d][m] = 0;
    }
    __syncthreads();
    size_t ob = (size_t)z * 64 * 224;
    for (int idx = tid; idx < 64 * 224; idx += 256) {
        int d = idx / 224, m = idx % 224;
        vt[ob + idx] = t[d][m];
    }
}

// ---------------- softmax + scale + decomposed rel-pos bias ----------------
// grid (196, Wc*12). S: [z][196][224] bf16; writes P in place, pad keys -> 0.
__global__ __launch_bounds__(256) void softmax_rel(
    const u16* __restrict__ qkvc, u16* __restrict__ S,
    const float* __restrict__ relH, const float* __restrict__ relW)
{
    int n = blockIdx.x;
    int z = blockIdx.y;
    int wb = z / 12, h = z % 12;
    int tid = threadIdx.x;
    __shared__ float qs[64];
    __shared__ float rel[28];
    __shared__ float red[8];
    size_t qbase = (size_t)(wb * 196 + n) * 2304 + h * 64;
    if (tid < 64) qs[tid] = bf2f(qkvc[qbase + tid]);
    __syncthreads();
    if (tid < 28) {
        int kk = tid % 14;
        bool isH = tid < 14;
        int qi = isH ? (n / 14) : (n % 14);
        const float* R = (isH ? relH : relW) + (size_t)(qi - kk + 13) * 64;
        float d = 0.f;
        for (int c = 0; c < 64; c++) d += qs[c] * R[c];
        rel[tid] = d;
    }
    __syncthreads();
    size_t srow = (size_t)z * 196 * 224 + (size_t)n * 224;
    int m = tid;
    bool valid = m < 196;
    float s;
    if (valid) s = 0.125f * bf2f(S[srow + m]) + rel[m / 14] + rel[14 + m % 14];
    else       s = -1e30f;
    float mx = s;
    for (int o = 32; o > 0; o >>= 1) mx = fmaxf(mx, __shfl_xor(mx, o));
    if ((tid & 63) == 0) red[tid >> 6] = mx;
    __syncthreads();
    mx = fmaxf(fmaxf(red[0], red[1]), fmaxf(red[2], red[3]));
    __syncthreads();
    float e = valid ? expf(s - mx) : 0.f;
    float sm = e;
    for (int o = 32; o > 0; o >>= 1) sm += __shfl_xor(sm, o);
    if ((tid & 63) == 0) red[4 + (tid >> 6)] = sm;
    __syncthreads();
    sm = red[4] + red[5] + red[6] + red[7];
    float p = e / sm;
    if (tid < 224) S[srow + tid] = f2bf(valid ? p : 0.f);
}

// LDS slot swizzle: row stride is 32 u16 = 64 B = 4 x 16B slots. Unswizzled,
// a quad's 16 lanes (16 consecutive rows, same slot) hit only 2 of the 8
// 16B bank groups -> 8-way conflict (9.4M SQ_LDS_BANK_CONFLICT measured).
// XOR the slot index with (row>>1)&3: rows 0..7 then cover all 8 bank
// groups, residual 2-way aliasing is free (m136). Bijective per row; the
// same mapping is used on ds_write and ds_read so data is consistent.
__device__ __forceinline__ int swz_off(int row, int kcElem) {
    return row * 32 + (kcElem ^ (((row >> 1) & 3) << 3));
}

// ---------------- NT-mode MFMA bf16 GEMM, 128x128 tile, BK=32 ----------------
// MODE 0: qkv = lnw @ qkvT^T + bias              (bf16 out Cb)
// MODE 1: S = q k^T per (window,head), blockIdx.z (bf16 out Cb, ld 224)
// MODE 2: PV: P @ Vt^T -> attn channel block     (bf16 out Cb)
// MODE 3: proj — scatter window-row -> global; Cf[g] = x_fp32[g]+acc+bias (fp32)
// MODE 4: fc1 + bias + exact gelu                (bf16 out Cb)
// MODE 5: fc2 — Cf[idx] = xf[idx]+acc+bias       (fp32 d_out RMW)
template <int MODE>
__global__ __launch_bounds__(256, 2) void gemm_nt(
    const u16* __restrict__ Aall, const u16* __restrict__ Ball,
    const float* __restrict__ bias, const float* xf,
    u16* __restrict__ Cb, float* Cf, int M, int row0)
{
    constexpr int BK = 32;
    int N, K, lda, ldb;
    size_t aoff = 0, boff = 0, coff = 0;
    if constexpr (MODE == 0) { N = 2304; K = 768; lda = 768; ldb = 768; }
    else if constexpr (MODE == 1) {
        N = 196; K = 64; lda = 2304; ldb = 2304;
        int z = blockIdx.z;
        aoff = (size_t)(z / 12) * 196 * 2304 + (size_t)(z % 12) * 64;  // q
        boff = aoff + 768;                                             // k
        coff = (size_t)z * 196 * 224;
    } else if constexpr (MODE == 2) {
        N = 64; K = 224; lda = 224; ldb = 224;
        int z = blockIdx.z;
        aoff = (size_t)z * 196 * 224;                                  // P
        boff = (size_t)z * 64 * 224;                                   // V^T
        coff = (size_t)(z / 12) * 196 * 768 + (size_t)(z % 12) * 64;   // attn out
    } else if constexpr (MODE == 3) { N = 768; K = 768; lda = 768; ldb = 768; }
    else if constexpr (MODE == 4) { N = 3072; K = 768; lda = 768; ldb = 768; }
    else { N = 768; K = 3072; lda = 3072; ldb = 3072; }

    __shared__ __align__(16) u16 As[128 * BK];
    __shared__ __align__(16) u16 Bs[128 * BK];

    const u16* A = Aall + aoff;
    const u16* B = Ball + boff;
    int tid = threadIdx.x, wid = tid >> 6, lane = tid & 63;
    int quad = lane >> 4, l16 = lane & 15;
    int m_tile = blockIdx.y * 128, n_tile = blockIdx.x * 128;
    int wm0 = (wid >> 1) * 64, wn0 = (wid & 1) * 64;

    f32x4_t acc[4][4];
    f32x4_t z4 = {0.f, 0.f, 0.f, 0.f};
    for (int mt = 0; mt < 4; mt++)
        for (int nt = 0; nt < 4; nt++) acc[mt][nt] = z4;

    int rbase = wid * 32 + (lane >> 2);
    int kc = (lane & 3) * 8;
    const u16* aptr[2];
    const u16* bptr[2];
    int ldst[2];
    for (int i = 0; i < 2; i++) {
        int r = rbase + i * 16;
        int am = m_tile + r; if (am > M - 1) am = M - 1;
        int bn = n_tile + r; if (bn > N - 1) bn = N - 1;
        aptr[i] = A + (size_t)am * lda;
        bptr[i] = B + (size_t)bn * ldb;
        ldst[i] = swz_off(r, kc);
    }

    for (int k0 = 0; k0 < K; k0 += BK) {
        uint4 av[2], bv[2];
        for (int i = 0; i < 2; i++) {
            av[i] = *(const uint4*)(aptr[i] + k0 + kc);
            bv[i] = *(const uint4*)(bptr[i] + k0 + kc);
        }
        __syncthreads();
        for (int i = 0; i < 2; i++) {
            *(uint4*)&As[ldst[i]] = av[i];
            *(uint4*)&Bs[ldst[i]] = bv[i];
        }
        __syncthreads();
        bf16x8_t af[4], bfv[4];
        for (int t = 0; t < 4; t++) {
            int ar = wm0 + t * 16 + l16;
            int br = wn0 + t * 16 + l16;
            af[t]  = *(const bf16x8_t*)&As[swz_off(ar, quad * 8)];
            bfv[t] = *(const bf16x8_t*)&Bs[swz_off(br, quad * 8)];
        }
        for (int mt = 0; mt < 4; mt++)
            for (int nt = 0; nt < 4; nt++)
                acc[mt][nt] = __builtin_amdgcn_mfma_f32_16x16x32_bf16(
                    af[mt], bfv[nt], acc[mt][nt], 0, 0, 0);
    }

    // epilogue: C/D layout col=lane&15, row=quad*4+reg (m89/m91-verified)
    for (int mt = 0; mt < 4; mt++) {
        int rl = wm0 + mt * 16 + quad * 4;
        for (int nt = 0; nt < 4; nt++) {
            int col = n_tile + wn0 + nt * 16 + l16;
            if (col >= N) continue;
            for (int rg = 0; rg < 4; rg++) {
                int row = m_tile + rl + rg;
                if (row >= M) continue;
                float v = acc[mt][nt][rg];
                if constexpr (MODE == 0) {
                    Cb[(size_t)row * 2304 + col] = f2bf(v + bias[col]);
                } else if constexpr (MODE == 1) {
                    Cb[coff + (size_t)row * 224 + col] = f2bf(v);
                } else if constexpr (MODE == 2) {
                    Cb[coff + (size_t)row * 768 + col] = f2bf(v);
                } else if constexpr (MODE == 3) {
                    int wr = row0 + row;
                    int wb = wr / 196, t = wr % 196;
                    int gh = ((wb % 25) / 5) * 14 + t / 14;
                    int gw = (wb % 5) * 14 + t % 14;
                    if (gh < 64 && gw < 64) {
                        size_t g = (size_t)(((wb / 25) * 64 + gh) * 64 + gw) * 768 + col;
                        Cf[g] = xf[g] + v + bias[col];
                    }
                } else if constexpr (MODE == 4) {
                    float tt = v + bias[col];
                    Cb[(size_t)row * 3072 + col] =
                        f2bf(0.5f * tt * (1.0f + erff(tt * 0.70710678118f)));
                } else {
                    size_t idx = (size_t)(row0 + row) * 768 + col;
                    Cf[idx] = xf[idx] + v + bias[col];
                }
            }
        }
    }
}

extern "C" void kernel_launch(void* const* d_in, const int* in_sizes, int n_in,
                              void* d_out, int out_size, void* d_ws, size_t ws_size,
                              hipStream_t stream)
{
    (void)in_sizes; (void)n_in; (void)out_size;
    const float* x      = (const float*)d_in[0];
    const float* ln1_w  = (const float*)d_in[1];
    const float* ln1_b  = (const float*)d_in[2];
    const float* qkv_w  = (const float*)d_in[3];
    const float* qkv_b  = (const float*)d_in[4];
    const float* proj_w = (const float*)d_in[5];
    const float* proj_b = (const float*)d_in[6];
    const float* rel_h  = (const float*)d_in[7];
    const float* rel_w  = (const float*)d_in[8];
    const float* ln2_w  = (const float*)d_in[9];
    const float* ln2_b  = (const float*)d_in[10];
    const float* fc1_w  = (const float*)d_in[11];
    const float* fc1_b  = (const float*)d_in[12];
    const float* fc2_w  = (const float*)d_in[13];
    const float* fc2_b  = (const float*)d_in[14];

    // ---- ws layout: weights always at base, scratch above ----
    const size_t WT = 14155776ull;   // 13.5 MB
    char* ws = (char*)d_ws;
    u16* qkvT  = (u16*)ws;
    u16* projT = qkvT + 2304 * 768;
    u16* fc1T  = projT + 768 * 768;
    u16* fc2T  = fc1T + 3072 * 768;
    char* scratch = ws + WT;
    size_t avail = (ws_size > WT) ? (ws_size - WT) : 0;

    // per-window: lnw 301056 + qkv 903168 + S 1053696 + vt 344064 + attn 301056
    // Wc capped at 25: attention-chain working set = 25 * 2.9 MB = 72.5 MB,
    // L3-resident (Wc=100 -> 290 MB > 256 MB Infinity Cache -> HBM thrash;
    // rocprof showed 6.2 GB WRITE_SIZE on the dominant gemm dispatches).
    const size_t perW = 2903040ull;
    static const int wc_cand[7] = {25, 20, 10, 5, 4, 2, 1};
    int Wc = 1;
    for (int i = 0; i < 7; i++) {
        if ((size_t)wc_cand[i] * perW <= avail) { Wc = wc_cand[i]; break; }
    }
    // Rm capped at 8192: hbuf = 50 MB, MLP working set ~110 MB, L3-resident.
    static const int rm_cand[7] = {8192, 4096, 2048, 1024, 512, 256, 128};
    int Rm = 128;
    for (int i = 0; i < 7; i++) {
        if ((size_t)rm_cand[i] * 7680ull <= avail) { Rm = rm_cand[i]; break; }
    }

    u16* lnwc  = (u16*)scratch;
    u16* qkvc  = (u16*)(scratch + (size_t)Wc * 301056ull);
    u16* Sc    = (u16*)(scratch + (size_t)Wc * 1204224ull);
    u16* vtc   = (u16*)(scratch + (size_t)Wc * 2257920ull);
    u16* attnc = (u16*)(scratch + (size_t)Wc * 2601984ull);
    u16* hbuf  = (u16*)scratch;                               // MLP overlays
    u16* xn2c  = (u16*)(scratch + (size_t)Rm * 6144ull);
    float* dout = (float*)d_out;                              // x1 (fp32)

    transpose_wf<<<dim3(72, 24), 256, 0, stream>>>(qkv_w, qkvT, 768, 2304);
    transpose_wf<<<dim3(24, 24), 256, 0, stream>>>(proj_w, projT, 768, 768);
    transpose_wf<<<dim3(96, 24), 256, 0, stream>>>(fc1_w, fc1T, 768, 3072);
    transpose_wf<<<dim3(24, 96), 256, 0, stream>>>(fc2_w, fc2T, 3072, 768);

    int nch = 100 / Wc;
    int rows = Wc * 196;
    int gy = (rows + 127) / 128;
    for (int c = 0; c < nch; c++) {
        int r0 = c * rows;
        ln1_window<<<rows, 256, 0, stream>>>(x, ln1_w, ln1_b, lnwc, r0);
        gemm_nt<0><<<dim3(18, gy), 256, 0, stream>>>(
            lnwc, qkvT, qkv_b, nullptr, qkvc, nullptr, rows, 0);
        gemm_nt<1><<<dim3(2, 2, Wc * 12), 256, 0, stream>>>(
            qkvc, qkvc, nullptr, nullptr, Sc, nullptr, 196, 0);
        build_vt<<<Wc * 12, 256, 0, stream>>>(qkvc, vtc);
        softmax_rel<<<dim3(196, Wc * 12), 256, 0, stream>>>(qkvc, Sc, rel_h, rel_w);
        gemm_nt<2><<<dim3(1, 2, Wc * 12), 256, 0, stream>>>(
            Sc, vtc, nullptr, nullptr, attnc, nullptr, 196, 0);
        gemm_nt<3><<<dim3(6, gy), 256, 0, stream>>>(
            attnc, projT, proj_b, x, nullptr, dout, rows, r0);
    }

    int nm = 16384 / Rm;
    for (int c = 0; c < nm; c++) {
        int r0 = c * Rm;
        ln2_chunk<<<Rm, 256, 0, stream>>>(dout + (size_t)r0 * 768, ln2_w, ln2_b, xn2c);
        gemm_nt<4><<<dim3(24, Rm / 128), 256, 0, stream>>>(
            xn2c, fc1T, fc1_b, nullptr, hbuf, nullptr, Rm, 0);
        gemm_nt<5><<<dim3(6, Rm / 128), 256, 0, stream>>>(
            hbuf, fc2T, fc2_b, dout, nullptr, dout, Rm, r0);
    }
}

// Round 2
// 2145.367 us; speedup vs baseline: 1.5293x; 1.5293x over previous
//
#include <hip/hip_runtime.h>

typedef unsigned short u16;
typedef __bf16 bf16x8_t __attribute__((ext_vector_type(8)));
typedef float f32x4_t __attribute__((ext_vector_type(4)));

__device__ __forceinline__ float bf2f(u16 u) {
    union { unsigned u; float f; } c; c.u = ((unsigned)u) << 16; return c.f;
}
__device__ __forceinline__ u16 f2bf(float f) {
    union { float f; unsigned u; } c; c.f = f;
    unsigned u = c.u;
    unsigned r = (u + 0x7FFFu + ((u >> 16) & 1u)) >> 16;
    return (u16)r;
}

__device__ __forceinline__ void block_sum2(float& s, float& sq) {
    for (int o = 32; o > 0; o >>= 1) { s += __shfl_xor(s, o); sq += __shfl_xor(sq, o); }
    __shared__ float sh[8];
    int wid = threadIdx.x >> 6;
    if ((threadIdx.x & 63) == 0) { sh[wid] = s; sh[4 + wid] = sq; }
    __syncthreads();
    s  = sh[0] + sh[1] + sh[2] + sh[3];
    sq = sh[4] + sh[5] + sh[6] + sh[7];
}

// ---- LN1 + window partition: fp32 x -> bf16 window rows (wide stores) ------
__global__ __launch_bounds__(256) void ln1_window(
    const float* __restrict__ x, const float* __restrict__ w, const float* __restrict__ b,
    u16* __restrict__ out, int row0)
{
    int lrow = blockIdx.x, tid = threadIdx.x;
    int wr = row0 + lrow;
    int wb = wr / 196, t = wr % 196;
    int gh = ((wb % 25) / 5) * 14 + t / 14;
    int gw = (wb % 5) * 14 + t % 14;
    size_t orow = (size_t)lrow * 768;
    __shared__ u16 rowbuf[768];
    if (gh >= 64 || gw >= 64) {
        rowbuf[tid] = 0; rowbuf[tid + 256] = 0; rowbuf[tid + 512] = 0;
        __syncthreads();
        if (tid < 96) *(uint4*)&out[orow + (tid << 3)] = *(const uint4*)&rowbuf[tid << 3];
        return;
    }
    size_t base = (size_t)(((wb / 25) * 64 + gh) * 64 + gw) * 768;
    float v0 = x[base + tid], v1 = x[base + tid + 256], v2 = x[base + tid + 512];
    float s = v0 + v1 + v2, sq = v0 * v0 + v1 * v1 + v2 * v2;
    block_sum2(s, sq);
    float mean = s * (1.0f / 768.0f);
    float var  = sq * (1.0f / 768.0f) - mean * mean;
    float inv  = rsqrtf(var + 1e-5f);
    rowbuf[tid]       = f2bf((v0 - mean) * inv * w[tid]       + b[tid]);
    rowbuf[tid + 256] = f2bf((v1 - mean) * inv * w[tid + 256] + b[tid + 256]);
    rowbuf[tid + 512] = f2bf((v2 - mean) * inv * w[tid + 512] + b[tid + 512]);
    __syncthreads();
    if (tid < 96) *(uint4*)&out[orow + (tid << 3)] = *(const uint4*)&rowbuf[tid << 3];
}

// ---- LN2 chunk: fp32 x1 rows -> bf16 (wide stores) -------------------------
__global__ __launch_bounds__(256) void ln2_chunk(
    const float* __restrict__ xin, const float* __restrict__ w, const float* __restrict__ b,
    u16* __restrict__ out)
{
    int row = blockIdx.x, tid = threadIdx.x;
    size_t base = (size_t)row * 768;
    __shared__ u16 rowbuf[768];
    float v0 = xin[base + tid], v1 = xin[base + tid + 256], v2 = xin[base + tid + 512];
    float s = v0 + v1 + v2, sq = v0 * v0 + v1 * v1 + v2 * v2;
    block_sum2(s, sq);
    float mean = s * (1.0f / 768.0f);
    float var  = sq * (1.0f / 768.0f) - mean * mean;
    float inv  = rsqrtf(var + 1e-5f);
    rowbuf[tid]       = f2bf((v0 - mean) * inv * w[tid]       + b[tid]);
    rowbuf[tid + 256] = f2bf((v1 - mean) * inv * w[tid + 256] + b[tid + 256]);
    rowbuf[tid + 512] = f2bf((v2 - mean) * inv * w[tid + 512] + b[tid + 512]);
    __syncthreads();
    if (tid < 96) *(uint4*)&out[base + (tid << 3)] = *(const uint4*)&rowbuf[tid << 3];
}

// ------------- weight transpose + cast: fp32 in[K][N] -> bf16 out[N][K] -----
__global__ __launch_bounds__(256) void transpose_wf(
    const float* __restrict__ in, u16* __restrict__ out, int K, int N)
{
    __shared__ u16 t[32][33];
    __shared__ u16 tt[32][32];   // row = n-local, 64B rows, 16B-aligned
    int n0 = blockIdx.x * 32, k0 = blockIdx.y * 32;
    int tx = threadIdx.x & 31, ty = threadIdx.x >> 5;
    for (int q = 0; q < 4; q++) {
        int k = k0 + ty + q * 8, n = n0 + tx;
        t[ty + q * 8][tx] = (k < K && n < N) ? f2bf(in[(size_t)k * N + n]) : (u16)0;
    }
    __syncthreads();
    for (int q = 0; q < 4; q++) tt[ty + q * 8][tx] = t[tx][ty + q * 8];
    __syncthreads();
    if (threadIdx.x < 128) {
        int r = threadIdx.x >> 2, c8 = (threadIdx.x & 3) << 3;
        int n = n0 + r, k = k0 + c8;
        if (n < N && k < K)
            *(uint4*)&out[(size_t)n * K + k] = *(const uint4*)&tt[r][c8];
    }
}

// ------- build V^T per (local window, head): vt[z][d][m], m padded to 224 ---
__global__ __launch_bounds__(256) void build_vt(
    const u16* __restrict__ qkvc, u16* __restrict__ vt)
{
    int z = blockIdx.x;
    int wb = z / 12, h = z % 12;
    __shared__ u16 t[64][232];   // 464B rows: 16B-aligned for uint4 reads
    int tid = threadIdx.x;
    for (int base = 0; base < 196; base += 4) {
        int m = base + (tid >> 6);
        int d = tid & 63;
        t[d][m] = qkvc[(size_t)(wb * 196 + m) * 2304 + 1536 + h * 64 + d];
    }
    for (int idx = tid; idx < 28 * 64; idx += 256) {
        int m = 196 + idx / 64, d = idx % 64;
        t[d][m] = 0;
    }
    __syncthreads();
    size_t ob = (size_t)z * 64 * 224;
    for (int idx = tid; idx < 64 * 28; idx += 256) {
        int d = idx / 28, c8 = (idx % 28) << 3;
        *(uint4*)&vt[ob + (size_t)d * 224 + c8] = *(const uint4*)&t[d][c8];
    }
}

// ---------------- softmax + scale + decomposed rel-pos bias ----------------
// grid (196, Wc*12). S: [z][196][224] bf16; writes P in place, pad keys -> 0.
__global__ __launch_bounds__(256) void softmax_rel(
    const u16* __restrict__ qkvc, u16* __restrict__ S,
    const float* __restrict__ relH, const float* __restrict__ relW)
{
    int n = blockIdx.x;
    int z = blockIdx.y;
    int wb = z / 12, h = z % 12;
    int tid = threadIdx.x;
    __shared__ float qs[64];
    __shared__ float rel[28];
    __shared__ float red[8];
    __shared__ u16 obuf[224];
    size_t qbase = (size_t)(wb * 196 + n) * 2304 + h * 64;
    if (tid < 64) qs[tid] = bf2f(qkvc[qbase + tid]);
    __syncthreads();
    if (tid < 28) {
        int kk = tid % 14;
        bool isH = tid < 14;
        int qi = isH ? (n / 14) : (n % 14);
        const float* R = (isH ? relH : relW) + (size_t)(qi - kk + 13) * 64;
        float d = 0.f;
        for (int c = 0; c < 64; c++) d += qs[c] * R[c];
        rel[tid] = d;
    }
    __syncthreads();
    size_t srow = (size_t)z * 196 * 224 + (size_t)n * 224;
    int m = tid;
    bool valid = m < 196;
    float s;
    if (valid) s = 0.125f * bf2f(S[srow + m]) + rel[m / 14] + rel[14 + m % 14];
    else       s = -1e30f;
    float mx = s;
    for (int o = 32; o > 0; o >>= 1) mx = fmaxf(mx, __shfl_xor(mx, o));
    if ((tid & 63) == 0) red[tid >> 6] = mx;
    __syncthreads();
    mx = fmaxf(fmaxf(red[0], red[1]), fmaxf(red[2], red[3]));
    __syncthreads();
    float e = valid ? expf(s - mx) : 0.f;
    float sm = e;
    for (int o = 32; o > 0; o >>= 1) sm += __shfl_xor(sm, o);
    if ((tid & 63) == 0) red[4 + (tid >> 6)] = sm;
    __syncthreads();
    sm = red[4] + red[5] + red[6] + red[7];
    float p = e / sm;
    if (tid < 224) obuf[tid] = f2bf(valid ? p : 0.f);
    __syncthreads();
    if (tid < 28) *(uint4*)&S[srow + (tid << 3)] = *(const uint4*)&obuf[tid << 3];
}

// LDS slot swizzle for staging tiles (round-1 verified: conflicts -> 0).
__device__ __forceinline__ int swz_off(int row, int kcElem) {
    return row * 32 + (kcElem ^ (((row >> 1) & 3) << 3));
}

// ---------------- NT-mode MFMA bf16 GEMM, 128x128 tile, BK=32 ----------------
// MODE 0: qkv = lnw @ qkvT^T + bias              (bf16 out Cb)
// MODE 1: S = q k^T per (window,head), blockIdx.z (bf16 out Cb, ld 224)
// MODE 2: PV: P @ Vt^T -> attn channel block     (bf16 out Cb)
// MODE 3: proj — scatter window-row -> global; Cf[g] = x_fp32[g]+acc+bias (fp32)
// MODE 4: fc1 + bias + exact gelu                (bf16 out Cb)
// MODE 5: fc2 — Cf[idx] = xf[idx]+acc+bias       (fp32 d_out RMW)
//
// Epilogue: LDS-staged, then cooperative 16B-per-lane row-contiguous stores.
// (2B/lane scalar epilogue stores measured 126 B of fabric WRITE per element
//  — a full 128B line per bf16 store. Wide stores guarantee full-line writes.)
template <int MODE>
__global__ __launch_bounds__(256, 2) void gemm_nt(
    const u16* __restrict__ Aall, const u16* __restrict__ Ball,
    const float* __restrict__ bias, const float* xf,
    u16* __restrict__ Cb, float* Cf, int M, int row0)
{
    constexpr int BK = 32;
    int N, K, lda, ldb;
    size_t aoff = 0, boff = 0, coff = 0;
    if constexpr (MODE == 0) { N = 2304; K = 768; lda = 768; ldb = 768; }
    else if constexpr (MODE == 1) {
        N = 196; K = 64; lda = 2304; ldb = 2304;
        int z = blockIdx.z;
        aoff = (size_t)(z / 12) * 196 * 2304 + (size_t)(z % 12) * 64;  // q
        boff = aoff + 768;                                             // k
        coff = (size_t)z * 196 * 224;
    } else if constexpr (MODE == 2) {
        N = 64; K = 224; lda = 224; ldb = 224;
        int z = blockIdx.z;
        aoff = (size_t)z * 196 * 224;                                  // P
        boff = (size_t)z * 64 * 224;                                   // V^T
        coff = (size_t)(z / 12) * 196 * 768 + (size_t)(z % 12) * 64;   // attn out
    } else if constexpr (MODE == 3) { N = 768; K = 768; lda = 768; ldb = 768; }
    else if constexpr (MODE == 4) { N = 3072; K = 768; lda = 768; ldb = 768; }
    else { N = 768; K = 3072; lda = 3072; ldb = 3072; }

    __shared__ __align__(16) u16 As[128 * BK];
    __shared__ __align__(16) u16 Bs[128 * BK];
    // C staging: bf16 [128][136] (272B rows => quad rows 16 banks apart, free
    // 2-way) or fp32 [64][132] halves (528B rows, same property). 34 KB.
    __shared__ __align__(16) u16 Cs[128 * 136];

    const u16* A = Aall + aoff;
    const u16* B = Ball + boff;
    int tid = threadIdx.x, wid = tid >> 6, lane = tid & 63;
    int quad = lane >> 4, l16 = lane & 15;
    int m_tile = blockIdx.y * 128, n_tile = blockIdx.x * 128;
    int wm0 = (wid >> 1) * 64, wn0 = (wid & 1) * 64;

    f32x4_t acc[4][4];
    f32x4_t z4 = {0.f, 0.f, 0.f, 0.f};
    for (int mt = 0; mt < 4; mt++)
        for (int nt = 0; nt < 4; nt++) acc[mt][nt] = z4;

    int rbase = wid * 32 + (lane >> 2);
    int kc = (lane & 3) * 8;
    const u16* aptr[2];
    const u16* bptr[2];
    int ldst[2];
    for (int i = 0; i < 2; i++) {
        int r = rbase + i * 16;
        int am = m_tile + r; if (am > M - 1) am = M - 1;
        int bn = n_tile + r; if (bn > N - 1) bn = N - 1;
        aptr[i] = A + (size_t)am * lda;
        bptr[i] = B + (size_t)bn * ldb;
        ldst[i] = swz_off(r, kc);
    }

    for (int k0 = 0; k0 < K; k0 += BK) {
        uint4 av[2], bv[2];
        for (int i = 0; i < 2; i++) {
            av[i] = *(const uint4*)(aptr[i] + k0 + kc);
            bv[i] = *(const uint4*)(bptr[i] + k0 + kc);
        }
        __syncthreads();
        for (int i = 0; i < 2; i++) {
            *(uint4*)&As[ldst[i]] = av[i];
            *(uint4*)&Bs[ldst[i]] = bv[i];
        }
        __syncthreads();
        bf16x8_t af[4], bfv[4];
        for (int t = 0; t < 4; t++) {
            int ar = wm0 + t * 16 + l16;
            int br = wn0 + t * 16 + l16;
            af[t]  = *(const bf16x8_t*)&As[swz_off(ar, quad * 8)];
            bfv[t] = *(const bf16x8_t*)&Bs[swz_off(br, quad * 8)];
        }
        for (int mt = 0; mt < 4; mt++)
            for (int nt = 0; nt < 4; nt++)
                acc[mt][nt] = __builtin_amdgcn_mfma_f32_16x16x32_bf16(
                    af[mt], bfv[nt], acc[mt][nt], 0, 0, 0);
    }

    // ---- epilogue (C/D frag layout: col=lane&15, row=quad*4+reg) ----
    if constexpr (MODE == 0 || MODE == 1 || MODE == 2 || MODE == 4) {
        for (int mt = 0; mt < 4; mt++) {
            int rl = wm0 + mt * 16 + quad * 4;
            for (int nt = 0; nt < 4; nt++) {
                int cl = wn0 + nt * 16 + l16;
                int col = n_tile + cl;
                for (int rg = 0; rg < 4; rg++) {
                    float v = acc[mt][nt][rg];
                    u16 o;
                    if constexpr (MODE == 0) o = f2bf(v + bias[col]);
                    else if constexpr (MODE == 4) {
                        float g = v + bias[col];
                        o = f2bf(0.5f * g * (1.0f + erff(g * 0.70710678118f)));
                    } else o = f2bf(v);
                    Cs[(rl + rg) * 136 + cl] = o;
                }
            }
        }
        __syncthreads();
        int ldc = (MODE == 0) ? 2304 : (MODE == 1) ? 224 : (MODE == 2) ? 768 : 3072;
        int colmax = (MODE == 1) ? 224 : N;   // mode-1 pad cols overwritten by softmax
        for (int it = 0; it < 8; it++) {
            int chunk = tid + it * 256;
            int r = chunk >> 4, c8 = (chunk & 15) << 3;
            int grow = m_tile + r, gcol = n_tile + c8;
            if (grow >= M || gcol >= colmax) continue;
            *(uint4*)&Cb[coff + (size_t)grow * ldc + gcol] = *(const uint4*)&Cs[r * 136 + c8];
        }
    } else {
        // fp32 RMW modes (3, 5): two 64-row halves through LDS
        float* Cfs = (float*)Cs;   // [64][132]
        for (int half = 0; half < 2; half++) {
            __syncthreads();
            if ((wm0 >> 6) == half) {
                for (int mt = 0; mt < 4; mt++) {
                    int rloc = mt * 16 + quad * 4;
                    for (int nt = 0; nt < 4; nt++) {
                        int cl = wn0 + nt * 16 + l16;
                        for (int rg = 0; rg < 4; rg++)
                            Cfs[(rloc + rg) * 132 + cl] = acc[mt][nt][rg];
                    }
                }
            }
            __syncthreads();
            for (int it = 0; it < 8; it++) {
                int chunk = tid + it * 256;
                int r = chunk >> 5, c4 = (chunk & 31) << 2;
                int grow = m_tile + half * 64 + r;
                int gcol = n_tile + c4;
                if (grow >= M || gcol >= N) continue;
                f32x4_t v4 = *(const f32x4_t*)&Cfs[r * 132 + c4];
                f32x4_t b4 = *(const f32x4_t*)&bias[gcol];
                if constexpr (MODE == 5) {
                    size_t idx = (size_t)(row0 + grow) * 768 + gcol;
                    f32x4_t x4 = *(const f32x4_t*)&xf[idx];
                    f32x4_t o4;
                    for (int j = 0; j < 4; j++) o4[j] = v4[j] + x4[j] + b4[j];
                    *(f32x4_t*)&Cf[idx] = o4;
                } else {
                    int wr = row0 + grow;
                    int wb2 = wr / 196, t2 = wr % 196;
                    int gh = ((wb2 % 25) / 5) * 14 + t2 / 14;
                    int gw = (wb2 % 5) * 14 + t2 % 14;
                    if (gh < 64 && gw < 64) {
                        size_t g = (size_t)(((wb2 / 25) * 64 + gh) * 64 + gw) * 768 + gcol;
                        f32x4_t x4 = *(const f32x4_t*)&xf[g];
                        f32x4_t o4;
                        for (int j = 0; j < 4; j++) o4[j] = v4[j] + x4[j] + b4[j];
                        *(f32x4_t*)&Cf[g] = o4;
                    }
                }
            }
        }
    }
}

extern "C" void kernel_launch(void* const* d_in, const int* in_sizes, int n_in,
                              void* d_out, int out_size, void* d_ws, size_t ws_size,
                              hipStream_t stream)
{
    (void)in_sizes; (void)n_in; (void)out_size;
    const float* x      = (const float*)d_in[0];
    const float* ln1_w  = (const float*)d_in[1];
    const float* ln1_b  = (const float*)d_in[2];
    const float* qkv_w  = (const float*)d_in[3];
    const float* qkv_b  = (const float*)d_in[4];
    const float* proj_w = (const float*)d_in[5];
    const float* proj_b = (const float*)d_in[6];
    const float* rel_h  = (const float*)d_in[7];
    const float* rel_w  = (const float*)d_in[8];
    const float* ln2_w  = (const float*)d_in[9];
    const float* ln2_b  = (const float*)d_in[10];
    const float* fc1_w  = (const float*)d_in[11];
    const float* fc1_b  = (const float*)d_in[12];
    const float* fc2_w  = (const float*)d_in[13];
    const float* fc2_b  = (const float*)d_in[14];

    // ---- ws layout: weights always at base, scratch above ----
    const size_t WT = 14155776ull;   // 13.5 MB
    char* ws = (char*)d_ws;
    u16* qkvT  = (u16*)ws;
    u16* projT = qkvT + 2304 * 768;
    u16* fc1T  = projT + 768 * 768;
    u16* fc2T  = fc1T + 3072 * 768;
    char* scratch = ws + WT;
    size_t avail = (ws_size > WT) ? (ws_size - WT) : 0;

    // per-window: lnw 301056 + qkv 903168 + S 1053696 + vt 344064 + attn 301056
    const size_t perW = 2903040ull;
    static const int wc_cand[7] = {25, 20, 10, 5, 4, 2, 1};
    int Wc = 1;
    for (int i = 0; i < 7; i++) {
        if ((size_t)wc_cand[i] * perW <= avail) { Wc = wc_cand[i]; break; }
    }
    static const int rm_cand[7] = {8192, 4096, 2048, 1024, 512, 256, 128};
    int Rm = 128;
    for (int i = 0; i < 7; i++) {
        if ((size_t)rm_cand[i] * 7680ull <= avail) { Rm = rm_cand[i]; break; }
    }

    u16* lnwc  = (u16*)scratch;
    u16* qkvc  = (u16*)(scratch + (size_t)Wc * 301056ull);
    u16* Sc    = (u16*)(scratch + (size_t)Wc * 1204224ull);
    u16* vtc   = (u16*)(scratch + (size_t)Wc * 2257920ull);
    u16* attnc = (u16*)(scratch + (size_t)Wc * 2601984ull);
    u16* hbuf  = (u16*)scratch;                               // MLP overlays
    u16* xn2c  = (u16*)(scratch + (size_t)Rm * 6144ull);
    float* dout = (float*)d_out;                              // x1 (fp32)

    transpose_wf<<<dim3(72, 24), 256, 0, stream>>>(qkv_w, qkvT, 768, 2304);
    transpose_wf<<<dim3(24, 24), 256, 0, stream>>>(proj_w, projT, 768, 768);
    transpose_wf<<<dim3(96, 24), 256, 0, stream>>>(fc1_w, fc1T, 768, 3072);
    transpose_wf<<<dim3(24, 96), 256, 0, stream>>>(fc2_w, fc2T, 3072, 768);

    int nch = 100 / Wc;
    int rows = Wc * 196;
    int gy = (rows + 127) / 128;
    for (int c = 0; c < nch; c++) {
        int r0 = c * rows;
        ln1_window<<<rows, 256, 0, stream>>>(x, ln1_w, ln1_b, lnwc, r0);
        gemm_nt<0><<<dim3(18, gy), 256, 0, stream>>>(
            lnwc, qkvT, qkv_b, nullptr, qkvc, nullptr, rows, 0);
        gemm_nt<1><<<dim3(2, 2, Wc * 12), 256, 0, stream>>>(
            qkvc, qkvc, nullptr, nullptr, Sc, nullptr, 196, 0);
        build_vt<<<Wc * 12, 256, 0, stream>>>(qkvc, vtc);
        softmax_rel<<<dim3(196, Wc * 12), 256, 0, stream>>>(qkvc, Sc, rel_h, rel_w);
        gemm_nt<2><<<dim3(1, 2, Wc * 12), 256, 0, stream>>>(
            Sc, vtc, nullptr, nullptr, attnc, nullptr, 196, 0);
        gemm_nt<3><<<dim3(6, gy), 256, 0, stream>>>(
            attnc, projT, proj_b, x, nullptr, dout, rows, r0);
    }

    int nm = 16384 / Rm;
    for (int c = 0; c < nm; c++) {
        int r0 = c * Rm;
        ln2_chunk<<<Rm, 256, 0, stream>>>(dout + (size_t)r0 * 768, ln2_w, ln2_b, xn2c);
        gemm_nt<4><<<dim3(24, Rm / 128), 256, 0, stream>>>(
            xn2c, fc1T, fc1_b, nullptr, hbuf, nullptr, Rm, 0);
        gemm_nt<5><<<dim3(6, Rm / 128), 256, 0, stream>>>(
            hbuf, fc2T, fc2_b, dout, nullptr, dout, Rm, r0);
    }
}

// Round 3
// 2050.522 us; speedup vs baseline: 1.6000x; 1.0463x over previous
//
#include <hip/hip_runtime.h>

typedef unsigned short u16;
typedef __bf16 bf16x8_t __attribute__((ext_vector_type(8)));
typedef float f32x4_t __attribute__((ext_vector_type(4)));

__device__ __forceinline__ float bf2f(u16 u) {
    union { unsigned u; float f; } c; c.u = ((unsigned)u) << 16; return c.f;
}
__device__ __forceinline__ u16 f2bf(float f) {
    union { float f; unsigned u; } c; c.f = f;
    unsigned u = c.u;
    unsigned r = (u + 0x7FFFu + ((u >> 16) & 1u)) >> 16;
    return (u16)r;
}

__device__ __forceinline__ void block_sum2(float& s, float& sq) {
    for (int o = 32; o > 0; o >>= 1) { s += __shfl_xor(s, o); sq += __shfl_xor(sq, o); }
    __shared__ float sh[8];
    int wid = threadIdx.x >> 6;
    if ((threadIdx.x & 63) == 0) { sh[wid] = s; sh[4 + wid] = sq; }
    __syncthreads();
    s  = sh[0] + sh[1] + sh[2] + sh[3];
    sq = sh[4] + sh[5] + sh[6] + sh[7];
}

// ---- LN1 + window partition: fp32 x -> bf16 window rows (wide stores) ------
__global__ __launch_bounds__(256) void ln1_window(
    const float* __restrict__ x, const float* __restrict__ w, const float* __restrict__ b,
    u16* __restrict__ out, int row0)
{
    int lrow = blockIdx.x, tid = threadIdx.x;
    int wr = row0 + lrow;
    int wb = wr / 196, t = wr % 196;
    int gh = ((wb % 25) / 5) * 14 + t / 14;
    int gw = (wb % 5) * 14 + t % 14;
    size_t orow = (size_t)lrow * 768;
    __shared__ u16 rowbuf[768];
    if (gh >= 64 || gw >= 64) {
        rowbuf[tid] = 0; rowbuf[tid + 256] = 0; rowbuf[tid + 512] = 0;
        __syncthreads();
        if (tid < 96) *(uint4*)&out[orow + (tid << 3)] = *(const uint4*)&rowbuf[tid << 3];
        return;
    }
    size_t base = (size_t)(((wb / 25) * 64 + gh) * 64 + gw) * 768;
    float v0 = x[base + tid], v1 = x[base + tid + 256], v2 = x[base + tid + 512];
    float s = v0 + v1 + v2, sq = v0 * v0 + v1 * v1 + v2 * v2;
    block_sum2(s, sq);
    float mean = s * (1.0f / 768.0f);
    float var  = sq * (1.0f / 768.0f) - mean * mean;
    float inv  = rsqrtf(var + 1e-5f);
    rowbuf[tid]       = f2bf((v0 - mean) * inv * w[tid]       + b[tid]);
    rowbuf[tid + 256] = f2bf((v1 - mean) * inv * w[tid + 256] + b[tid + 256]);
    rowbuf[tid + 512] = f2bf((v2 - mean) * inv * w[tid + 512] + b[tid + 512]);
    __syncthreads();
    if (tid < 96) *(uint4*)&out[orow + (tid << 3)] = *(const uint4*)&rowbuf[tid << 3];
}

// ---- LN2 chunk: fp32 x1 rows -> bf16 (wide stores) -------------------------
__global__ __launch_bounds__(256) void ln2_chunk(
    const float* __restrict__ xin, const float* __restrict__ w, const float* __restrict__ b,
    u16* __restrict__ out)
{
    int row = blockIdx.x, tid = threadIdx.x;
    size_t base = (size_t)row * 768;
    __shared__ u16 rowbuf[768];
    float v0 = xin[base + tid], v1 = xin[base + tid + 256], v2 = xin[base + tid + 512];
    float s = v0 + v1 + v2, sq = v0 * v0 + v1 * v1 + v2 * v2;
    block_sum2(s, sq);
    float mean = s * (1.0f / 768.0f);
    float var  = sq * (1.0f / 768.0f) - mean * mean;
    float inv  = rsqrtf(var + 1e-5f);
    rowbuf[tid]       = f2bf((v0 - mean) * inv * w[tid]       + b[tid]);
    rowbuf[tid + 256] = f2bf((v1 - mean) * inv * w[tid + 256] + b[tid + 256]);
    rowbuf[tid + 512] = f2bf((v2 - mean) * inv * w[tid + 512] + b[tid + 512]);
    __syncthreads();
    if (tid < 96) *(uint4*)&out[base + (tid << 3)] = *(const uint4*)&rowbuf[tid << 3];
}

// ------------- weight transpose + cast: fp32 in[K][N] -> bf16 out[N][K] -----
__global__ __launch_bounds__(256) void transpose_wf(
    const float* __restrict__ in, u16* __restrict__ out, int K, int N)
{
    __shared__ u16 t[32][33];
    __shared__ u16 tt[32][32];   // row = n-local, 64B rows, 16B-aligned
    int n0 = blockIdx.x * 32, k0 = blockIdx.y * 32;
    int tx = threadIdx.x & 31, ty = threadIdx.x >> 5;
    for (int q = 0; q < 4; q++) {
        int k = k0 + ty + q * 8, n = n0 + tx;
        t[ty + q * 8][tx] = (k < K && n < N) ? f2bf(in[(size_t)k * N + n]) : (u16)0;
    }
    __syncthreads();
    for (int q = 0; q < 4; q++) tt[ty + q * 8][tx] = t[tx][ty + q * 8];
    __syncthreads();
    if (threadIdx.x < 128) {
        int r = threadIdx.x >> 2, c8 = (threadIdx.x & 3) << 3;
        int n = n0 + r, k = k0 + c8;
        if (n < N && k < K)
            *(uint4*)&out[(size_t)n * K + k] = *(const uint4*)&tt[r][c8];
    }
}

// ------- build V^T per (local window, head): vt[z][d][m], m padded to 224 ---
__global__ __launch_bounds__(256) void build_vt(
    const u16* __restrict__ qkvc, u16* __restrict__ vt)
{
    int z = blockIdx.x;
    int wb = z / 12, h = z % 12;
    __shared__ u16 t[64][232];   // 464B rows: 16B-aligned for uint4 reads
    int tid = threadIdx.x;
    for (int base = 0; base < 196; base += 4) {
        int m = base + (tid >> 6);
        int d = tid & 63;
        t[d][m] = qkvc[(size_t)(wb * 196 + m) * 2304 + 1536 + h * 64 + d];
    }
    for (int idx = tid; idx < 28 * 64; idx += 256) {
        int m = 196 + idx / 64, d = idx % 64;
        t[d][m] = 0;
    }
    __syncthreads();
    size_t ob = (size_t)z * 64 * 224;
    for (int idx = tid; idx < 64 * 28; idx += 256) {
        int d = idx / 28, c8 = (idx % 28) << 3;
        *(uint4*)&vt[ob + (size_t)d * 224 + c8] = *(const uint4*)&t[d][c8];
    }
}

// ---------------- softmax + scale + decomposed rel-pos bias ----------------
// grid (196, Wc*12). S: [z][196][224] bf16; writes P in place, pad keys -> 0.
__global__ __launch_bounds__(256) void softmax_rel(
    const u16* __restrict__ qkvc, u16* __restrict__ S,
    const float* __restrict__ relH, const float* __restrict__ relW)
{
    int n = blockIdx.x;
    int z = blockIdx.y;
    int wb = z / 12, h = z % 12;
    int tid = threadIdx.x;
    __shared__ float qs[64];
    __shared__ float rel[28];
    __shared__ float red[8];
    __shared__ u16 obuf[224];
    size_t qbase = (size_t)(wb * 196 + n) * 2304 + h * 64;
    if (tid < 64) qs[tid] = bf2f(qkvc[qbase + tid]);
    __syncthreads();
    if (tid < 28) {
        int kk = tid % 14;
        bool isH = tid < 14;
        int qi = isH ? (n / 14) : (n % 14);
        const float* R = (isH ? relH : relW) + (size_t)(qi - kk + 13) * 64;
        float d = 0.f;
        for (int c = 0; c < 64; c++) d += qs[c] * R[c];
        rel[tid] = d;
    }
    __syncthreads();
    size_t srow = (size_t)z * 196 * 224 + (size_t)n * 224;
    int m = tid;
    bool valid = m < 196;
    float s;
    if (valid) s = 0.125f * bf2f(S[srow + m]) + rel[m / 14] + rel[14 + m % 14];
    else       s = -1e30f;
    float mx = s;
    for (int o = 32; o > 0; o >>= 1) mx = fmaxf(mx, __shfl_xor(mx, o));
    if ((tid & 63) == 0) red[tid >> 6] = mx;
    __syncthreads();
    mx = fmaxf(fmaxf(red[0], red[1]), fmaxf(red[2], red[3]));
    __syncthreads();
    float e = valid ? expf(s - mx) : 0.f;
    float sm = e;
    for (int o = 32; o > 0; o >>= 1) sm += __shfl_xor(sm, o);
    if ((tid & 63) == 0) red[4 + (tid >> 6)] = sm;
    __syncthreads();
    sm = red[4] + red[5] + red[6] + red[7];
    float p = e / sm;
    if (tid < 224) obuf[tid] = f2bf(valid ? p : 0.f);
    __syncthreads();
    if (tid < 28) *(uint4*)&S[srow + (tid << 3)] = *(const uint4*)&obuf[tid << 3];
}

// LDS slot swizzle for staging tiles (round-1 verified: conflicts -> 0).
__device__ __forceinline__ int swz_off(int row, int kcElem) {
    return row * 32 + (kcElem ^ (((row >> 1) & 3) << 3));
}

// ---------------- NT-mode MFMA bf16 GEMM, 128x128 tile, BK=32 ----------------
// MODE 0: qkv = lnw @ qkvT^T + bias              (bf16 out Cb)
// MODE 1: S = q k^T per (window,head), blockIdx.z (bf16 out Cb, ld 224)
// MODE 2: PV: P @ Vt^T -> attn channel block     (bf16 out Cb)
// MODE 3: proj — scatter window-row -> global; Cf[g] = x_fp32[g]+acc+bias (fp32)
// MODE 4: fc1 + bias + exact gelu                (bf16 out Cb)
// MODE 5: fc2 — Cf[idx] = xf[idx]+acc+bias       (fp32 d_out RMW)
//
// LDS layout: one 17408-B arena. K-loop uses [0,16K) as As|Bs; the epilogue
// (dead As/Bs) reuses it as the C staging buffer (bf16: 64-row halves,
// fp32: 32-row quarters) for cooperative 16B-per-lane full-line stores.
// K-loop is software-pipelined: prefetch tile k+1 into regs between the
// LDS publish barrier and the MFMAs, so global latency hides under compute.
template <int MODE>
__global__ __launch_bounds__(256, 4) void gemm_nt(
    const u16* __restrict__ Aall, const u16* __restrict__ Ball,
    const float* __restrict__ bias, const float* xf,
    u16* __restrict__ Cb, float* Cf, int M, int row0)
{
    constexpr int BK = 32;
    int N, K, lda, ldb;
    size_t aoff = 0, boff = 0, coff = 0;
    if constexpr (MODE == 0) { N = 2304; K = 768; lda = 768; ldb = 768; }
    else if constexpr (MODE == 1) {
        N = 196; K = 64; lda = 2304; ldb = 2304;
        int z = blockIdx.z;
        aoff = (size_t)(z / 12) * 196 * 2304 + (size_t)(z % 12) * 64;  // q
        boff = aoff + 768;                                             // k
        coff = (size_t)z * 196 * 224;
    } else if constexpr (MODE == 2) {
        N = 64; K = 224; lda = 224; ldb = 224;
        int z = blockIdx.z;
        aoff = (size_t)z * 196 * 224;                                  // P
        boff = (size_t)z * 64 * 224;                                   // V^T
        coff = (size_t)(z / 12) * 196 * 768 + (size_t)(z % 12) * 64;   // attn out
    } else if constexpr (MODE == 3) { N = 768; K = 768; lda = 768; ldb = 768; }
    else if constexpr (MODE == 4) { N = 3072; K = 768; lda = 768; ldb = 768; }
    else { N = 768; K = 3072; lda = 3072; ldb = 3072; }

    // 17408 B arena: max(As+Bs = 16384 B, bf16 Cs half = 64*136*2 = 17408 B,
    // fp32 Cs quarter = 32*132*4 = 16896 B)
    __shared__ __align__(16) u16 smem[8704];
    u16* As = smem;           // [128*32]
    u16* Bs = smem + 4096;    // [128*32]

    const u16* A = Aall + aoff;
    const u16* B = Ball + boff;
    int tid = threadIdx.x, wid = tid >> 6, lane = tid & 63;
    int quad = lane >> 4, l16 = lane & 15;
    int m_tile = blockIdx.y * 128, n_tile = blockIdx.x * 128;
    int wm0 = (wid >> 1) * 64, wn0 = (wid & 1) * 64;

    f32x4_t acc[4][4];
    f32x4_t z4 = {0.f, 0.f, 0.f, 0.f};
    for (int mt = 0; mt < 4; mt++)
        for (int nt = 0; nt < 4; nt++) acc[mt][nt] = z4;

    int rbase = wid * 32 + (lane >> 2);
    int kc = (lane & 3) * 8;
    const u16* aptr[2];
    const u16* bptr[2];
    int ldst[2];
    for (int i = 0; i < 2; i++) {
        int r = rbase + i * 16;
        int am = m_tile + r; if (am > M - 1) am = M - 1;
        int bn = n_tile + r; if (bn > N - 1) bn = N - 1;
        aptr[i] = A + (size_t)am * lda;
        bptr[i] = B + (size_t)bn * ldb;
        ldst[i] = swz_off(r, kc);
    }

    // prologue: load tile 0 into regs
    uint4 av[2], bv[2];
    for (int i = 0; i < 2; i++) {
        av[i] = *(const uint4*)(aptr[i] + kc);
        bv[i] = *(const uint4*)(bptr[i] + kc);
    }

    for (int k0 = 0; k0 < K; k0 += BK) {
        __syncthreads();   // consumers of previous tile done
        for (int i = 0; i < 2; i++) {
            *(uint4*)&As[ldst[i]] = av[i];
            *(uint4*)&Bs[ldst[i]] = bv[i];
        }
        __syncthreads();   // tile published
        if (k0 + BK < K) {     // prefetch next tile (overlaps MFMAs below)
            for (int i = 0; i < 2; i++) {
                av[i] = *(const uint4*)(aptr[i] + k0 + BK + kc);
                bv[i] = *(const uint4*)(bptr[i] + k0 + BK + kc);
            }
        }
        bf16x8_t af[4], bfv[4];
        for (int t = 0; t < 4; t++) {
            int ar = wm0 + t * 16 + l16;
            int br = wn0 + t * 16 + l16;
            af[t]  = *(const bf16x8_t*)&As[swz_off(ar, quad * 8)];
            bfv[t] = *(const bf16x8_t*)&Bs[swz_off(br, quad * 8)];
        }
        for (int mt = 0; mt < 4; mt++)
            for (int nt = 0; nt < 4; nt++)
                acc[mt][nt] = __builtin_amdgcn_mfma_f32_16x16x32_bf16(
                    af[mt], bfv[nt], acc[mt][nt], 0, 0, 0);
    }

    // ---- epilogue (C/D frag layout: col=lane&15, row=quad*4+reg) ----
    if constexpr (MODE == 0 || MODE == 1 || MODE == 2 || MODE == 4) {
        u16* Cs = smem;   // [64][136] per half
        int ldc = (MODE == 0) ? 2304 : (MODE == 1) ? 224 : (MODE == 2) ? 768 : 3072;
        int colmax = (MODE == 1) ? 224 : N;   // mode-1 pad cols overwritten later
        for (int half = 0; half < 2; half++) {
            __syncthreads();   // As/Bs (or prev half) free
            if ((wm0 >> 6) == half) {
                for (int mt = 0; mt < 4; mt++) {
                    int rl = mt * 16 + quad * 4;
                    for (int nt = 0; nt < 4; nt++) {
                        int cl = wn0 + nt * 16 + l16;
                        int col = n_tile + cl;
                        for (int rg = 0; rg < 4; rg++) {
                            float v = acc[mt][nt][rg];
                            u16 o;
                            if constexpr (MODE == 0) o = f2bf(v + bias[col]);
                            else if constexpr (MODE == 4) {
                                float g = v + bias[col];
                                o = f2bf(0.5f * g * (1.0f + erff(g * 0.70710678118f)));
                            } else o = f2bf(v);
                            Cs[(rl + rg) * 136 + cl] = o;
                        }
                    }
                }
            }
            __syncthreads();
            for (int it = 0; it < 4; it++) {
                int chunk = tid + it * 256;
                int r = chunk >> 4, c8 = (chunk & 15) << 3;
                int grow = m_tile + half * 64 + r, gcol = n_tile + c8;
                if (grow >= M || gcol >= colmax) continue;
                *(uint4*)&Cb[coff + (size_t)grow * ldc + gcol] =
                    *(const uint4*)&Cs[r * 136 + c8];
            }
        }
    } else {
        // fp32 RMW modes (3, 5): four 32-row quarters through LDS
        float* Cfs = (float*)smem;   // [32][132]
        for (int q = 0; q < 4; q++) {
            __syncthreads();
            if ((wm0 >> 6) == (q >> 1)) {
                for (int mt2 = 0; mt2 < 2; mt2++) {
                    int mt = (q & 1) * 2 + mt2;
                    int rloc = mt2 * 16 + quad * 4;
                    for (int nt = 0; nt < 4; nt++) {
                        int cl = wn0 + nt * 16 + l16;
                        for (int rg = 0; rg < 4; rg++)
                            Cfs[(rloc + rg) * 132 + cl] = acc[mt][nt][rg];
                    }
                }
            }
            __syncthreads();
            for (int it = 0; it < 4; it++) {
                int chunk = tid + it * 256;
                int r = chunk >> 5, c4 = (chunk & 31) << 2;
                int grow = m_tile + q * 32 + r;
                int gcol = n_tile + c4;
                if (grow >= M || gcol >= N) continue;
                f32x4_t v4 = *(const f32x4_t*)&Cfs[r * 132 + c4];
                f32x4_t b4 = *(const f32x4_t*)&bias[gcol];
                if constexpr (MODE == 5) {
                    size_t idx = (size_t)(row0 + grow) * 768 + gcol;
                    f32x4_t x4 = *(const f32x4_t*)&xf[idx];
                    f32x4_t o4;
                    for (int j = 0; j < 4; j++) o4[j] = v4[j] + x4[j] + b4[j];
                    *(f32x4_t*)&Cf[idx] = o4;
                } else {
                    int wr = row0 + grow;
                    int wb2 = wr / 196, t2 = wr % 196;
                    int gh = ((wb2 % 25) / 5) * 14 + t2 / 14;
                    int gw = (wb2 % 5) * 14 + t2 % 14;
                    if (gh < 64 && gw < 64) {
                        size_t g = (size_t)(((wb2 / 25) * 64 + gh) * 64 + gw) * 768 + gcol;
                        f32x4_t x4 = *(const f32x4_t*)&xf[g];
                        f32x4_t o4;
                        for (int j = 0; j < 4; j++) o4[j] = v4[j] + x4[j] + b4[j];
                        *(f32x4_t*)&Cf[g] = o4;
                    }
                }
            }
        }
    }
}

extern "C" void kernel_launch(void* const* d_in, const int* in_sizes, int n_in,
                              void* d_out, int out_size, void* d_ws, size_t ws_size,
                              hipStream_t stream)
{
    (void)in_sizes; (void)n_in; (void)out_size;
    const float* x      = (const float*)d_in[0];
    const float* ln1_w  = (const float*)d_in[1];
    const float* ln1_b  = (const float*)d_in[2];
    const float* qkv_w  = (const float*)d_in[3];
    const float* qkv_b  = (const float*)d_in[4];
    const float* proj_w = (const float*)d_in[5];
    const float* proj_b = (const float*)d_in[6];
    const float* rel_h  = (const float*)d_in[7];
    const float* rel_w  = (const float*)d_in[8];
    const float* ln2_w  = (const float*)d_in[9];
    const float* ln2_b  = (const float*)d_in[10];
    const float* fc1_w  = (const float*)d_in[11];
    const float* fc1_b  = (const float*)d_in[12];
    const float* fc2_w  = (const float*)d_in[13];
    const float* fc2_b  = (const float*)d_in[14];

    // ---- ws layout: weights always at base, scratch above ----
    const size_t WT = 14155776ull;   // 13.5 MB
    char* ws = (char*)d_ws;
    u16* qkvT  = (u16*)ws;
    u16* projT = qkvT + 2304 * 768;
    u16* fc1T  = projT + 768 * 768;
    u16* fc2T  = fc1T + 3072 * 768;
    char* scratch = ws + WT;
    size_t avail = (ws_size > WT) ? (ws_size - WT) : 0;

    // per-window: lnw 301056 + qkv 903168 + S 1053696 + vt 344064 + attn 301056
    const size_t perW = 2903040ull;
    static const int wc_cand[7] = {25, 20, 10, 5, 4, 2, 1};
    int Wc = 1;
    for (int i = 0; i < 7; i++) {
        if ((size_t)wc_cand[i] * perW <= avail) { Wc = wc_cand[i]; break; }
    }
    // MLP: single pass if possible (fc2 grid parallelism); fall back to chunks
    static const int rm_cand[8] = {16384, 8192, 4096, 2048, 1024, 512, 256, 128};
    int Rm = 128;
    for (int i = 0; i < 8; i++) {
        if ((size_t)rm_cand[i] * 7680ull <= avail) { Rm = rm_cand[i]; break; }
    }

    u16* lnwc  = (u16*)scratch;
    u16* qkvc  = (u16*)(scratch + (size_t)Wc * 301056ull);
    u16* Sc    = (u16*)(scratch + (size_t)Wc * 1204224ull);
    u16* vtc   = (u16*)(scratch + (size_t)Wc * 2257920ull);
    u16* attnc = (u16*)(scratch + (size_t)Wc * 2601984ull);
    u16* hbuf  = (u16*)scratch;                               // MLP overlays
    u16* xn2c  = (u16*)(scratch + (size_t)Rm * 6144ull);
    float* dout = (float*)d_out;                              // x1 (fp32)

    transpose_wf<<<dim3(72, 24), 256, 0, stream>>>(qkv_w, qkvT, 768, 2304);
    transpose_wf<<<dim3(24, 24), 256, 0, stream>>>(proj_w, projT, 768, 768);
    transpose_wf<<<dim3(96, 24), 256, 0, stream>>>(fc1_w, fc1T, 768, 3072);
    transpose_wf<<<dim3(24, 96), 256, 0, stream>>>(fc2_w, fc2T, 3072, 768);

    int nch = 100 / Wc;
    int rows = Wc * 196;
    int gy = (rows + 127) / 128;
    for (int c = 0; c < nch; c++) {
        int r0 = c * rows;
        ln1_window<<<rows, 256, 0, stream>>>(x, ln1_w, ln1_b, lnwc, r0);
        gemm_nt<0><<<dim3(18, gy), 256, 0, stream>>>(
            lnwc, qkvT, qkv_b, nullptr, qkvc, nullptr, rows, 0);
        gemm_nt<1><<<dim3(2, 2, Wc * 12), 256, 0, stream>>>(
            qkvc, qkvc, nullptr, nullptr, Sc, nullptr, 196, 0);
        build_vt<<<Wc * 12, 256, 0, stream>>>(qkvc, vtc);
        softmax_rel<<<dim3(196, Wc * 12), 256, 0, stream>>>(qkvc, Sc, rel_h, rel_w);
        gemm_nt<2><<<dim3(1, 2, Wc * 12), 256, 0, stream>>>(
            Sc, vtc, nullptr, nullptr, attnc, nullptr, 196, 0);
        gemm_nt<3><<<dim3(6, gy), 256, 0, stream>>>(
            attnc, projT, proj_b, x, nullptr, dout, rows, r0);
    }

    int nm = 16384 / Rm;
    for (int c = 0; c < nm; c++) {
        int r0 = c * Rm;
        ln2_chunk<<<Rm, 256, 0, stream>>>(dout + (size_t)r0 * 768, ln2_w, ln2_b, xn2c);
        gemm_nt<4><<<dim3(24, Rm / 128), 256, 0, stream>>>(
            xn2c, fc1T, fc1_b, nullptr, hbuf, nullptr, Rm, 0);
        gemm_nt<5><<<dim3(6, Rm / 128), 256, 0, stream>>>(
            hbuf, fc2T, fc2_b, dout, nullptr, dout, Rm, r0);
    }
}

// Round 4
// 1002.300 us; speedup vs baseline: 3.2733x; 2.0458x over previous
//
#include <hip/hip_runtime.h>

typedef unsigned short u16;
typedef __bf16 bf16x8_t __attribute__((ext_vector_type(8)));
typedef float f32x4_t __attribute__((ext_vector_type(4)));

__device__ __forceinline__ float bf2f(u16 u) {
    union { unsigned u; float f; } c; c.u = ((unsigned)u) << 16; return c.f;
}
__device__ __forceinline__ u16 f2bf(float f) {
    union { float f; unsigned u; } c; c.f = f;
    unsigned u = c.u;
    unsigned r = (u + 0x7FFFu + ((u >> 16) & 1u)) >> 16;
    return (u16)r;
}

// async global->LDS, 16B per lane. LDS dest is wave-uniform base + lane*16.
__device__ __forceinline__ void gld16(const u16* g, u16* l) {
    __builtin_amdgcn_global_load_lds(
        (const __attribute__((address_space(1))) unsigned*)g,
        (__attribute__((address_space(3))) unsigned*)l, 16, 0, 0);
}

__device__ __forceinline__ void block_sum2(float& s, float& sq) {
    for (int o = 32; o > 0; o >>= 1) { s += __shfl_xor(s, o); sq += __shfl_xor(sq, o); }
    __shared__ float sh[8];
    int wid = threadIdx.x >> 6;
    if ((threadIdx.x & 63) == 0) { sh[wid] = s; sh[4 + wid] = sq; }
    __syncthreads();
    s  = sh[0] + sh[1] + sh[2] + sh[3];
    sq = sh[4] + sh[5] + sh[6] + sh[7];
}

// ---- LN1 + window partition: fp32 x -> bf16 window rows (wide stores) ------
__global__ __launch_bounds__(256) void ln1_window(
    const float* __restrict__ x, const float* __restrict__ w, const float* __restrict__ b,
    u16* __restrict__ out, int row0)
{
    int lrow = blockIdx.x, tid = threadIdx.x;
    int wr = row0 + lrow;
    int wb = wr / 196, t = wr % 196;
    int gh = ((wb % 25) / 5) * 14 + t / 14;
    int gw = (wb % 5) * 14 + t % 14;
    size_t orow = (size_t)lrow * 768;
    __shared__ u16 rowbuf[768];
    if (gh >= 64 || gw >= 64) {
        rowbuf[tid] = 0; rowbuf[tid + 256] = 0; rowbuf[tid + 512] = 0;
        __syncthreads();
        if (tid < 96) *(uint4*)&out[orow + (tid << 3)] = *(const uint4*)&rowbuf[tid << 3];
        return;
    }
    size_t base = (size_t)(((wb / 25) * 64 + gh) * 64 + gw) * 768;
    float v0 = x[base + tid], v1 = x[base + tid + 256], v2 = x[base + tid + 512];
    float s = v0 + v1 + v2, sq = v0 * v0 + v1 * v1 + v2 * v2;
    block_sum2(s, sq);
    float mean = s * (1.0f / 768.0f);
    float var  = sq * (1.0f / 768.0f) - mean * mean;
    float inv  = rsqrtf(var + 1e-5f);
    rowbuf[tid]       = f2bf((v0 - mean) * inv * w[tid]       + b[tid]);
    rowbuf[tid + 256] = f2bf((v1 - mean) * inv * w[tid + 256] + b[tid + 256]);
    rowbuf[tid + 512] = f2bf((v2 - mean) * inv * w[tid + 512] + b[tid + 512]);
    __syncthreads();
    if (tid < 96) *(uint4*)&out[orow + (tid << 3)] = *(const uint4*)&rowbuf[tid << 3];
}

// ---- LN2 chunk: fp32 x1 rows -> bf16 (wide stores) -------------------------
__global__ __launch_bounds__(256) void ln2_chunk(
    const float* __restrict__ xin, const float* __restrict__ w, const float* __restrict__ b,
    u16* __restrict__ out)
{
    int row = blockIdx.x, tid = threadIdx.x;
    size_t base = (size_t)row * 768;
    __shared__ u16 rowbuf[768];
    float v0 = xin[base + tid], v1 = xin[base + tid + 256], v2 = xin[base + tid + 512];
    float s = v0 + v1 + v2, sq = v0 * v0 + v1 * v1 + v2 * v2;
    block_sum2(s, sq);
    float mean = s * (1.0f / 768.0f);
    float var  = sq * (1.0f / 768.0f) - mean * mean;
    float inv  = rsqrtf(var + 1e-5f);
    rowbuf[tid]       = f2bf((v0 - mean) * inv * w[tid]       + b[tid]);
    rowbuf[tid + 256] = f2bf((v1 - mean) * inv * w[tid + 256] + b[tid + 256]);
    rowbuf[tid + 512] = f2bf((v2 - mean) * inv * w[tid + 512] + b[tid + 512]);
    __syncthreads();
    if (tid < 96) *(uint4*)&out[base + (tid << 3)] = *(const uint4*)&rowbuf[tid << 3];
}

// ------------- weight transpose + cast: fp32 in[K][N] -> bf16 out[N][K] -----
__global__ __launch_bounds__(256) void transpose_wf(
    const float* __restrict__ in, u16* __restrict__ out, int K, int N)
{
    __shared__ u16 t[32][33];
    __shared__ u16 tt[32][32];   // row = n-local, 64B rows, 16B-aligned
    int n0 = blockIdx.x * 32, k0 = blockIdx.y * 32;
    int tx = threadIdx.x & 31, ty = threadIdx.x >> 5;
    for (int q = 0; q < 4; q++) {
        int k = k0 + ty + q * 8, n = n0 + tx;
        t[ty + q * 8][tx] = (k < K && n < N) ? f2bf(in[(size_t)k * N + n]) : (u16)0;
    }
    __syncthreads();
    for (int q = 0; q < 4; q++) tt[ty + q * 8][tx] = t[tx][ty + q * 8];
    __syncthreads();
    if (threadIdx.x < 128) {
        int r = threadIdx.x >> 2, c8 = (threadIdx.x & 3) << 3;
        int n = n0 + r, k = k0 + c8;
        if (n < N && k < K)
            *(uint4*)&out[(size_t)n * K + k] = *(const uint4*)&tt[r][c8];
    }
}

// ------- build V^T per (local window, head): vt[z][d][m], m padded to 224 ---
__global__ __launch_bounds__(256) void build_vt(
    const u16* __restrict__ qkvc, u16* __restrict__ vt)
{
    int z = blockIdx.x;
    int wb = z / 12, h = z % 12;
    __shared__ u16 t[64][232];   // 464B rows: 16B-aligned for uint4 reads
    int tid = threadIdx.x;
    for (int base = 0; base < 196; base += 4) {
        int m = base + (tid >> 6);
        int d = tid & 63;
        t[d][m] = qkvc[(size_t)(wb * 196 + m) * 2304 + 1536 + h * 64 + d];
    }
    for (int idx = tid; idx < 28 * 64; idx += 256) {
        int m = 196 + idx / 64, d = idx % 64;
        t[d][m] = 0;
    }
    __syncthreads();
    size_t ob = (size_t)z * 64 * 224;
    for (int idx = tid; idx < 64 * 28; idx += 256) {
        int d = idx / 28, c8 = (idx % 28) << 3;
        *(uint4*)&vt[ob + (size_t)d * 224 + c8] = *(const uint4*)&t[d][c8];
    }
}

// ---------------- softmax + scale + decomposed rel-pos bias ----------------
// grid (196, Wc*12). S: [z][196][224] bf16; writes P in place, pad keys -> 0.
__global__ __launch_bounds__(256) void softmax_rel(
    const u16* __restrict__ qkvc, u16* __restrict__ S,
    const float* __restrict__ relH, const float* __restrict__ relW)
{
    int n = blockIdx.x;
    int z = blockIdx.y;
    int wb = z / 12, h = z % 12;
    int tid = threadIdx.x;
    __shared__ float qs[64];
    __shared__ float rel[28];
    __shared__ float red[8];
    __shared__ u16 obuf[224];
    size_t qbase = (size_t)(wb * 196 + n) * 2304 + h * 64;
    if (tid < 64) qs[tid] = bf2f(qkvc[qbase + tid]);
    __syncthreads();
    if (tid < 28) {
        int kk = tid % 14;
        bool isH = tid < 14;
        int qi = isH ? (n / 14) : (n % 14);
        const float* R = (isH ? relH : relW) + (size_t)(qi - kk + 13) * 64;
        float d = 0.f;
        for (int c = 0; c < 64; c++) d += qs[c] * R[c];
        rel[tid] = d;
    }
    __syncthreads();
    size_t srow = (size_t)z * 196 * 224 + (size_t)n * 224;
    int m = tid;
    bool valid = m < 196;
    float s;
    if (valid) s = 0.125f * bf2f(S[srow + m]) + rel[m / 14] + rel[14 + m % 14];
    else       s = -1e30f;
    float mx = s;
    for (int o = 32; o > 0; o >>= 1) mx = fmaxf(mx, __shfl_xor(mx, o));
    if ((tid & 63) == 0) red[tid >> 6] = mx;
    __syncthreads();
    mx = fmaxf(fmaxf(red[0], red[1]), fmaxf(red[2], red[3]));
    __syncthreads();
    float e = valid ? expf(s - mx) : 0.f;
    float sm = e;
    for (int o = 32; o > 0; o >>= 1) sm += __shfl_xor(sm, o);
    if ((tid & 63) == 0) red[4 + (tid >> 6)] = sm;
    __syncthreads();
    sm = red[4] + red[5] + red[6] + red[7];
    float p = e / sm;
    if (tid < 224) obuf[tid] = f2bf(valid ? p : 0.f);
    __syncthreads();
    if (tid < 28) *(uint4*)&S[srow + (tid << 3)] = *(const uint4*)&obuf[tid << 3];
}

// LDS slot swizzle on the READ side. gload_lds writes LDS linearly; the
// matching permutation is applied to the GLOBAL source column slot
// (slot ^ (row>>1)&3), so LDS[row][s] holds global slot s^xr and the
// reader fetches global slot q at LDS[row][q^xr] == swz_off(row, q*8).
// Round-1 verified: SQ_LDS_BANK_CONFLICT -> 0 with this read pattern.
__device__ __forceinline__ int swz_off(int row, int kcElem) {
    return row * 32 + (kcElem ^ (((row >> 1) & 3) << 3));
}

// ---------------- NT-mode MFMA bf16 GEMM, 128x128 tile, BK=32 ----------------
// m97 structure: per K-step {4x global_load_lds dwordx4 -> barrier (drains
// vmcnt) -> ds_read frags + 16 MFMA -> barrier}. No VGPR staging round-trip;
// wave-level TLP (4 blocks/CU) hides the drain.
// MODE 0: qkv = lnw @ qkvT^T + bias              (bf16 out Cb)
// MODE 1: S = q k^T per (window,head), blockIdx.z (bf16 out Cb, ld 224)
// MODE 2: PV: P @ Vt^T -> attn channel block     (bf16 out Cb)
// MODE 3: proj — scatter window-row -> global; Cf[g] = x_fp32[g]+acc+bias (fp32)
// MODE 4: fc1 + bias + exact gelu                (bf16 out Cb)
// MODE 5: fc2 — Cf[idx] = xf[idx]+acc+bias       (fp32 d_out RMW)
template <int MODE>
__global__ __launch_bounds__(256, 4) void gemm_nt(
    const u16* __restrict__ Aall, const u16* __restrict__ Ball,
    const float* __restrict__ bias, const float* xf,
    u16* __restrict__ Cb, float* Cf, int M, int row0)
{
    constexpr int BK = 32;
    int N, K, lda, ldb;
    size_t aoff = 0, boff = 0, coff = 0;
    if constexpr (MODE == 0) { N = 2304; K = 768; lda = 768; ldb = 768; }
    else if constexpr (MODE == 1) {
        N = 196; K = 64; lda = 2304; ldb = 2304;
        int z = blockIdx.z;
        aoff = (size_t)(z / 12) * 196 * 2304 + (size_t)(z % 12) * 64;  // q
        boff = aoff + 768;                                             // k
        coff = (size_t)z * 196 * 224;
    } else if constexpr (MODE == 2) {
        N = 64; K = 224; lda = 224; ldb = 224;
        int z = blockIdx.z;
        aoff = (size_t)z * 196 * 224;                                  // P
        boff = (size_t)z * 64 * 224;                                   // V^T
        coff = (size_t)(z / 12) * 196 * 768 + (size_t)(z % 12) * 64;   // attn out
    } else if constexpr (MODE == 3) { N = 768; K = 768; lda = 768; ldb = 768; }
    else if constexpr (MODE == 4) { N = 3072; K = 768; lda = 768; ldb = 768; }
    else { N = 768; K = 3072; lda = 3072; ldb = 3072; }

    // 17408 B arena: K-loop As|Bs (16 KB); epilogue reuses as C staging.
    __shared__ __align__(16) u16 smem[8704];
    u16* As = smem;           // [128*32] linear
    u16* Bs = smem + 4096;    // [128*32] linear

    int tid = threadIdx.x, wid = tid >> 6, lane = tid & 63;
    int quad = lane >> 4, l16 = lane & 15;

    // XCD-aware bijective block swizzle (m204) for single-z modes: each XCD
    // gets a contiguous chunk of tile-space -> A/B panel reuse in its L2.
    int bx = blockIdx.x, by = blockIdx.y;
    if constexpr (MODE != 1 && MODE != 2) {
        int gX = gridDim.x;
        int nwg = gX * gridDim.y;
        int orig = by * gX + bx;
        int q = nwg >> 3, r = nwg & 7;
        int xcd = orig & 7, idx = orig >> 3;
        int wg = (xcd < r ? xcd * (q + 1) : r * (q + 1) + (xcd - r) * q) + idx;
        bx = wg % gX; by = wg / gX;
    }
    int m_tile = by * 128, n_tile = bx * 128;
    int wm0 = (wid >> 1) * 64, wn0 = (wid & 1) * 64;

    const u16* A = Aall + aoff;
    const u16* B = Ball + boff;

    // staging: wave wid owns rows [wid*32, wid*32+32) of As and Bs.
    // 2 issues per buffer; issue j: lane i -> lds row r0+ (i>>2), slot i&3.
    // global column slot pre-swizzled: (i&3) ^ ((row>>1)&3).
    const u16* gA[2]; const u16* gB[2];
    u16 *lA[2], *lB[2];
    {
        int s = lane & 3, rofs = lane >> 2;
        for (int j = 0; j < 2; j++) {
            int r0 = wid * 32 + j * 16;
            int rr = r0 + rofs;
            int xr = (rr >> 1) & 3;
            int colo = ((s ^ xr) << 3);
            int am = m_tile + rr; if (am > M - 1) am = M - 1;
            int bn = n_tile + rr; if (bn > N - 1) bn = N - 1;
            gA[j] = A + (size_t)am * lda + colo;
            gB[j] = B + (size_t)bn * ldb + colo;
            lA[j] = &As[r0 * 32];
            lB[j] = &Bs[r0 * 32];
        }
    }

    f32x4_t acc[4][4];
    f32x4_t z4 = {0.f, 0.f, 0.f, 0.f};
    for (int mt = 0; mt < 4; mt++)
        for (int nt = 0; nt < 4; nt++) acc[mt][nt] = z4;

    for (int k0 = 0; k0 < K; k0 += BK) {
        gld16(gA[0] + k0, lA[0]);
        gld16(gA[1] + k0, lA[1]);
        gld16(gB[0] + k0, lB[0]);
        gld16(gB[1] + k0, lB[1]);
        __syncthreads();   // drains vmcnt -> tile visible
        bf16x8_t af[4], bfv[4];
        for (int t = 0; t < 4; t++) {
            int ar = wm0 + t * 16 + l16;
            int br = wn0 + t * 16 + l16;
            af[t]  = *(const bf16x8_t*)&As[swz_off(ar, quad * 8)];
            bfv[t] = *(const bf16x8_t*)&Bs[swz_off(br, quad * 8)];
        }
        for (int mt = 0; mt < 4; mt++)
            for (int nt = 0; nt < 4; nt++)
                acc[mt][nt] = __builtin_amdgcn_mfma_f32_16x16x32_bf16(
                    af[mt], bfv[nt], acc[mt][nt], 0, 0, 0);
        __syncthreads();   // all reads done before next overwrite
    }

    // ---- epilogue (C/D frag layout: col=lane&15, row=quad*4+reg) ----
    if constexpr (MODE == 0 || MODE == 1 || MODE == 2 || MODE == 4) {
        u16* Cs = smem;   // [64][136] per half
        int ldc = (MODE == 0) ? 2304 : (MODE == 1) ? 224 : (MODE == 2) ? 768 : 3072;
        int colmax = (MODE == 1) ? 224 : N;   // mode-1 pad cols overwritten later
        for (int half = 0; half < 2; half++) {
            __syncthreads();   // As/Bs (or prev half) free
            if ((wm0 >> 6) == half) {
                for (int mt = 0; mt < 4; mt++) {
                    int rl = mt * 16 + quad * 4;
                    for (int nt = 0; nt < 4; nt++) {
                        int cl = wn0 + nt * 16 + l16;
                        int col = n_tile + cl;
                        for (int rg = 0; rg < 4; rg++) {
                            float v = acc[mt][nt][rg];
                            u16 o;
                            if constexpr (MODE == 0) o = f2bf(v + bias[col]);
                            else if constexpr (MODE == 4) {
                                float g = v + bias[col];
                                o = f2bf(0.5f * g * (1.0f + erff(g * 0.70710678118f)));
                            } else o = f2bf(v);
                            Cs[(rl + rg) * 136 + cl] = o;
                        }
                    }
                }
            }
            __syncthreads();
            for (int it = 0; it < 4; it++) {
                int chunk = tid + it * 256;
                int r = chunk >> 4, c8 = (chunk & 15) << 3;
                int grow = m_tile + half * 64 + r, gcol = n_tile + c8;
                if (grow >= M || gcol >= colmax) continue;
                *(uint4*)&Cb[coff + (size_t)grow * ldc + gcol] =
                    *(const uint4*)&Cs[r * 136 + c8];
            }
        }
    } else {
        // fp32 RMW modes (3, 5): four 32-row quarters through LDS
        float* Cfs = (float*)smem;   // [32][132]
        for (int q = 0; q < 4; q++) {
            __syncthreads();
            if ((wm0 >> 6) == (q >> 1)) {
                for (int mt2 = 0; mt2 < 2; mt2++) {
                    int mt = (q & 1) * 2 + mt2;
                    int rloc = mt2 * 16 + quad * 4;
                    for (int nt = 0; nt < 4; nt++) {
                        int cl = wn0 + nt * 16 + l16;
                        for (int rg = 0; rg < 4; rg++)
                            Cfs[(rloc + rg) * 132 + cl] = acc[mt][nt][rg];
                    }
                }
            }
            __syncthreads();
            for (int it = 0; it < 4; it++) {
                int chunk = tid + it * 256;
                int r = chunk >> 5, c4 = (chunk & 31) << 2;
                int grow = m_tile + q * 32 + r;
                int gcol = n_tile + c4;
                if (grow >= M || gcol >= N) continue;
                f32x4_t v4 = *(const f32x4_t*)&Cfs[r * 132 + c4];
                f32x4_t b4 = *(const f32x4_t*)&bias[gcol];
                if constexpr (MODE == 5) {
                    size_t idx = (size_t)(row0 + grow) * 768 + gcol;
                    f32x4_t x4 = *(const f32x4_t*)&xf[idx];
                    f32x4_t o4;
                    for (int j = 0; j < 4; j++) o4[j] = v4[j] + x4[j] + b4[j];
                    *(f32x4_t*)&Cf[idx] = o4;
                } else {
                    int wr = row0 + grow;
                    int wb2 = wr / 196, t2 = wr % 196;
                    int gh = ((wb2 % 25) / 5) * 14 + t2 / 14;
                    int gw = (wb2 % 5) * 14 + t2 % 14;
                    if (gh < 64 && gw < 64) {
                        size_t g = (size_t)(((wb2 / 25) * 64 + gh) * 64 + gw) * 768 + gcol;
                        f32x4_t x4 = *(const f32x4_t*)&xf[g];
                        f32x4_t o4;
                        for (int j = 0; j < 4; j++) o4[j] = v4[j] + x4[j] + b4[j];
                        *(f32x4_t*)&Cf[g] = o4;
                    }
                }
            }
        }
    }
}

extern "C" void kernel_launch(void* const* d_in, const int* in_sizes, int n_in,
                              void* d_out, int out_size, void* d_ws, size_t ws_size,
                              hipStream_t stream)
{
    (void)in_sizes; (void)n_in; (void)out_size;
    const float* x      = (const float*)d_in[0];
    const float* ln1_w  = (const float*)d_in[1];
    const float* ln1_b  = (const float*)d_in[2];
    const float* qkv_w  = (const float*)d_in[3];
    const float* qkv_b  = (const float*)d_in[4];
    const float* proj_w = (const float*)d_in[5];
    const float* proj_b = (const float*)d_in[6];
    const float* rel_h  = (const float*)d_in[7];
    const float* rel_w  = (const float*)d_in[8];
    const float* ln2_w  = (const float*)d_in[9];
    const float* ln2_b  = (const float*)d_in[10];
    const float* fc1_w  = (const float*)d_in[11];
    const float* fc1_b  = (const float*)d_in[12];
    const float* fc2_w  = (const float*)d_in[13];
    const float* fc2_b  = (const float*)d_in[14];

    // ---- ws layout: weights always at base, scratch above ----
    const size_t WT = 14155776ull;   // 13.5 MB
    char* ws = (char*)d_ws;
    u16* qkvT  = (u16*)ws;
    u16* projT = qkvT + 2304 * 768;
    u16* fc1T  = projT + 768 * 768;
    u16* fc2T  = fc1T + 3072 * 768;
    char* scratch = ws + WT;
    size_t avail = (ws_size > WT) ? (ws_size - WT) : 0;

    // per-window: lnw 301056 + qkv 903168 + S 1053696 + vt 344064 + attn 301056
    // Wc=100 (single pass) preferred: max grid parallelism, fewest launches.
    // L3-residency chunking was tested (rounds 1-3) and is NOT the lever.
    const size_t perW = 2903040ull;
    static const int wc_cand[8] = {100, 50, 25, 20, 10, 5, 2, 1};
    int Wc = 1;
    for (int i = 0; i < 8; i++) {
        if ((size_t)wc_cand[i] * perW <= avail) { Wc = wc_cand[i]; break; }
    }
    static const int rm_cand[8] = {16384, 8192, 4096, 2048, 1024, 512, 256, 128};
    int Rm = 128;
    for (int i = 0; i < 8; i++) {
        if ((size_t)rm_cand[i] * 7680ull <= avail) { Rm = rm_cand[i]; break; }
    }

    u16* lnwc  = (u16*)scratch;
    u16* qkvc  = (u16*)(scratch + (size_t)Wc * 301056ull);
    u16* Sc    = (u16*)(scratch + (size_t)Wc * 1204224ull);
    u16* vtc   = (u16*)(scratch + (size_t)Wc * 2257920ull);
    u16* attnc = (u16*)(scratch + (size_t)Wc * 2601984ull);
    u16* hbuf  = (u16*)scratch;                               // MLP overlays
    u16* xn2c  = (u16*)(scratch + (size_t)Rm * 6144ull);
    float* dout = (float*)d_out;                              // x1 (fp32)

    transpose_wf<<<dim3(72, 24), 256, 0, stream>>>(qkv_w, qkvT, 768, 2304);
    transpose_wf<<<dim3(24, 24), 256, 0, stream>>>(proj_w, projT, 768, 768);
    transpose_wf<<<dim3(96, 24), 256, 0, stream>>>(fc1_w, fc1T, 768, 3072);
    transpose_wf<<<dim3(24, 96), 256, 0, stream>>>(fc2_w, fc2T, 3072, 768);

    int nch = 100 / Wc;
    int rows = Wc * 196;
    int gy = (rows + 127) / 128;
    for (int c = 0; c < nch; c++) {
        int r0 = c * rows;
        ln1_window<<<rows, 256, 0, stream>>>(x, ln1_w, ln1_b, lnwc, r0);
        gemm_nt<0><<<dim3(18, gy), 256, 0, stream>>>(
            lnwc, qkvT, qkv_b, nullptr, qkvc, nullptr, rows, 0);
        gemm_nt<1><<<dim3(2, 2, Wc * 12), 256, 0, stream>>>(
            qkvc, qkvc, nullptr, nullptr, Sc, nullptr, 196, 0);
        build_vt<<<Wc * 12, 256, 0, stream>>>(qkvc, vtc);
        softmax_rel<<<dim3(196, Wc * 12), 256, 0, stream>>>(qkvc, Sc, rel_h, rel_w);
        gemm_nt<2><<<dim3(1, 2, Wc * 12), 256, 0, stream>>>(
            Sc, vtc, nullptr, nullptr, attnc, nullptr, 196, 0);
        gemm_nt<3><<<dim3(6, gy), 256, 0, stream>>>(
            attnc, projT, proj_b, x, nullptr, dout, rows, r0);
    }

    int nm = 16384 / Rm;
    for (int c = 0; c < nm; c++) {
        int r0 = c * Rm;
        ln2_chunk<<<Rm, 256, 0, stream>>>(dout + (size_t)r0 * 768, ln2_w, ln2_b, xn2c);
        gemm_nt<4><<<dim3(24, Rm / 128), 256, 0, stream>>>(
            xn2c, fc1T, fc1_b, nullptr, hbuf, nullptr, Rm, 0);
        gemm_nt<5><<<dim3(6, Rm / 128), 256, 0, stream>>>(
            hbuf, fc2T, fc2_b, dout, nullptr, dout, Rm, r0);
    }
}

// Round 5
// 758.945 us; speedup vs baseline: 4.3229x; 1.3206x over previous
//
#include <hip/hip_runtime.h>

typedef unsigned short u16;
typedef __bf16 bf16x8_t __attribute__((ext_vector_type(8)));
typedef float f32x4_t __attribute__((ext_vector_type(4)));

__device__ __forceinline__ float bf2f(u16 u) {
    union { unsigned u; float f; } c; c.u = ((unsigned)u) << 16; return c.f;
}
__device__ __forceinline__ u16 f2bf(float f) {
    union { float f; unsigned u; } c; c.f = f;
    unsigned u = c.u;
    unsigned r = (u + 0x7FFFu + ((u >> 16) & 1u)) >> 16;
    return (u16)r;
}

// async global->LDS, 16B per lane. LDS dest is wave-uniform base + lane*16.
__device__ __forceinline__ void gld16(const u16* g, u16* l) {
    __builtin_amdgcn_global_load_lds(
        (const __attribute__((address_space(1))) unsigned*)g,
        (__attribute__((address_space(3))) unsigned*)l, 16, 0, 0);
}

__device__ __forceinline__ void block_sum2(float& s, float& sq) {
    for (int o = 32; o > 0; o >>= 1) { s += __shfl_xor(s, o); sq += __shfl_xor(sq, o); }
    __shared__ float sh[8];
    int wid = threadIdx.x >> 6;
    if ((threadIdx.x & 63) == 0) { sh[wid] = s; sh[4 + wid] = sq; }
    __syncthreads();
    s  = sh[0] + sh[1] + sh[2] + sh[3];
    sq = sh[4] + sh[5] + sh[6] + sh[7];
}

// ---- LN1 + window partition: fp32 x -> bf16 window rows (wide stores) ------
__global__ __launch_bounds__(256) void ln1_window(
    const float* __restrict__ x, const float* __restrict__ w, const float* __restrict__ b,
    u16* __restrict__ out, int row0)
{
    int lrow = blockIdx.x, tid = threadIdx.x;
    int wr = row0 + lrow;
    int wb = wr / 196, t = wr % 196;
    int gh = ((wb % 25) / 5) * 14 + t / 14;
    int gw = (wb % 5) * 14 + t % 14;
    size_t orow = (size_t)lrow * 768;
    __shared__ u16 rowbuf[768];
    if (gh >= 64 || gw >= 64) {
        rowbuf[tid] = 0; rowbuf[tid + 256] = 0; rowbuf[tid + 512] = 0;
        __syncthreads();
        if (tid < 96) *(uint4*)&out[orow + (tid << 3)] = *(const uint4*)&rowbuf[tid << 3];
        return;
    }
    size_t base = (size_t)(((wb / 25) * 64 + gh) * 64 + gw) * 768;
    float v0 = x[base + tid], v1 = x[base + tid + 256], v2 = x[base + tid + 512];
    float s = v0 + v1 + v2, sq = v0 * v0 + v1 * v1 + v2 * v2;
    block_sum2(s, sq);
    float mean = s * (1.0f / 768.0f);
    float var  = sq * (1.0f / 768.0f) - mean * mean;
    float inv  = rsqrtf(var + 1e-5f);
    rowbuf[tid]       = f2bf((v0 - mean) * inv * w[tid]       + b[tid]);
    rowbuf[tid + 256] = f2bf((v1 - mean) * inv * w[tid + 256] + b[tid + 256]);
    rowbuf[tid + 512] = f2bf((v2 - mean) * inv * w[tid + 512] + b[tid + 512]);
    __syncthreads();
    if (tid < 96) *(uint4*)&out[orow + (tid << 3)] = *(const uint4*)&rowbuf[tid << 3];
}

// ---- LN2 chunk: fp32 x1 rows -> bf16 (wide stores) -------------------------
__global__ __launch_bounds__(256) void ln2_chunk(
    const float* __restrict__ xin, const float* __restrict__ w, const float* __restrict__ b,
    u16* __restrict__ out)
{
    int row = blockIdx.x, tid = threadIdx.x;
    size_t base = (size_t)row * 768;
    __shared__ u16 rowbuf[768];
    float v0 = xin[base + tid], v1 = xin[base + tid + 256], v2 = xin[base + tid + 512];
    float s = v0 + v1 + v2, sq = v0 * v0 + v1 * v1 + v2 * v2;
    block_sum2(s, sq);
    float mean = s * (1.0f / 768.0f);
    float var  = sq * (1.0f / 768.0f) - mean * mean;
    float inv  = rsqrtf(var + 1e-5f);
    rowbuf[tid]       = f2bf((v0 - mean) * inv * w[tid]       + b[tid]);
    rowbuf[tid + 256] = f2bf((v1 - mean) * inv * w[tid + 256] + b[tid + 256]);
    rowbuf[tid + 512] = f2bf((v2 - mean) * inv * w[tid + 512] + b[tid + 512]);
    __syncthreads();
    if (tid < 96) *(uint4*)&out[base + (tid << 3)] = *(const uint4*)&rowbuf[tid << 3];
}

// ------------- weight transpose + cast: fp32 in[K][N] -> bf16 out[N][K] -----
__global__ __launch_bounds__(256) void transpose_wf(
    const float* __restrict__ in, u16* __restrict__ out, int K, int N)
{
    __shared__ u16 t[32][33];
    __shared__ u16 tt[32][32];   // row = n-local, 64B rows, 16B-aligned
    int n0 = blockIdx.x * 32, k0 = blockIdx.y * 32;
    int tx = threadIdx.x & 31, ty = threadIdx.x >> 5;
    for (int q = 0; q < 4; q++) {
        int k = k0 + ty + q * 8, n = n0 + tx;
        t[ty + q * 8][tx] = (k < K && n < N) ? f2bf(in[(size_t)k * N + n]) : (u16)0;
    }
    __syncthreads();
    for (int q = 0; q < 4; q++) tt[ty + q * 8][tx] = t[tx][ty + q * 8];
    __syncthreads();
    if (threadIdx.x < 128) {
        int r = threadIdx.x >> 2, c8 = (threadIdx.x & 3) << 3;
        int n = n0 + r, k = k0 + c8;
        if (n < N && k < K)
            *(uint4*)&out[(size_t)n * K + k] = *(const uint4*)&tt[r][c8];
    }
}

// --- rel tables -> bf16 combined matrix relT[64][64]: rows 0..26 = rel_h,
// rows 27..53 = rel_w, rows 54..63 = 0. B-operand of the MODE-6 G2 GEMM. ----
__global__ __launch_bounds__(256) void build_relT(
    const float* __restrict__ rh, const float* __restrict__ rw, u16* __restrict__ out)
{
    int i = blockIdx.x * 256 + threadIdx.x;   // 16 blocks x 256 = 4096
    int r = i >> 6, c = i & 63;
    float v = (r < 27) ? rh[r * 64 + c] : (r < 54 ? rw[(r - 27) * 64 + c] : 0.f);
    out[i] = f2bf(v);
}

// ------- build V^T per (local window, head): vt[z][d][m], m padded to 224 ---
__global__ __launch_bounds__(256) void build_vt(
    const u16* __restrict__ qkvc, u16* __restrict__ vt)
{
    int z = blockIdx.x;
    int wb = z / 12, h = z % 12;
    __shared__ u16 t[64][232];   // 464B rows: 16B-aligned for uint4 reads
    int tid = threadIdx.x;
    for (int base = 0; base < 196; base += 4) {
        int m = base + (tid >> 6);
        int d = tid & 63;
        t[d][m] = qkvc[(size_t)(wb * 196 + m) * 2304 + 1536 + h * 64 + d];
    }
    for (int idx = tid; idx < 28 * 64; idx += 256) {
        int m = 196 + idx / 64, d = idx % 64;
        t[d][m] = 0;
    }
    __syncthreads();
    size_t ob = (size_t)z * 64 * 224;
    for (int idx = tid; idx < 64 * 28; idx += 256) {
        int d = idx / 28, c8 = (idx % 28) << 3;
        *(uint4*)&vt[ob + (size_t)d * 224 + c8] = *(const uint4*)&t[d][c8];
    }
}

// ------------- softmax v2: barrier-free, wave-per-row, bias from G2 ---------
// grid (49, Wc*12). S: [z][196][224] bf16 in place; pad keys -> 0.
// bias(n,m) = G2[n][n/14 - m/14 + 13] + G2[n][27 + n%14 - m%14 + 13]
__global__ __launch_bounds__(256) void softmax_rel2(
    u16* __restrict__ S, const u16* __restrict__ G2)
{
    int z = blockIdx.y;
    int wv = threadIdx.x >> 6, lane = threadIdx.x & 63;
    int n = blockIdx.x * 4 + wv;                 // 49*4 = 196, all valid
    size_t srow = (size_t)z * 196 * 224 + (size_t)n * 224;
    const u16* g2 = G2 + (size_t)z * 196 * 64 + (size_t)n * 64;
    int qh = n / 14, qw = n % 14;
    float s[4];
    for (int c = 0; c < 4; c++) {
        int m = c * 64 + lane;
        if (m < 196) {
            int kk = m / 14, jj = m % 14;
            float bh = bf2f(g2[qh - kk + 13]);
            float bw = bf2f(g2[27 + qw - jj + 13]);
            s[c] = 0.125f * bf2f(S[srow + m]) + bh + bw;
        } else s[c] = -1e30f;
    }
    float mx = fmaxf(fmaxf(s[0], s[1]), fmaxf(s[2], s[3]));
    for (int o = 32; o > 0; o >>= 1) mx = fmaxf(mx, __shfl_xor(mx, o));
    float e[4], sm = 0.f;
    for (int c = 0; c < 4; c++) {
        int m = c * 64 + lane;
        e[c] = (m < 196) ? expf(s[c] - mx) : 0.f;
        sm += e[c];
    }
    for (int o = 32; o > 0; o >>= 1) sm += __shfl_xor(sm, o);
    float inv = 1.0f / sm;
    for (int c = 0; c < 4; c++) {
        int m = c * 64 + lane;
        if (m < 224) S[srow + m] = f2bf(e[c] * inv);
    }
}

// LDS slot swizzle on the READ side. gload_lds writes LDS linearly; the
// matching permutation is applied to the GLOBAL source column slot
// (slot ^ (row>>1)&3), so LDS[row][s] holds global slot s^xr and the
// reader fetches global slot q at LDS[row][q^xr] == swz_off(row, q*8).
__device__ __forceinline__ int swz_off(int row, int kcElem) {
    return row * 32 + (kcElem ^ (((row >> 1) & 3) << 3));
}

// ---------------- NT-mode MFMA bf16 GEMM, 128x128 tile, BK=32 ----------------
// m97 structure: per K-step {4x global_load_lds dwordx4 -> barrier -> ds_read
// frags + 16 MFMA -> barrier}. Wave-level TLP (4 blocks/CU) hides the drain.
// MODE 0: qkv = lnw @ qkvT^T + bias              (bf16 out Cb)
// MODE 1: S = q k^T per (window,head), blockIdx.z (bf16 out Cb, ld 224)
// MODE 2: PV: P @ Vt^T -> attn channel block     (bf16 out Cb)
// MODE 3: proj — scatter window-row -> global; Cf[g] = x_fp32[g]+acc+bias (fp32)
// MODE 4: fc1 + bias + exact gelu                (bf16 out Cb)
// MODE 5: fc2 — Cf[idx] = xf[idx]+acc+bias       (fp32 d_out RMW)
// MODE 6: G2 = q @ relT^T per (window,head)      (bf16 out Cb, ld 64)
template <int MODE>
__global__ __launch_bounds__(256, 4) void gemm_nt(
    const u16* __restrict__ Aall, const u16* __restrict__ Ball,
    const float* __restrict__ bias, const float* xf,
    u16* __restrict__ Cb, float* Cf, int M, int row0)
{
    constexpr int BK = 32;
    int N, K, lda, ldb;
    size_t aoff = 0, boff = 0, coff = 0;
    if constexpr (MODE == 0) { N = 2304; K = 768; lda = 768; ldb = 768; }
    else if constexpr (MODE == 1) {
        N = 196; K = 64; lda = 2304; ldb = 2304;
        int z = blockIdx.z;
        aoff = (size_t)(z / 12) * 196 * 2304 + (size_t)(z % 12) * 64;  // q
        boff = aoff + 768;                                             // k
        coff = (size_t)z * 196 * 224;
    } else if constexpr (MODE == 2) {
        N = 64; K = 224; lda = 224; ldb = 224;
        int z = blockIdx.z;
        aoff = (size_t)z * 196 * 224;                                  // P
        boff = (size_t)z * 64 * 224;                                   // V^T
        coff = (size_t)(z / 12) * 196 * 768 + (size_t)(z % 12) * 64;   // attn out
    } else if constexpr (MODE == 3) { N = 768; K = 768; lda = 768; ldb = 768; }
    else if constexpr (MODE == 4) { N = 3072; K = 768; lda = 768; ldb = 768; }
    else if constexpr (MODE == 6) {
        N = 64; K = 64; lda = 2304; ldb = 64;
        int z = blockIdx.z;
        aoff = (size_t)(z / 12) * 196 * 2304 + (size_t)(z % 12) * 64;  // q
        boff = 0;                                                      // relT
        coff = (size_t)z * 196 * 64;
    }
    else { N = 768; K = 3072; lda = 3072; ldb = 3072; }

    // 17408 B arena: K-loop As|Bs (16 KB); epilogue reuses as C staging.
    __shared__ __align__(16) u16 smem[8704];
    u16* As = smem;           // [128*32] linear
    u16* Bs = smem + 4096;    // [128*32] linear

    int tid = threadIdx.x, wid = tid >> 6, lane = tid & 63;
    int quad = lane >> 4, l16 = lane & 15;

    // XCD-aware bijective block swizzle (m204) for single-z modes.
    int bx = blockIdx.x, by = blockIdx.y;
    if constexpr (MODE != 1 && MODE != 2 && MODE != 6) {
        int gX = gridDim.x;
        int nwg = gX * gridDim.y;
        int orig = by * gX + bx;
        int q = nwg >> 3, r = nwg & 7;
        int xcd = orig & 7, idx = orig >> 3;
        int wg = (xcd < r ? xcd * (q + 1) : r * (q + 1) + (xcd - r) * q) + idx;
        bx = wg % gX; by = wg / gX;
    }
    int m_tile = by * 128, n_tile = bx * 128;
    int wm0 = (wid >> 1) * 64, wn0 = (wid & 1) * 64;

    const u16* A = Aall + aoff;
    const u16* B = Ball + boff;

    // staging: wave wid owns rows [wid*32, wid*32+32) of As and Bs.
    const u16* gA[2]; const u16* gB[2];
    u16 *lA[2], *lB[2];
    {
        int s = lane & 3, rofs = lane >> 2;
        for (int j = 0; j < 2; j++) {
            int r0 = wid * 32 + j * 16;
            int rr = r0 + rofs;
            int xr = (rr >> 1) & 3;
            int colo = ((s ^ xr) << 3);
            int am = m_tile + rr; if (am > M - 1) am = M - 1;
            int bn = n_tile + rr; if (bn > N - 1) bn = N - 1;
            gA[j] = A + (size_t)am * lda + colo;
            gB[j] = B + (size_t)bn * ldb + colo;
            lA[j] = &As[r0 * 32];
            lB[j] = &Bs[r0 * 32];
        }
    }

    f32x4_t acc[4][4];
    f32x4_t z4 = {0.f, 0.f, 0.f, 0.f};
    for (int mt = 0; mt < 4; mt++)
        for (int nt = 0; nt < 4; nt++) acc[mt][nt] = z4;

    for (int k0 = 0; k0 < K; k0 += BK) {
        gld16(gA[0] + k0, lA[0]);
        gld16(gA[1] + k0, lA[1]);
        gld16(gB[0] + k0, lB[0]);
        gld16(gB[1] + k0, lB[1]);
        __syncthreads();   // drains vmcnt -> tile visible
        bf16x8_t af[4], bfv[4];
        for (int t = 0; t < 4; t++) {
            int ar = wm0 + t * 16 + l16;
            int br = wn0 + t * 16 + l16;
            af[t]  = *(const bf16x8_t*)&As[swz_off(ar, quad * 8)];
            bfv[t] = *(const bf16x8_t*)&Bs[swz_off(br, quad * 8)];
        }
        for (int mt = 0; mt < 4; mt++)
            for (int nt = 0; nt < 4; nt++)
                acc[mt][nt] = __builtin_amdgcn_mfma_f32_16x16x32_bf16(
                    af[mt], bfv[nt], acc[mt][nt], 0, 0, 0);
        __syncthreads();   // all reads done before next overwrite
    }

    // ---- epilogue (C/D frag layout: col=lane&15, row=quad*4+reg) ----
    if constexpr (MODE == 0 || MODE == 1 || MODE == 2 || MODE == 4 || MODE == 6) {
        u16* Cs = smem;   // [64][136] per half
        int ldc = (MODE == 0) ? 2304 : (MODE == 1) ? 224 : (MODE == 2) ? 768
                : (MODE == 6) ? 64 : 3072;
        int colmax = (MODE == 1) ? 224 : N;   // mode-1 pad cols overwritten later
        for (int half = 0; half < 2; half++) {
            __syncthreads();   // As/Bs (or prev half) free
            if ((wm0 >> 6) == half) {
                for (int mt = 0; mt < 4; mt++) {
                    int rl = mt * 16 + quad * 4;
                    for (int nt = 0; nt < 4; nt++) {
                        int cl = wn0 + nt * 16 + l16;
                        int col = n_tile + cl;
                        for (int rg = 0; rg < 4; rg++) {
                            float v = acc[mt][nt][rg];
                            u16 o;
                            if constexpr (MODE == 0) o = f2bf(v + bias[col]);
                            else if constexpr (MODE == 4) {
                                float g = v + bias[col];
                                o = f2bf(0.5f * g * (1.0f + erff(g * 0.70710678118f)));
                            } else o = f2bf(v);
                            Cs[(rl + rg) * 136 + cl] = o;
                        }
                    }
                }
            }
            __syncthreads();
            for (int it = 0; it < 4; it++) {
                int chunk = tid + it * 256;
                int r = chunk >> 4, c8 = (chunk & 15) << 3;
                int grow = m_tile + half * 64 + r, gcol = n_tile + c8;
                if (grow >= M || gcol >= colmax) continue;
                *(uint4*)&Cb[coff + (size_t)grow * ldc + gcol] =
                    *(const uint4*)&Cs[r * 136 + c8];
            }
        }
    } else {
        // fp32 RMW modes (3, 5): four 32-row quarters through LDS
        float* Cfs = (float*)smem;   // [32][132]
        for (int q = 0; q < 4; q++) {
            __syncthreads();
            if ((wm0 >> 6) == (q >> 1)) {
                for (int mt2 = 0; mt2 < 2; mt2++) {
                    int mt = (q & 1) * 2 + mt2;
                    int rloc = mt2 * 16 + quad * 4;
                    for (int nt = 0; nt < 4; nt++) {
                        int cl = wn0 + nt * 16 + l16;
                        for (int rg = 0; rg < 4; rg++)
                            Cfs[(rloc + rg) * 132 + cl] = acc[mt][nt][rg];
                    }
                }
            }
            __syncthreads();
            for (int it = 0; it < 4; it++) {
                int chunk = tid + it * 256;
                int r = chunk >> 5, c4 = (chunk & 31) << 2;
                int grow = m_tile + q * 32 + r;
                int gcol = n_tile + c4;
                if (grow >= M || gcol >= N) continue;
                f32x4_t v4 = *(const f32x4_t*)&Cfs[r * 132 + c4];
                f32x4_t b4 = *(const f32x4_t*)&bias[gcol];
                if constexpr (MODE == 5) {
                    size_t idx = (size_t)(row0 + grow) * 768 + gcol;
                    f32x4_t x4 = *(const f32x4_t*)&xf[idx];
                    f32x4_t o4;
                    for (int j = 0; j < 4; j++) o4[j] = v4[j] + x4[j] + b4[j];
                    *(f32x4_t*)&Cf[idx] = o4;
                } else {
                    int wr = row0 + grow;
                    int wb2 = wr / 196, t2 = wr % 196;
                    int gh = ((wb2 % 25) / 5) * 14 + t2 / 14;
                    int gw = (wb2 % 5) * 14 + t2 % 14;
                    if (gh < 64 && gw < 64) {
                        size_t g = (size_t)(((wb2 / 25) * 64 + gh) * 64 + gw) * 768 + gcol;
                        f32x4_t x4 = *(const f32x4_t*)&xf[g];
                        f32x4_t o4;
                        for (int j = 0; j < 4; j++) o4[j] = v4[j] + x4[j] + b4[j];
                        *(f32x4_t*)&Cf[g] = o4;
                    }
                }
            }
        }
    }
}

extern "C" void kernel_launch(void* const* d_in, const int* in_sizes, int n_in,
                              void* d_out, int out_size, void* d_ws, size_t ws_size,
                              hipStream_t stream)
{
    (void)in_sizes; (void)n_in; (void)out_size;
    const float* x      = (const float*)d_in[0];
    const float* ln1_w  = (const float*)d_in[1];
    const float* ln1_b  = (const float*)d_in[2];
    const float* qkv_w  = (const float*)d_in[3];
    const float* qkv_b  = (const float*)d_in[4];
    const float* proj_w = (const float*)d_in[5];
    const float* proj_b = (const float*)d_in[6];
    const float* rel_h  = (const float*)d_in[7];
    const float* rel_w  = (const float*)d_in[8];
    const float* ln2_w  = (const float*)d_in[9];
    const float* ln2_b  = (const float*)d_in[10];
    const float* fc1_w  = (const float*)d_in[11];
    const float* fc1_b  = (const float*)d_in[12];
    const float* fc2_w  = (const float*)d_in[13];
    const float* fc2_b  = (const float*)d_in[14];

    // ---- ws layout: weights always at base, scratch above ----
    const size_t WT = 14155776ull + 8192ull;   // 13.5 MB weights + relT (8 KB)
    char* ws = (char*)d_ws;
    u16* qkvT  = (u16*)ws;
    u16* projT = qkvT + 2304 * 768;
    u16* fc1T  = projT + 768 * 768;
    u16* fc2T  = fc1T + 3072 * 768;
    u16* relT  = fc2T + 3072 * 768;            // [64][64] bf16
    char* scratch = ws + WT;
    size_t avail = (ws_size > WT) ? (ws_size - WT) : 0;

    // per-window: lnw 301056 + qkv 903168 + S 1053696 + vt 344064 + attn 301056
    //           + G2 301056  = 3204096
    const size_t perW = 3204096ull;
    static const int wc_cand[8] = {100, 50, 25, 20, 10, 5, 2, 1};
    int Wc = 1;
    for (int i = 0; i < 8; i++) {
        if ((size_t)wc_cand[i] * perW <= avail) { Wc = wc_cand[i]; break; }
    }
    static const int rm_cand[8] = {16384, 8192, 4096, 2048, 1024, 512, 256, 128};
    int Rm = 128;
    for (int i = 0; i < 8; i++) {
        if ((size_t)rm_cand[i] * 7680ull <= avail) { Rm = rm_cand[i]; break; }
    }

    u16* lnwc  = (u16*)scratch;
    u16* qkvc  = (u16*)(scratch + (size_t)Wc * 301056ull);
    u16* Sc    = (u16*)(scratch + (size_t)Wc * 1204224ull);
    u16* vtc   = (u16*)(scratch + (size_t)Wc * 2257920ull);
    u16* attnc = (u16*)(scratch + (size_t)Wc * 2601984ull);
    u16* G2c   = (u16*)(scratch + (size_t)Wc * 2903040ull);
    u16* hbuf  = (u16*)scratch;                               // MLP overlays
    u16* xn2c  = (u16*)(scratch + (size_t)Rm * 6144ull);
    float* dout = (float*)d_out;                              // x1 (fp32)

    transpose_wf<<<dim3(72, 24), 256, 0, stream>>>(qkv_w, qkvT, 768, 2304);
    transpose_wf<<<dim3(24, 24), 256, 0, stream>>>(proj_w, projT, 768, 768);
    transpose_wf<<<dim3(96, 24), 256, 0, stream>>>(fc1_w, fc1T, 768, 3072);
    transpose_wf<<<dim3(24, 96), 256, 0, stream>>>(fc2_w, fc2T, 3072, 768);
    build_relT<<<16, 256, 0, stream>>>(rel_h, rel_w, relT);

    int nch = 100 / Wc;
    int rows = Wc * 196;
    int gy = (rows + 127) / 128;
    for (int c = 0; c < nch; c++) {
        int r0 = c * rows;
        ln1_window<<<rows, 256, 0, stream>>>(x, ln1_w, ln1_b, lnwc, r0);
        gemm_nt<0><<<dim3(18, gy), 256, 0, stream>>>(
            lnwc, qkvT, qkv_b, nullptr, qkvc, nullptr, rows, 0);
        gemm_nt<1><<<dim3(2, 2, Wc * 12), 256, 0, stream>>>(
            qkvc, qkvc, nullptr, nullptr, Sc, nullptr, 196, 0);
        gemm_nt<6><<<dim3(1, 2, Wc * 12), 256, 0, stream>>>(
            qkvc, relT, nullptr, nullptr, G2c, nullptr, 196, 0);
        build_vt<<<Wc * 12, 256, 0, stream>>>(qkvc, vtc);
        softmax_rel2<<<dim3(49, Wc * 12), 256, 0, stream>>>(Sc, G2c);
        gemm_nt<2><<<dim3(1, 2, Wc * 12), 256, 0, stream>>>(
            Sc, vtc, nullptr, nullptr, attnc, nullptr, 196, 0);
        gemm_nt<3><<<dim3(6, gy), 256, 0, stream>>>(
            attnc, projT, proj_b, x, nullptr, dout, rows, r0);
    }

    int nm = 16384 / Rm;
    for (int c = 0; c < nm; c++) {
        int r0 = c * Rm;
        ln2_chunk<<<Rm, 256, 0, stream>>>(dout + (size_t)r0 * 768, ln2_w, ln2_b, xn2c);
        gemm_nt<4><<<dim3(24, Rm / 128), 256, 0, stream>>>(
            xn2c, fc1T, fc1_b, nullptr, hbuf, nullptr, Rm, 0);
        gemm_nt<5><<<dim3(6, Rm / 128), 256, 0, stream>>>(
            hbuf, fc2T, fc2_b, dout, nullptr, dout, Rm, r0);
    }
}

// Round 8
// 754.088 us; speedup vs baseline: 4.3507x; 1.0064x over previous
//
#include <hip/hip_runtime.h>

typedef unsigned short u16;
typedef __bf16 bf16x8_t __attribute__((ext_vector_type(8)));
typedef float f32x4_t __attribute__((ext_vector_type(4)));

__device__ __forceinline__ float bf2f(u16 u) {
    union { unsigned u; float f; } c; c.u = ((unsigned)u) << 16; return c.f;
}
__device__ __forceinline__ u16 f2bf(float f) {
    union { float f; unsigned u; } c; c.f = f;
    unsigned u = c.u;
    unsigned r = (u + 0x7FFFu + ((u >> 16) & 1u)) >> 16;
    return (u16)r;
}

// async global->LDS, 16B per lane. LDS dest is wave-uniform base + lane*16.
__device__ __forceinline__ void gld16(const u16* g, u16* l) {
    __builtin_amdgcn_global_load_lds(
        (const __attribute__((address_space(1))) unsigned*)g,
        (__attribute__((address_space(3))) unsigned*)l, 16, 0, 0);
}

__device__ __forceinline__ void block_sum2(float& s, float& sq) {
    for (int o = 32; o > 0; o >>= 1) { s += __shfl_xor(s, o); sq += __shfl_xor(sq, o); }
    __shared__ float sh[8];
    int wid = threadIdx.x >> 6;
    if ((threadIdx.x & 63) == 0) { sh[wid] = s; sh[4 + wid] = sq; }
    __syncthreads();
    s  = sh[0] + sh[1] + sh[2] + sh[3];
    sq = sh[4] + sh[5] + sh[6] + sh[7];
}

// ---- LN1 + window partition: fp32 x -> bf16 window rows (wide stores) ------
__global__ __launch_bounds__(256) void ln1_window(
    const float* __restrict__ x, const float* __restrict__ w, const float* __restrict__ b,
    u16* __restrict__ out, int row0)
{
    int lrow = blockIdx.x, tid = threadIdx.x;
    int wr = row0 + lrow;
    int wb = wr / 196, t = wr % 196;
    int gh = ((wb % 25) / 5) * 14 + t / 14;
    int gw = (wb % 5) * 14 + t % 14;
    size_t orow = (size_t)lrow * 768;
    __shared__ u16 rowbuf[768];
    if (gh >= 64 || gw >= 64) {
        rowbuf[tid] = 0; rowbuf[tid + 256] = 0; rowbuf[tid + 512] = 0;
        __syncthreads();
        if (tid < 96) *(uint4*)&out[orow + (tid << 3)] = *(const uint4*)&rowbuf[tid << 3];
        return;
    }
    size_t base = (size_t)(((wb / 25) * 64 + gh) * 64 + gw) * 768;
    float v0 = x[base + tid], v1 = x[base + tid + 256], v2 = x[base + tid + 512];
    float s = v0 + v1 + v2, sq = v0 * v0 + v1 * v1 + v2 * v2;
    block_sum2(s, sq);
    float mean = s * (1.0f / 768.0f);
    float var  = sq * (1.0f / 768.0f) - mean * mean;
    float inv  = rsqrtf(var + 1e-5f);
    rowbuf[tid]       = f2bf((v0 - mean) * inv * w[tid]       + b[tid]);
    rowbuf[tid + 256] = f2bf((v1 - mean) * inv * w[tid + 256] + b[tid + 256]);
    rowbuf[tid + 512] = f2bf((v2 - mean) * inv * w[tid + 512] + b[tid + 512]);
    __syncthreads();
    if (tid < 96) *(uint4*)&out[orow + (tid << 3)] = *(const uint4*)&rowbuf[tid << 3];
}

// ---- LN2 chunk: fp32 x1 rows -> bf16 (wide stores) -------------------------
__global__ __launch_bounds__(256) void ln2_chunk(
    const float* __restrict__ xin, const float* __restrict__ w, const float* __restrict__ b,
    u16* __restrict__ out)
{
    int row = blockIdx.x, tid = threadIdx.x;
    size_t base = (size_t)row * 768;
    __shared__ u16 rowbuf[768];
    float v0 = xin[base + tid], v1 = xin[base + tid + 256], v2 = xin[base + tid + 512];
    float s = v0 + v1 + v2, sq = v0 * v0 + v1 * v1 + v2 * v2;
    block_sum2(s, sq);
    float mean = s * (1.0f / 768.0f);
    float var  = sq * (1.0f / 768.0f) - mean * mean;
    float inv  = rsqrtf(var + 1e-5f);
    rowbuf[tid]       = f2bf((v0 - mean) * inv * w[tid]       + b[tid]);
    rowbuf[tid + 256] = f2bf((v1 - mean) * inv * w[tid + 256] + b[tid + 256]);
    rowbuf[tid + 512] = f2bf((v2 - mean) * inv * w[tid + 512] + b[tid + 512]);
    __syncthreads();
    if (tid < 96) *(uint4*)&out[base + (tid << 3)] = *(const uint4*)&rowbuf[tid << 3];
}

// ------------- weight transpose + cast: fp32 in[K][N] -> bf16 out[N][K] -----
__global__ __launch_bounds__(256) void transpose_wf(
    const float* __restrict__ in, u16* __restrict__ out, int K, int N)
{
    __shared__ u16 t[32][33];
    __shared__ u16 tt[32][32];   // row = n-local, 64B rows, 16B-aligned
    int n0 = blockIdx.x * 32, k0 = blockIdx.y * 32;
    int tx = threadIdx.x & 31, ty = threadIdx.x >> 5;
    for (int q = 0; q < 4; q++) {
        int k = k0 + ty + q * 8, n = n0 + tx;
        t[ty + q * 8][tx] = (k < K && n < N) ? f2bf(in[(size_t)k * N + n]) : (u16)0;
    }
    __syncthreads();
    for (int q = 0; q < 4; q++) tt[ty + q * 8][tx] = t[tx][ty + q * 8];
    __syncthreads();
    if (threadIdx.x < 128) {
        int r = threadIdx.x >> 2, c8 = (threadIdx.x & 3) << 3;
        int n = n0 + r, k = k0 + c8;
        if (n < N && k < K)
            *(uint4*)&out[(size_t)n * K + k] = *(const uint4*)&tt[r][c8];
    }
}

// --- rel tables -> bf16 combined matrix relT[64][64]: rows 0..26 = rel_h,
// rows 27..53 = rel_w, rows 54..63 = 0. B-operand of the MODE-6 G2 GEMM. ----
__global__ __launch_bounds__(256) void build_relT(
    const float* __restrict__ rh, const float* __restrict__ rw, u16* __restrict__ out)
{
    int i = blockIdx.x * 256 + threadIdx.x;   // 16 blocks x 256 = 4096
    int r = i >> 6, c = i & 63;
    float v = (r < 27) ? rh[r * 64 + c] : (r < 54 ? rw[(r - 27) * 64 + c] : 0.f);
    out[i] = f2bf(v);
}

// ------- build V^T per (local window, head): vt[z][d][m], m padded to 224 ---
__global__ __launch_bounds__(256) void build_vt(
    const u16* __restrict__ qkvc, u16* __restrict__ vt)
{
    int z = blockIdx.x;
    int wb = z / 12, h = z % 12;
    __shared__ u16 t[64][232];   // 464B rows: 16B-aligned for uint4 reads
    int tid = threadIdx.x;
    for (int base = 0; base < 196; base += 4) {
        int m = base + (tid >> 6);
        int d = tid & 63;
        t[d][m] = qkvc[(size_t)(wb * 196 + m) * 2304 + 1536 + h * 64 + d];
    }
    for (int idx = tid; idx < 28 * 64; idx += 256) {
        int m = 196 + idx / 64, d = idx % 64;
        t[d][m] = 0;
    }
    __syncthreads();
    size_t ob = (size_t)z * 64 * 224;
    for (int idx = tid; idx < 64 * 28; idx += 256) {
        int d = idx / 28, c8 = (idx % 28) << 3;
        *(uint4*)&vt[ob + (size_t)d * 224 + c8] = *(const uint4*)&t[d][c8];
    }
}

// ------------- softmax v2: barrier-free, wave-per-row, bias from G2 ---------
// grid (49, Wc*12). S: [z][196][224] bf16 in place; pad keys -> 0.
// bias(n,m) = G2[n][n/14 - m/14 + 13] + G2[n][27 + n%14 - m%14 + 13]
__global__ __launch_bounds__(256) void softmax_rel2(
    u16* __restrict__ S, const u16* __restrict__ G2)
{
    int z = blockIdx.y;
    int wv = threadIdx.x >> 6, lane = threadIdx.x & 63;
    int n = blockIdx.x * 4 + wv;                 // 49*4 = 196, all valid
    size_t srow = (size_t)z * 196 * 224 + (size_t)n * 224;
    const u16* g2 = G2 + (size_t)z * 196 * 64 + (size_t)n * 64;
    int qh = n / 14, qw = n % 14;
    float s[4];
    for (int c = 0; c < 4; c++) {
        int m = c * 64 + lane;
        if (m < 196) {
            int kk = m / 14, jj = m % 14;
            float bh = bf2f(g2[qh - kk + 13]);
            float bw = bf2f(g2[27 + qw - jj + 13]);
            s[c] = 0.125f * bf2f(S[srow + m]) + bh + bw;
        } else s[c] = -1e30f;
    }
    float mx = fmaxf(fmaxf(s[0], s[1]), fmaxf(s[2], s[3]));
    for (int o = 32; o > 0; o >>= 1) mx = fmaxf(mx, __shfl_xor(mx, o));
    float e[4], sm = 0.f;
    for (int c = 0; c < 4; c++) {
        int m = c * 64 + lane;
        e[c] = (m < 196) ? expf(s[c] - mx) : 0.f;
        sm += e[c];
    }
    for (int o = 32; o > 0; o >>= 1) sm += __shfl_xor(sm, o);
    float inv = 1.0f / sm;
    for (int c = 0; c < 4; c++) {
        int m = c * 64 + lane;
        if (m < 224) S[srow + m] = f2bf(e[c] * inv);
    }
}

// LDS slot swizzle on the READ side. gload_lds writes LDS linearly; the
// matching permutation is applied to the GLOBAL source column slot
// (slot ^ (row>>1)&3), so LDS[row][s] holds global slot s^xr and the
// reader fetches global slot q at LDS[row][q^xr] == swz_off(row, q*8).
__device__ __forceinline__ int swz_off(int row, int kcElem) {
    return row * 32 + (kcElem ^ (((row >> 1) & 3) << 3));
}

// ---------------- NT-mode MFMA bf16 GEMM, 128x128 tile, BK=32 ----------------
// Round-4-proven staging (gld_lds w16, both-sides slot swizzle, row clamps),
// now DOUBLE-BUFFERED with ONE barrier per K-step:
//   prologue: issue tile 0 -> buf0
//   iter k:   barrier (drains tile-k loads; all waves done reading buf^1)
//             issue tile k+1 -> buf^1   (DMA lands while we compute)
//             ds_read frags from buf + 16 MFMA
// Buffer select is a uniform byte offset (cur<<13) — no runtime-indexed
// pointer arrays (rule #20). All barriers unconditional.
// MODE 0: qkv = lnw @ qkvT^T + bias              (bf16 out Cb)
// MODE 1: S = q k^T per (window,head), blockIdx.z (bf16 out Cb, ld 224)
// MODE 2: PV: P @ Vt^T -> attn channel block     (bf16 out Cb)
// MODE 3: proj — scatter window-row -> global; Cf[g] = x_fp32[g]+acc+bias (fp32)
// MODE 4: fc1 + bias + exact gelu                (bf16 out Cb)
// MODE 5: fc2 — Cf[idx] = xf[idx]+acc+bias       (fp32 d_out RMW)
// MODE 6: G2 = q @ relT^T per (window,head)      (bf16 out Cb, ld 64)
template <int MODE>
__global__ __launch_bounds__(256, 4) void gemm_nt(
    const u16* __restrict__ Aall, const u16* __restrict__ Ball,
    const float* __restrict__ bias, const float* xf,
    u16* __restrict__ Cb, float* Cf, int M, int row0)
{
    constexpr int BK = 32;
    int N, K, lda, ldb;
    size_t aoff = 0, boff = 0, coff = 0;
    if constexpr (MODE == 0) { N = 2304; K = 768; lda = 768; ldb = 768; }
    else if constexpr (MODE == 1) {
        N = 196; K = 64; lda = 2304; ldb = 2304;
        int z = blockIdx.z;
        aoff = (size_t)(z / 12) * 196 * 2304 + (size_t)(z % 12) * 64;  // q
        boff = aoff + 768;                                             // k
        coff = (size_t)z * 196 * 224;
    } else if constexpr (MODE == 2) {
        N = 64; K = 224; lda = 224; ldb = 224;
        int z = blockIdx.z;
        aoff = (size_t)z * 196 * 224;                                  // P
        boff = (size_t)z * 64 * 224;                                   // V^T
        coff = (size_t)(z / 12) * 196 * 768 + (size_t)(z % 12) * 64;   // attn out
    } else if constexpr (MODE == 3) { N = 768; K = 768; lda = 768; ldb = 768; }
    else if constexpr (MODE == 4) { N = 3072; K = 768; lda = 768; ldb = 768; }
    else if constexpr (MODE == 6) {
        N = 64; K = 64; lda = 2304; ldb = 64;
        int z = blockIdx.z;
        aoff = (size_t)(z / 12) * 196 * 2304 + (size_t)(z % 12) * 64;  // q
        boff = 0;                                                      // relT
        coff = (size_t)z * 196 * 64;
    }
    else { N = 768; K = 3072; lda = 3072; ldb = 3072; }

    // 32 KB arena: buf0 = As|Bs at [0,8192) u16, buf1 at [8192,16384) u16.
    // Epilogue reuses [0,8704) as C staging.
    __shared__ __align__(16) u16 smem[16384];

    int tid = threadIdx.x, wid = tid >> 6, lane = tid & 63;
    int quad = lane >> 4, l16 = lane & 15;

    // XCD-aware bijective block swizzle (m204) for single-z modes.
    int bx = blockIdx.x, by = blockIdx.y;
    if constexpr (MODE != 1 && MODE != 2 && MODE != 6) {
        int gX = gridDim.x;
        int nwg = gX * gridDim.y;
        int orig = by * gX + bx;
        int q = nwg >> 3, r = nwg & 7;
        int xcd = orig & 7, idx = orig >> 3;
        int wg = (xcd < r ? xcd * (q + 1) : r * (q + 1) + (xcd - r) * q) + idx;
        bx = wg % gX; by = wg / gX;
    }
    int m_tile = by * 128, n_tile = bx * 128;
    int wm0 = (wid >> 1) * 64, wn0 = (wid & 1) * 64;

    const u16* A = Aall + aoff;
    const u16* B = Ball + boff;

    // staging: wave wid owns rows [wid*32, wid*32+32) of As and Bs.
    // 2 issues per operand; issue j: lane i -> lds row r0 + (i>>2), slot i&3.
    // global column slot pre-swizzled: (i&3) ^ ((row>>1)&3). rows clamped.
    const u16* gA[2]; const u16* gB[2];
    int loff[2];
    {
        int s = lane & 3, rofs = lane >> 2;
        for (int j = 0; j < 2; j++) {
            int r0 = wid * 32 + j * 16;
            int rr = r0 + rofs;
            int xr = (rr >> 1) & 3;
            int colo = ((s ^ xr) << 3);
            int am = m_tile + rr; if (am > M - 1) am = M - 1;
            int bn = n_tile + rr; if (bn > N - 1) bn = N - 1;
            gA[j] = A + (size_t)am * lda + colo;
            gB[j] = B + (size_t)bn * ldb + colo;
            loff[j] = r0 * 32;
        }
    }

    f32x4_t acc[4][4];
    f32x4_t z4 = {0.f, 0.f, 0.f, 0.f};
    for (int mt = 0; mt < 4; mt++)
        for (int nt = 0; nt < 4; nt++) acc[mt][nt] = z4;

    // prologue: issue tile 0 into buf0
    for (int j = 0; j < 2; j++) {
        gld16(gA[j], smem + loff[j]);
        gld16(gB[j], smem + 4096 + loff[j]);
    }

    int cur = 0;
    for (int k0 = 0; k0 < K; k0 += BK) {
        __syncthreads();   // drains tile-k loads; all waves done reading buf^1
        int boffc = cur << 13;          // current buffer byte-base (u16 elems)
        if (k0 + BK < K) {
            int boffn = boffc ^ 8192;   // prefetch target = other buffer
            for (int j = 0; j < 2; j++) {
                gld16(gA[j] + k0 + BK, smem + boffn + loff[j]);
                gld16(gB[j] + k0 + BK, smem + boffn + 4096 + loff[j]);
            }
        }
        const u16* Ac = smem + boffc;
        const u16* Bc = smem + boffc + 4096;
        bf16x8_t af[4], bfv[4];
        for (int t = 0; t < 4; t++) {
            int ar = wm0 + t * 16 + l16;
            int br = wn0 + t * 16 + l16;
            af[t]  = *(const bf16x8_t*)&Ac[swz_off(ar, quad * 8)];
            bfv[t] = *(const bf16x8_t*)&Bc[swz_off(br, quad * 8)];
        }
        for (int mt = 0; mt < 4; mt++)
            for (int nt = 0; nt < 4; nt++)
                acc[mt][nt] = __builtin_amdgcn_mfma_f32_16x16x32_bf16(
                    af[mt], bfv[nt], acc[mt][nt], 0, 0, 0);
        cur ^= 1;
    }

    // ---- epilogue (C/D frag layout: col=lane&15, row=quad*4+reg) ----
    if constexpr (MODE == 0 || MODE == 1 || MODE == 2 || MODE == 4 || MODE == 6) {
        u16* Cs = smem;   // [64][136] per half
        int ldc = (MODE == 0) ? 2304 : (MODE == 1) ? 224 : (MODE == 2) ? 768
                : (MODE == 6) ? 64 : 3072;
        int colmax = (MODE == 1) ? 224 : N;   // mode-1 pad cols overwritten later
        for (int half = 0; half < 2; half++) {
            __syncthreads();   // K-loop reads (or prev half) done
            if ((wm0 >> 6) == half) {
                for (int mt = 0; mt < 4; mt++) {
                    int rl = mt * 16 + quad * 4;
                    for (int nt = 0; nt < 4; nt++) {
                        int cl = wn0 + nt * 16 + l16;
                        int col = n_tile + cl;
                        for (int rg = 0; rg < 4; rg++) {
                            float v = acc[mt][nt][rg];
                            u16 o;
                            if constexpr (MODE == 0) o = f2bf(v + bias[col]);
                            else if constexpr (MODE == 4) {
                                float g = v + bias[col];
                                o = f2bf(0.5f * g * (1.0f + erff(g * 0.70710678118f)));
                            } else o = f2bf(v);
                            Cs[(rl + rg) * 136 + cl] = o;
                        }
                    }
                }
            }
            __syncthreads();
            for (int it = 0; it < 4; it++) {
                int chunk = tid + it * 256;
                int r = chunk >> 4, c8 = (chunk & 15) << 3;
                int grow = m_tile + half * 64 + r, gcol = n_tile + c8;
                if (grow >= M || gcol >= colmax) continue;
                *(uint4*)&Cb[coff + (size_t)grow * ldc + gcol] =
                    *(const uint4*)&Cs[r * 136 + c8];
            }
        }
    } else {
        // fp32 RMW modes (3, 5): four 32-row quarters through LDS
        float* Cfs = (float*)smem;   // [32][132]
        for (int q = 0; q < 4; q++) {
            __syncthreads();
            if ((wm0 >> 6) == (q >> 1)) {
                for (int mt2 = 0; mt2 < 2; mt2++) {
                    int mt = (q & 1) * 2 + mt2;
                    int rloc = mt2 * 16 + quad * 4;
                    for (int nt = 0; nt < 4; nt++) {
                        int cl = wn0 + nt * 16 + l16;
                        for (int rg = 0; rg < 4; rg++)
                            Cfs[(rloc + rg) * 132 + cl] = acc[mt][nt][rg];
                    }
                }
            }
            __syncthreads();
            for (int it = 0; it < 4; it++) {
                int chunk = tid + it * 256;
                int r = chunk >> 5, c4 = (chunk & 31) << 2;
                int grow = m_tile + q * 32 + r;
                int gcol = n_tile + c4;
                if (grow >= M || gcol >= N) continue;
                f32x4_t v4 = *(const f32x4_t*)&Cfs[r * 132 + c4];
                f32x4_t b4 = *(const f32x4_t*)&bias[gcol];
                if constexpr (MODE == 5) {
                    size_t idx = (size_t)(row0 + grow) * 768 + gcol;
                    f32x4_t x4 = *(const f32x4_t*)&xf[idx];
                    f32x4_t o4;
                    for (int j = 0; j < 4; j++) o4[j] = v4[j] + x4[j] + b4[j];
                    *(f32x4_t*)&Cf[idx] = o4;
                } else {
                    int wr = row0 + grow;
                    int wb2 = wr / 196, t2 = wr % 196;
                    int gh = ((wb2 % 25) / 5) * 14 + t2 / 14;
                    int gw = (wb2 % 5) * 14 + t2 % 14;
                    if (gh < 64 && gw < 64) {
                        size_t g = (size_t)(((wb2 / 25) * 64 + gh) * 64 + gw) * 768 + gcol;
                        f32x4_t x4 = *(const f32x4_t*)&xf[g];
                        f32x4_t o4;
                        for (int j = 0; j < 4; j++) o4[j] = v4[j] + x4[j] + b4[j];
                        *(f32x4_t*)&Cf[g] = o4;
                    }
                }
            }
        }
    }
}

extern "C" void kernel_launch(void* const* d_in, const int* in_sizes, int n_in,
                              void* d_out, int out_size, void* d_ws, size_t ws_size,
                              hipStream_t stream)
{
    (void)in_sizes; (void)n_in; (void)out_size;
    const float* x      = (const float*)d_in[0];
    const float* ln1_w  = (const float*)d_in[1];
    const float* ln1_b  = (const float*)d_in[2];
    const float* qkv_w  = (const float*)d_in[3];
    const float* qkv_b  = (const float*)d_in[4];
    const float* proj_w = (const float*)d_in[5];
    const float* proj_b = (const float*)d_in[6];
    const float* rel_h  = (const float*)d_in[7];
    const float* rel_w  = (const float*)d_in[8];
    const float* ln2_w  = (const float*)d_in[9];
    const float* ln2_b  = (const float*)d_in[10];
    const float* fc1_w  = (const float*)d_in[11];
    const float* fc1_b  = (const float*)d_in[12];
    const float* fc2_w  = (const float*)d_in[13];
    const float* fc2_b  = (const float*)d_in[14];

    // ---- ws layout: weights always at base, scratch above ----
    const size_t WT = 14155776ull + 8192ull;   // 13.5 MB weights + relT (8 KB)
    char* ws = (char*)d_ws;
    u16* qkvT  = (u16*)ws;
    u16* projT = qkvT + 2304 * 768;
    u16* fc1T  = projT + 768 * 768;
    u16* fc2T  = fc1T + 3072 * 768;
    u16* relT  = fc2T + 3072 * 768;            // [64][64] bf16
    char* scratch = ws + WT;
    size_t avail = (ws_size > WT) ? (ws_size - WT) : 0;

    // per-window: lnw 301056 + qkv 903168 + S 1053696 + vt 344064 + attn 301056
    //           + G2 301056  = 3204096
    const size_t perW = 3204096ull;
    static const int wc_cand[8] = {100, 50, 25, 20, 10, 5, 2, 1};
    int Wc = 1;
    for (int i = 0; i < 8; i++) {
        if ((size_t)wc_cand[i] * perW <= avail) { Wc = wc_cand[i]; break; }
    }
    static const int rm_cand[8] = {16384, 8192, 4096, 2048, 1024, 512, 256, 128};
    int Rm = 128;
    for (int i = 0; i < 8; i++) {
        if ((size_t)rm_cand[i] * 7680ull <= avail) { Rm = rm_cand[i]; break; }
    }

    u16* lnwc  = (u16*)scratch;
    u16* qkvc  = (u16*)(scratch + (size_t)Wc * 301056ull);
    u16* Sc    = (u16*)(scratch + (size_t)Wc * 1204224ull);
    u16* vtc   = (u16*)(scratch + (size_t)Wc * 2257920ull);
    u16* attnc = (u16*)(scratch + (size_t)Wc * 2601984ull);
    u16* G2c   = (u16*)(scratch + (size_t)Wc * 2903040ull);
    u16* hbuf  = (u16*)scratch;                               // MLP overlays
    u16* xn2c  = (u16*)(scratch + (size_t)Rm * 6144ull);
    float* dout = (float*)d_out;                              // x1 (fp32)

    transpose_wf<<<dim3(72, 24), 256, 0, stream>>>(qkv_w, qkvT, 768, 2304);
    transpose_wf<<<dim3(24, 24), 256, 0, stream>>>(proj_w, projT, 768, 768);
    transpose_wf<<<dim3(96, 24), 256, 0, stream>>>(fc1_w, fc1T, 768, 3072);
    transpose_wf<<<dim3(24, 96), 256, 0, stream>>>(fc2_w, fc2T, 3072, 768);
    build_relT<<<16, 256, 0, stream>>>(rel_h, rel_w, relT);

    int nch = 100 / Wc;
    int rows = Wc * 196;
    int gy = (rows + 127) / 128;
    for (int c = 0; c < nch; c++) {
        int r0 = c * rows;
        ln1_window<<<rows, 256, 0, stream>>>(x, ln1_w, ln1_b, lnwc, r0);
        gemm_nt<0><<<dim3(18, gy), 256, 0, stream>>>(
            lnwc, qkvT, qkv_b, nullptr, qkvc, nullptr, rows, 0);
        gemm_nt<1><<<dim3(2, 2, Wc * 12), 256, 0, stream>>>(
            qkvc, qkvc, nullptr, nullptr, Sc, nullptr, 196, 0);
        gemm_nt<6><<<dim3(1, 2, Wc * 12), 256, 0, stream>>>(
            qkvc, relT, nullptr, nullptr, G2c, nullptr, 196, 0);
        build_vt<<<Wc * 12, 256, 0, stream>>>(qkvc, vtc);
        softmax_rel2<<<dim3(49, Wc * 12), 256, 0, stream>>>(Sc, G2c);
        gemm_nt<2><<<dim3(1, 2, Wc * 12), 256, 0, stream>>>(
            Sc, vtc, nullptr, nullptr, attnc, nullptr, 196, 0);
        gemm_nt<3><<<dim3(6, gy), 256, 0, stream>>>(
            attnc, projT, proj_b, x, nullptr, dout, rows, r0);
    }

    int nm = 16384 / Rm;
    for (int c = 0; c < nm; c++) {
        int r0 = c * Rm;
        ln2_chunk<<<Rm, 256, 0, stream>>>(dout + (size_t)r0 * 768, ln2_w, ln2_b, xn2c);
        gemm_nt<4><<<dim3(24, Rm / 128), 256, 0, stream>>>(
            xn2c, fc1T, fc1_b, nullptr, hbuf, nullptr, Rm, 0);
        gemm_nt<5><<<dim3(6, Rm / 128), 256, 0, stream>>>(
            hbuf, fc2T, fc2_b, dout, nullptr, dout, Rm, r0);
    }
}

// Round 9
// 753.307 us; speedup vs baseline: 4.3553x; 1.0010x over previous
//
#include <hip/hip_runtime.h>

typedef unsigned short u16;
typedef __bf16 bf16x8_t __attribute__((ext_vector_type(8)));
typedef float f32x4_t __attribute__((ext_vector_type(4)));

__device__ __forceinline__ float bf2f(u16 u) {
    union { unsigned u; float f; } c; c.u = ((unsigned)u) << 16; return c.f;
}
__device__ __forceinline__ u16 f2bf(float f) {
    union { float f; unsigned u; } c; c.f = f;
    unsigned u = c.u;
    unsigned r = (u + 0x7FFFu + ((u >> 16) & 1u)) >> 16;
    return (u16)r;
}

// async global->LDS, 16B per lane. LDS dest is wave-uniform base + lane*16.
__device__ __forceinline__ void gld16(const u16* g, u16* l) {
    __builtin_amdgcn_global_load_lds(
        (const __attribute__((address_space(1))) unsigned*)g,
        (__attribute__((address_space(3))) unsigned*)l, 16, 0, 0);
}

__device__ __forceinline__ void block_sum2(float& s, float& sq) {
    for (int o = 32; o > 0; o >>= 1) { s += __shfl_xor(s, o); sq += __shfl_xor(sq, o); }
    __shared__ float sh[8];
    int wid = threadIdx.x >> 6;
    if ((threadIdx.x & 63) == 0) { sh[wid] = s; sh[4 + wid] = sq; }
    __syncthreads();
    s  = sh[0] + sh[1] + sh[2] + sh[3];
    sq = sh[4] + sh[5] + sh[6] + sh[7];
}

// ---- LN1 + window partition: fp32 x -> bf16 window rows (wide stores) ------
__global__ __launch_bounds__(256) void ln1_window(
    const float* __restrict__ x, const float* __restrict__ w, const float* __restrict__ b,
    u16* __restrict__ out, int row0)
{
    int lrow = blockIdx.x, tid = threadIdx.x;
    int wr = row0 + lrow;
    int wb = wr / 196, t = wr % 196;
    int gh = ((wb % 25) / 5) * 14 + t / 14;
    int gw = (wb % 5) * 14 + t % 14;
    size_t orow = (size_t)lrow * 768;
    __shared__ u16 rowbuf[768];
    if (gh >= 64 || gw >= 64) {
        rowbuf[tid] = 0; rowbuf[tid + 256] = 0; rowbuf[tid + 512] = 0;
        __syncthreads();
        if (tid < 96) *(uint4*)&out[orow + (tid << 3)] = *(const uint4*)&rowbuf[tid << 3];
        return;
    }
    size_t base = (size_t)(((wb / 25) * 64 + gh) * 64 + gw) * 768;
    float v0 = x[base + tid], v1 = x[base + tid + 256], v2 = x[base + tid + 512];
    float s = v0 + v1 + v2, sq = v0 * v0 + v1 * v1 + v2 * v2;
    block_sum2(s, sq);
    float mean = s * (1.0f / 768.0f);
    float var  = sq * (1.0f / 768.0f) - mean * mean;
    float inv  = rsqrtf(var + 1e-5f);
    rowbuf[tid]       = f2bf((v0 - mean) * inv * w[tid]       + b[tid]);
    rowbuf[tid + 256] = f2bf((v1 - mean) * inv * w[tid + 256] + b[tid + 256]);
    rowbuf[tid + 512] = f2bf((v2 - mean) * inv * w[tid + 512] + b[tid + 512]);
    __syncthreads();
    if (tid < 96) *(uint4*)&out[orow + (tid << 3)] = *(const uint4*)&rowbuf[tid << 3];
}

// ---- LN2 chunk: fp32 x1 rows -> bf16 (wide stores) -------------------------
__global__ __launch_bounds__(256) void ln2_chunk(
    const float* __restrict__ xin, const float* __restrict__ w, const float* __restrict__ b,
    u16* __restrict__ out)
{
    int row = blockIdx.x, tid = threadIdx.x;
    size_t base = (size_t)row * 768;
    __shared__ u16 rowbuf[768];
    float v0 = xin[base + tid], v1 = xin[base + tid + 256], v2 = xin[base + tid + 512];
    float s = v0 + v1 + v2, sq = v0 * v0 + v1 * v1 + v2 * v2;
    block_sum2(s, sq);
    float mean = s * (1.0f / 768.0f);
    float var  = sq * (1.0f / 768.0f) - mean * mean;
    float inv  = rsqrtf(var + 1e-5f);
    rowbuf[tid]       = f2bf((v0 - mean) * inv * w[tid]       + b[tid]);
    rowbuf[tid + 256] = f2bf((v1 - mean) * inv * w[tid + 256] + b[tid + 256]);
    rowbuf[tid + 512] = f2bf((v2 - mean) * inv * w[tid + 512] + b[tid + 512]);
    __syncthreads();
    if (tid < 96) *(uint4*)&out[base + (tid << 3)] = *(const uint4*)&rowbuf[tid << 3];
}

// ------------- weight transpose + cast: fp32 in[K][N] -> bf16 out[N][K] -----
__global__ __launch_bounds__(256) void transpose_wf(
    const float* __restrict__ in, u16* __restrict__ out, int K, int N)
{
    __shared__ u16 t[32][33];
    __shared__ u16 tt[32][32];   // row = n-local, 64B rows, 16B-aligned
    int n0 = blockIdx.x * 32, k0 = blockIdx.y * 32;
    int tx = threadIdx.x & 31, ty = threadIdx.x >> 5;
    for (int q = 0; q < 4; q++) {
        int k = k0 + ty + q * 8, n = n0 + tx;
        t[ty + q * 8][tx] = (k < K && n < N) ? f2bf(in[(size_t)k * N + n]) : (u16)0;
    }
    __syncthreads();
    for (int q = 0; q < 4; q++) tt[ty + q * 8][tx] = t[tx][ty + q * 8];
    __syncthreads();
    if (threadIdx.x < 128) {
        int r = threadIdx.x >> 2, c8 = (threadIdx.x & 3) << 3;
        int n = n0 + r, k = k0 + c8;
        if (n < N && k < K)
            *(uint4*)&out[(size_t)n * K + k] = *(const uint4*)&tt[r][c8];
    }
}

// --- rel tables -> bf16 combined matrix relT[64][64]: rows 0..26 = rel_h,
// rows 27..53 = rel_w, rows 54..63 = 0. B-operand of the MODE-6 G2 GEMM. ----
__global__ __launch_bounds__(256) void build_relT(
    const float* __restrict__ rh, const float* __restrict__ rw, u16* __restrict__ out)
{
    int i = blockIdx.x * 256 + threadIdx.x;   // 16 blocks x 256 = 4096
    int r = i >> 6, c = i & 63;
    float v = (r < 27) ? rh[r * 64 + c] : (r < 54 ? rw[(r - 27) * 64 + c] : 0.f);
    out[i] = f2bf(v);
}

// ------- build V^T per (local window, head): vt[z][d][m], m padded to 224 ---
__global__ __launch_bounds__(256) void build_vt(
    const u16* __restrict__ qkvc, u16* __restrict__ vt)
{
    int z = blockIdx.x;
    int wb = z / 12, h = z % 12;
    __shared__ u16 t[64][232];   // 464B rows: 16B-aligned for uint4 reads
    int tid = threadIdx.x;
    for (int base = 0; base < 196; base += 4) {
        int m = base + (tid >> 6);
        int d = tid & 63;
        t[d][m] = qkvc[(size_t)(wb * 196 + m) * 2304 + 1536 + h * 64 + d];
    }
    for (int idx = tid; idx < 28 * 64; idx += 256) {
        int m = 196 + idx / 64, d = idx % 64;
        t[d][m] = 0;
    }
    __syncthreads();
    size_t ob = (size_t)z * 64 * 224;
    for (int idx = tid; idx < 64 * 28; idx += 256) {
        int d = idx / 28, c8 = (idx % 28) << 3;
        *(uint4*)&vt[ob + (size_t)d * 224 + c8] = *(const uint4*)&t[d][c8];
    }
}

// ------------- softmax v2: barrier-free, wave-per-row, bias from G2 ---------
// grid (49, Wc*12). S: [z][196][224] bf16 in place; pad keys -> 0.
// bias(n,m) = G2[n][n/14 - m/14 + 13] + G2[n][27 + n%14 - m%14 + 13]
__global__ __launch_bounds__(256) void softmax_rel2(
    u16* __restrict__ S, const u16* __restrict__ G2)
{
    int z = blockIdx.y;
    int wv = threadIdx.x >> 6, lane = threadIdx.x & 63;
    int n = blockIdx.x * 4 + wv;                 // 49*4 = 196, all valid
    size_t srow = (size_t)z * 196 * 224 + (size_t)n * 224;
    const u16* g2 = G2 + (size_t)z * 196 * 64 + (size_t)n * 64;
    int qh = n / 14, qw = n % 14;
    float s[4];
    for (int c = 0; c < 4; c++) {
        int m = c * 64 + lane;
        if (m < 196) {
            int kk = m / 14, jj = m % 14;
            float bh = bf2f(g2[qh - kk + 13]);
            float bw = bf2f(g2[27 + qw - jj + 13]);
            s[c] = 0.125f * bf2f(S[srow + m]) + bh + bw;
        } else s[c] = -1e30f;
    }
    float mx = fmaxf(fmaxf(s[0], s[1]), fmaxf(s[2], s[3]));
    for (int o = 32; o > 0; o >>= 1) mx = fmaxf(mx, __shfl_xor(mx, o));
    float e[4], sm = 0.f;
    for (int c = 0; c < 4; c++) {
        int m = c * 64 + lane;
        e[c] = (m < 196) ? expf(s[c] - mx) : 0.f;
        sm += e[c];
    }
    for (int o = 32; o > 0; o >>= 1) sm += __shfl_xor(sm, o);
    float inv = 1.0f / sm;
    for (int c = 0; c < 4; c++) {
        int m = c * 64 + lane;
        if (m < 224) S[srow + m] = f2bf(e[c] * inv);
    }
}

// LDS slot swizzle on the READ side. gload_lds writes LDS linearly; the
// matching permutation is applied to the GLOBAL source column slot
// (slot ^ (row>>1)&3), so LDS[row][s] holds global slot s^xr and the
// reader fetches global slot q at LDS[row][q^xr] == swz_off(row, q*8).
__device__ __forceinline__ int swz_off(int row, int kcElem) {
    return row * 32 + (kcElem ^ (((row >> 1) & 3) << 3));
}

// ---------------- NT-mode MFMA bf16 GEMM, 128x128 tile, BK=32 ----------------
// Round-8-proven staging (gld_lds w16, both-sides slot swizzle, row clamps),
// now a COUNTED-VMCNT 3-BUFFER PIPELINE (T4; depth 2):
//   prologue: issue tiles 0,1 into bufs 0,1          (8 loads/wave in flight)
//   iter k:   s_waitcnt vmcnt(4)  — oldest 4 = tile k's loads (issued at
//             iter k-2, aged ~2 compute phases -> landed); tile k+1's 4
//             stay IN FLIGHT across the barrier (never drain to 0)
//             s_barrier (raw; uniform count per wave -> no divergence)
//             issue tile k+2 into buf (k+2)%3  [reads of that buf completed
//             in iter k-1: MFMA register deps force the lgkm wait before the
//             MFMAs, which precede this barrier in program order]
//             ds_read frags from buf k%3 + 16 MFMA
// sched_barrier(0) fences the inline-asm waits (rule #18).
// MODE 0: qkv = lnw @ qkvT^T + bias              (bf16 out Cb)
// MODE 1: S = q k^T per (window,head), blockIdx.z (bf16 out Cb, ld 224)
// MODE 2: PV: P @ Vt^T -> attn channel block     (bf16 out Cb)
// MODE 3: proj — scatter window-row -> global; Cf[g] = x_fp32[g]+acc+bias (fp32)
// MODE 4: fc1 + bias + exact gelu                (bf16 out Cb)
// MODE 5: fc2 — Cf[idx] = xf[idx]+acc+bias       (fp32 d_out RMW)
// MODE 6: G2 = q @ relT^T per (window,head)      (bf16 out Cb, ld 64)
template <int MODE>
__global__ __launch_bounds__(256, 3) void gemm_nt(
    const u16* __restrict__ Aall, const u16* __restrict__ Ball,
    const float* __restrict__ bias, const float* xf,
    u16* __restrict__ Cb, float* Cf, int M, int row0)
{
    constexpr int BK = 32;
    int N, K, lda, ldb;
    size_t aoff = 0, boff = 0, coff = 0;
    if constexpr (MODE == 0) { N = 2304; K = 768; lda = 768; ldb = 768; }
    else if constexpr (MODE == 1) {
        N = 196; K = 64; lda = 2304; ldb = 2304;
        int z = blockIdx.z;
        aoff = (size_t)(z / 12) * 196 * 2304 + (size_t)(z % 12) * 64;  // q
        boff = aoff + 768;                                             // k
        coff = (size_t)z * 196 * 224;
    } else if constexpr (MODE == 2) {
        N = 64; K = 224; lda = 224; ldb = 224;
        int z = blockIdx.z;
        aoff = (size_t)z * 196 * 224;                                  // P
        boff = (size_t)z * 64 * 224;                                   // V^T
        coff = (size_t)(z / 12) * 196 * 768 + (size_t)(z % 12) * 64;   // attn out
    } else if constexpr (MODE == 3) { N = 768; K = 768; lda = 768; ldb = 768; }
    else if constexpr (MODE == 4) { N = 3072; K = 768; lda = 768; ldb = 768; }
    else if constexpr (MODE == 6) {
        N = 64; K = 64; lda = 2304; ldb = 64;
        int z = blockIdx.z;
        aoff = (size_t)(z / 12) * 196 * 2304 + (size_t)(z % 12) * 64;  // q
        boff = 0;                                                      // relT
        coff = (size_t)z * 196 * 64;
    }
    else { N = 768; K = 3072; lda = 3072; ldb = 3072; }

    // 48 KB arena: 3 staging buffers x 8192 u16 (As | Bs at +4096).
    // Epilogue reuses [0, 8704 u16) as C staging.
    __shared__ __align__(16) u16 smem[24576];

    int tid = threadIdx.x, wid = tid >> 6, lane = tid & 63;
    int quad = lane >> 4, l16 = lane & 15;

    // XCD-aware bijective block swizzle (m204) for single-z modes.
    int bx = blockIdx.x, by = blockIdx.y;
    if constexpr (MODE != 1 && MODE != 2 && MODE != 6) {
        int gX = gridDim.x;
        int nwg = gX * gridDim.y;
        int orig = by * gX + bx;
        int q = nwg >> 3, r = nwg & 7;
        int xcd = orig & 7, idx = orig >> 3;
        int wg = (xcd < r ? xcd * (q + 1) : r * (q + 1) + (xcd - r) * q) + idx;
        bx = wg % gX; by = wg / gX;
    }
    int m_tile = by * 128, n_tile = bx * 128;
    int wm0 = (wid >> 1) * 64, wn0 = (wid & 1) * 64;

    const u16* A = Aall + aoff;
    const u16* B = Ball + boff;

    // staging: wave wid owns rows [wid*32, wid*32+32) of As and Bs.
    // 2 issues per operand; issue j: lane i -> lds row r0 + (i>>2), slot i&3.
    // global column slot pre-swizzled: (i&3) ^ ((row>>1)&3). rows clamped.
    const u16* gA[2]; const u16* gB[2];
    int loff[2];
    {
        int s = lane & 3, rofs = lane >> 2;
        for (int j = 0; j < 2; j++) {
            int r0 = wid * 32 + j * 16;
            int rr = r0 + rofs;
            int xr = (rr >> 1) & 3;
            int colo = ((s ^ xr) << 3);
            int am = m_tile + rr; if (am > M - 1) am = M - 1;
            int bn = n_tile + rr; if (bn > N - 1) bn = N - 1;
            gA[j] = A + (size_t)am * lda + colo;
            gB[j] = B + (size_t)bn * ldb + colo;
            loff[j] = r0 * 32;
        }
    }

    f32x4_t acc[4][4];
    f32x4_t z4 = {0.f, 0.f, 0.f, 0.f};
    for (int mt = 0; mt < 4; mt++)
        for (int nt = 0; nt < 4; nt++) acc[mt][nt] = z4;

    int nsteps = K / BK;   // >= 2 for all modes
    // prologue: tiles 0 and 1 into buffers 0 and 1 (8 loads/wave outstanding)
    for (int j = 0; j < 2; j++) {
        gld16(gA[j], smem + loff[j]);
        gld16(gB[j], smem + 4096 + loff[j]);
    }
    for (int j = 0; j < 2; j++) {
        gld16(gA[j] + BK, smem + 8192 + loff[j]);
        gld16(gB[j] + BK, smem + 12288 + loff[j]);
    }

    int cur = 0;
    for (int k = 0; k < nsteps; k++) {
        if (k + 1 < nsteps) {
            asm volatile("s_waitcnt vmcnt(4)" ::: "memory");
        } else {
            asm volatile("s_waitcnt vmcnt(0)" ::: "memory");
        }
        __builtin_amdgcn_sched_barrier(0);
        __builtin_amdgcn_s_barrier();
        __builtin_amdgcn_sched_barrier(0);
        if (k + 2 < nsteps) {
            int nb = cur + 2; if (nb >= 3) nb -= 3;
            u16* dst = smem + nb * 8192;
            int kn = (k + 2) * BK;
            for (int j = 0; j < 2; j++) {
                gld16(gA[j] + kn, dst + loff[j]);
                gld16(gB[j] + kn, dst + 4096 + loff[j]);
            }
        }
        const u16* Ac = smem + cur * 8192;
        const u16* Bc = Ac + 4096;
        bf16x8_t af[4], bfv[4];
        for (int t = 0; t < 4; t++) {
            int ar = wm0 + t * 16 + l16;
            int br = wn0 + t * 16 + l16;
            af[t]  = *(const bf16x8_t*)&Ac[swz_off(ar, quad * 8)];
            bfv[t] = *(const bf16x8_t*)&Bc[swz_off(br, quad * 8)];
        }
        for (int mt = 0; mt < 4; mt++)
            for (int nt = 0; nt < 4; nt++)
                acc[mt][nt] = __builtin_amdgcn_mfma_f32_16x16x32_bf16(
                    af[mt], bfv[nt], acc[mt][nt], 0, 0, 0);
        cur++; if (cur >= 3) cur -= 3;
    }

    // ---- epilogue (C/D frag layout: col=lane&15, row=quad*4+reg) ----
    if constexpr (MODE == 0 || MODE == 1 || MODE == 2 || MODE == 4 || MODE == 6) {
        u16* Cs = smem;   // [64][136] per half
        int ldc = (MODE == 0) ? 2304 : (MODE == 1) ? 224 : (MODE == 2) ? 768
                : (MODE == 6) ? 64 : 3072;
        int colmax = (MODE == 1) ? 224 : N;   // mode-1 pad cols overwritten later
        for (int half = 0; half < 2; half++) {
            __syncthreads();   // K-loop reads (or prev half) done
            if ((wm0 >> 6) == half) {
                for (int mt = 0; mt < 4; mt++) {
                    int rl = mt * 16 + quad * 4;
                    for (int nt = 0; nt < 4; nt++) {
                        int cl = wn0 + nt * 16 + l16;
                        int col = n_tile + cl;
                        for (int rg = 0; rg < 4; rg++) {
                            float v = acc[mt][nt][rg];
                            u16 o;
                            if constexpr (MODE == 0) o = f2bf(v + bias[col]);
                            else if constexpr (MODE == 4) {
                                float g = v + bias[col];
                                o = f2bf(0.5f * g * (1.0f + erff(g * 0.70710678118f)));
                            } else o = f2bf(v);
                            Cs[(rl + rg) * 136 + cl] = o;
                        }
                    }
                }
            }
            __syncthreads();
            for (int it = 0; it < 4; it++) {
                int chunk = tid + it * 256;
                int r = chunk >> 4, c8 = (chunk & 15) << 3;
                int grow = m_tile + half * 64 + r, gcol = n_tile + c8;
                if (grow >= M || gcol >= colmax) continue;
                *(uint4*)&Cb[coff + (size_t)grow * ldc + gcol] =
                    *(const uint4*)&Cs[r * 136 + c8];
            }
        }
    } else {
        // fp32 RMW modes (3, 5): four 32-row quarters through LDS
        float* Cfs = (float*)smem;   // [32][132]
        for (int q = 0; q < 4; q++) {
            __syncthreads();
            if ((wm0 >> 6) == (q >> 1)) {
                for (int mt2 = 0; mt2 < 2; mt2++) {
                    int mt = (q & 1) * 2 + mt2;
                    int rloc = mt2 * 16 + quad * 4;
                    for (int nt = 0; nt < 4; nt++) {
                        int cl = wn0 + nt * 16 + l16;
                        for (int rg = 0; rg < 4; rg++)
                            Cfs[(rloc + rg) * 132 + cl] = acc[mt][nt][rg];
                    }
                }
            }
            __syncthreads();
            for (int it = 0; it < 4; it++) {
                int chunk = tid + it * 256;
                int r = chunk >> 5, c4 = (chunk & 31) << 2;
                int grow = m_tile + q * 32 + r;
                int gcol = n_tile + c4;
                if (grow >= M || gcol >= N) continue;
                f32x4_t v4 = *(const f32x4_t*)&Cfs[r * 132 + c4];
                f32x4_t b4 = *(const f32x4_t*)&bias[gcol];
                if constexpr (MODE == 5) {
                    size_t idx = (size_t)(row0 + grow) * 768 + gcol;
                    f32x4_t x4 = *(const f32x4_t*)&xf[idx];
                    f32x4_t o4;
                    for (int j = 0; j < 4; j++) o4[j] = v4[j] + x4[j] + b4[j];
                    *(f32x4_t*)&Cf[idx] = o4;
                } else {
                    int wr = row0 + grow;
                    int wb2 = wr / 196, t2 = wr % 196;
                    int gh = ((wb2 % 25) / 5) * 14 + t2 / 14;
                    int gw = (wb2 % 5) * 14 + t2 % 14;
                    if (gh < 64 && gw < 64) {
                        size_t g = (size_t)(((wb2 / 25) * 64 + gh) * 64 + gw) * 768 + gcol;
                        f32x4_t x4 = *(const f32x4_t*)&xf[g];
                        f32x4_t o4;
                        for (int j = 0; j < 4; j++) o4[j] = v4[j] + x4[j] + b4[j];
                        *(f32x4_t*)&Cf[g] = o4;
                    }
                }
            }
        }
    }
}

extern "C" void kernel_launch(void* const* d_in, const int* in_sizes, int n_in,
                              void* d_out, int out_size, void* d_ws, size_t ws_size,
                              hipStream_t stream)
{
    (void)in_sizes; (void)n_in; (void)out_size;
    const float* x      = (const float*)d_in[0];
    const float* ln1_w  = (const float*)d_in[1];
    const float* ln1_b  = (const float*)d_in[2];
    const float* qkv_w  = (const float*)d_in[3];
    const float* qkv_b  = (const float*)d_in[4];
    const float* proj_w = (const float*)d_in[5];
    const float* proj_b = (const float*)d_in[6];
    const float* rel_h  = (const float*)d_in[7];
    const float* rel_w  = (const float*)d_in[8];
    const float* ln2_w  = (const float*)d_in[9];
    const float* ln2_b  = (const float*)d_in[10];
    const float* fc1_w  = (const float*)d_in[11];
    const float* fc1_b  = (const float*)d_in[12];
    const float* fc2_w  = (const float*)d_in[13];
    const float* fc2_b  = (const float*)d_in[14];

    // ---- ws layout: weights always at base, scratch above ----
    const size_t WT = 14155776ull + 8192ull;   // 13.5 MB weights + relT (8 KB)
    char* ws = (char*)d_ws;
    u16* qkvT  = (u16*)ws;
    u16* projT = qkvT + 2304 * 768;
    u16* fc1T  = projT + 768 * 768;
    u16* fc2T  = fc1T + 3072 * 768;
    u16* relT  = fc2T + 3072 * 768;            // [64][64] bf16
    char* scratch = ws + WT;
    size_t avail = (ws_size > WT) ? (ws_size - WT) : 0;

    // per-window: lnw 301056 + qkv 903168 + S 1053696 + vt 344064 + attn 301056
    //           + G2 301056  = 3204096
    const size_t perW = 3204096ull;
    static const int wc_cand[8] = {100, 50, 25, 20, 10, 5, 2, 1};
    int Wc = 1;
    for (int i = 0; i < 8; i++) {
        if ((size_t)wc_cand[i] * perW <= avail) { Wc = wc_cand[i]; break; }
    }
    static const int rm_cand[8] = {16384, 8192, 4096, 2048, 1024, 512, 256, 128};
    int Rm = 128;
    for (int i = 0; i < 8; i++) {
        if ((size_t)rm_cand[i] * 7680ull <= avail) { Rm = rm_cand[i]; break; }
    }

    u16* lnwc  = (u16*)scratch;
    u16* qkvc  = (u16*)(scratch + (size_t)Wc * 301056ull);
    u16* Sc    = (u16*)(scratch + (size_t)Wc * 1204224ull);
    u16* vtc   = (u16*)(scratch + (size_t)Wc * 2257920ull);
    u16* attnc = (u16*)(scratch + (size_t)Wc * 2601984ull);
    u16* G2c   = (u16*)(scratch + (size_t)Wc * 2903040ull);
    u16* hbuf  = (u16*)scratch;                               // MLP overlays
    u16* xn2c  = (u16*)(scratch + (size_t)Rm * 6144ull);
    float* dout = (float*)d_out;                              // x1 (fp32)

    transpose_wf<<<dim3(72, 24), 256, 0, stream>>>(qkv_w, qkvT, 768, 2304);
    transpose_wf<<<dim3(24, 24), 256, 0, stream>>>(proj_w, projT, 768, 768);
    transpose_wf<<<dim3(96, 24), 256, 0, stream>>>(fc1_w, fc1T, 768, 3072);
    transpose_wf<<<dim3(24, 96), 256, 0, stream>>>(fc2_w, fc2T, 3072, 768);
    build_relT<<<16, 256, 0, stream>>>(rel_h, rel_w, relT);

    int nch = 100 / Wc;
    int rows = Wc * 196;
    int gy = (rows + 127) / 128;
    for (int c = 0; c < nch; c++) {
        int r0 = c * rows;
        ln1_window<<<rows, 256, 0, stream>>>(x, ln1_w, ln1_b, lnwc, r0);
        gemm_nt<0><<<dim3(18, gy), 256, 0, stream>>>(
            lnwc, qkvT, qkv_b, nullptr, qkvc, nullptr, rows, 0);
        gemm_nt<1><<<dim3(2, 2, Wc * 12), 256, 0, stream>>>(
            qkvc, qkvc, nullptr, nullptr, Sc, nullptr, 196, 0);
        gemm_nt<6><<<dim3(1, 2, Wc * 12), 256, 0, stream>>>(
            qkvc, relT, nullptr, nullptr, G2c, nullptr, 196, 0);
        build_vt<<<Wc * 12, 256, 0, stream>>>(qkvc, vtc);
        softmax_rel2<<<dim3(49, Wc * 12), 256, 0, stream>>>(Sc, G2c);
        gemm_nt<2><<<dim3(1, 2, Wc * 12), 256, 0, stream>>>(
            Sc, vtc, nullptr, nullptr, attnc, nullptr, 196, 0);
        gemm_nt<3><<<dim3(6, gy), 256, 0, stream>>>(
            attnc, projT, proj_b, x, nullptr, dout, rows, r0);
    }

    int nm = 16384 / Rm;
    for (int c = 0; c < nm; c++) {
        int r0 = c * Rm;
        ln2_chunk<<<Rm, 256, 0, stream>>>(dout + (size_t)r0 * 768, ln2_w, ln2_b, xn2c);
        gemm_nt<4><<<dim3(24, Rm / 128), 256, 0, stream>>>(
            xn2c, fc1T, fc1_b, nullptr, hbuf, nullptr, Rm, 0);
        gemm_nt<5><<<dim3(6, Rm / 128), 256, 0, stream>>>(
            hbuf, fc2T, fc2_b, dout, nullptr, dout, Rm, r0);
    }
}

// Round 10
// 714.959 us; speedup vs baseline: 4.5889x; 1.0536x over previous
//
#include <hip/hip_runtime.h>

typedef unsigned short u16;
typedef __bf16 bf16x8_t __attribute__((ext_vector_type(8)));
typedef float f32x4_t __attribute__((ext_vector_type(4)));

__device__ __forceinline__ float bf2f(u16 u) {
    union { unsigned u; float f; } c; c.u = ((unsigned)u) << 16; return c.f;
}
__device__ __forceinline__ u16 f2bf(float f) {
    union { float f; unsigned u; } c; c.f = f;
    unsigned u = c.u;
    unsigned r = (u + 0x7FFFu + ((u >> 16) & 1u)) >> 16;
    return (u16)r;
}

// async global->LDS, 16B per lane. LDS dest is wave-uniform base + lane*16.
__device__ __forceinline__ void gld16(const u16* g, u16* l) {
    __builtin_amdgcn_global_load_lds(
        (const __attribute__((address_space(1))) unsigned*)g,
        (__attribute__((address_space(3))) unsigned*)l, 16, 0, 0);
}

// ---- LN1 + window partition: wave-per-row (barrier-free), 4 rows/block -----
// grid rows/4. Lane handles 4 consecutive floats in each of 3 segments.
__global__ __launch_bounds__(256) void ln1_window(
    const float* __restrict__ x, const float* __restrict__ w, const float* __restrict__ b,
    u16* __restrict__ out, int row0)
{
    int wv = threadIdx.x >> 6, lane = threadIdx.x & 63;
    int lrow = blockIdx.x * 4 + wv;
    int wr = row0 + lrow;
    int wb = wr / 196, t = wr % 196;
    int gh = ((wb % 25) / 5) * 14 + t / 14;
    int gw = (wb % 5) * 14 + t % 14;
    size_t orow = (size_t)lrow * 768;
    if (gh >= 64 || gw >= 64) {
        uint2 zz; zz.x = 0u; zz.y = 0u;
        for (int seg = 0; seg < 3; seg++)
            *(uint2*)&out[orow + seg * 256 + lane * 4] = zz;
        return;
    }
    size_t base = (size_t)(((wb / 25) * 64 + gh) * 64 + gw) * 768;
    f32x4_t v[3];
    float s = 0.f, sq = 0.f;
    for (int seg = 0; seg < 3; seg++) {
        v[seg] = *(const f32x4_t*)&x[base + seg * 256 + lane * 4];
        for (int j = 0; j < 4; j++) { s += v[seg][j]; sq += v[seg][j] * v[seg][j]; }
    }
    for (int o = 32; o > 0; o >>= 1) { s += __shfl_xor(s, o); sq += __shfl_xor(sq, o); }
    float mean = s * (1.0f / 768.0f);
    float var  = sq * (1.0f / 768.0f) - mean * mean;
    float inv  = rsqrtf(var + 1e-5f);
    for (int seg = 0; seg < 3; seg++) {
        f32x4_t w4 = *(const f32x4_t*)&w[seg * 256 + lane * 4];
        f32x4_t b4 = *(const f32x4_t*)&b[seg * 256 + lane * 4];
        u16 o0 = f2bf((v[seg][0] - mean) * inv * w4[0] + b4[0]);
        u16 o1 = f2bf((v[seg][1] - mean) * inv * w4[1] + b4[1]);
        u16 o2 = f2bf((v[seg][2] - mean) * inv * w4[2] + b4[2]);
        u16 o3 = f2bf((v[seg][3] - mean) * inv * w4[3] + b4[3]);
        uint2 pv; pv.x = (unsigned)o0 | ((unsigned)o1 << 16);
        pv.y = (unsigned)o2 | ((unsigned)o3 << 16);
        *(uint2*)&out[orow + seg * 256 + lane * 4] = pv;
    }
}

// ---- LN2: wave-per-row (barrier-free), 4 rows/block. grid Rm/4 -------------
__global__ __launch_bounds__(256) void ln2_chunk(
    const float* __restrict__ xin, const float* __restrict__ w, const float* __restrict__ b,
    u16* __restrict__ out)
{
    int wv = threadIdx.x >> 6, lane = threadIdx.x & 63;
    int row = blockIdx.x * 4 + wv;
    size_t base = (size_t)row * 768;
    f32x4_t v[3];
    float s = 0.f, sq = 0.f;
    for (int seg = 0; seg < 3; seg++) {
        v[seg] = *(const f32x4_t*)&xin[base + seg * 256 + lane * 4];
        for (int j = 0; j < 4; j++) { s += v[seg][j]; sq += v[seg][j] * v[seg][j]; }
    }
    for (int o = 32; o > 0; o >>= 1) { s += __shfl_xor(s, o); sq += __shfl_xor(sq, o); }
    float mean = s * (1.0f / 768.0f);
    float var  = sq * (1.0f / 768.0f) - mean * mean;
    float inv  = rsqrtf(var + 1e-5f);
    for (int seg = 0; seg < 3; seg++) {
        f32x4_t w4 = *(const f32x4_t*)&w[seg * 256 + lane * 4];
        f32x4_t b4 = *(const f32x4_t*)&b[seg * 256 + lane * 4];
        u16 o0 = f2bf((v[seg][0] - mean) * inv * w4[0] + b4[0]);
        u16 o1 = f2bf((v[seg][1] - mean) * inv * w4[1] + b4[1]);
        u16 o2 = f2bf((v[seg][2] - mean) * inv * w4[2] + b4[2]);
        u16 o3 = f2bf((v[seg][3] - mean) * inv * w4[3] + b4[3]);
        uint2 pv; pv.x = (unsigned)o0 | ((unsigned)o1 << 16);
        pv.y = (unsigned)o2 | ((unsigned)o3 << 16);
        *(uint2*)&out[base + seg * 256 + lane * 4] = pv;
    }
}

// ------------- weight transpose + cast: fp32 in[K][N] -> bf16 out[N][K] -----
__global__ __launch_bounds__(256) void transpose_wf(
    const float* __restrict__ in, u16* __restrict__ out, int K, int N)
{
    __shared__ u16 t[32][33];
    __shared__ u16 tt[32][32];   // row = n-local, 64B rows, 16B-aligned
    int n0 = blockIdx.x * 32, k0 = blockIdx.y * 32;
    int tx = threadIdx.x & 31, ty = threadIdx.x >> 5;
    for (int q = 0; q < 4; q++) {
        int k = k0 + ty + q * 8, n = n0 + tx;
        t[ty + q * 8][tx] = (k < K && n < N) ? f2bf(in[(size_t)k * N + n]) : (u16)0;
    }
    __syncthreads();
    for (int q = 0; q < 4; q++) tt[ty + q * 8][tx] = t[tx][ty + q * 8];
    __syncthreads();
    if (threadIdx.x < 128) {
        int r = threadIdx.x >> 2, c8 = (threadIdx.x & 3) << 3;
        int n = n0 + r, k = k0 + c8;
        if (n < N && k < K)
            *(uint4*)&out[(size_t)n * K + k] = *(const uint4*)&tt[r][c8];
    }
}

// --- rel tables -> bf16 combined matrix relT[64][64]: rows 0..26 = rel_h,
// rows 27..53 = rel_w, rows 54..63 = 0. B-operand of the MODE-6 G2 GEMM. ----
__global__ __launch_bounds__(256) void build_relT(
    const float* __restrict__ rh, const float* __restrict__ rw, u16* __restrict__ out)
{
    int i = blockIdx.x * 256 + threadIdx.x;   // 16 blocks x 256 = 4096
    int r = i >> 6, c = i & 63;
    float v = (r < 27) ? rh[r * 64 + c] : (r < 54 ? rw[(r - 27) * 64 + c] : 0.f);
    out[i] = f2bf(v);
}

// ------- build V^T per (local window, head): vt[z][d][m], m padded to 224 ---
__global__ __launch_bounds__(256) void build_vt(
    const u16* __restrict__ qkvc, u16* __restrict__ vt)
{
    int z = blockIdx.x;
    int wb = z / 12, h = z % 12;
    __shared__ u16 t[64][232];   // 464B rows: 16B-aligned for uint4 reads
    int tid = threadIdx.x;
    for (int base = 0; base < 196; base += 4) {
        int m = base + (tid >> 6);
        int d = tid & 63;
        t[d][m] = qkvc[(size_t)(wb * 196 + m) * 2304 + 1536 + h * 64 + d];
    }
    for (int idx = tid; idx < 28 * 64; idx += 256) {
        int m = 196 + idx / 64, d = idx % 64;
        t[d][m] = 0;
    }
    __syncthreads();
    size_t ob = (size_t)z * 64 * 224;
    for (int idx = tid; idx < 64 * 28; idx += 256) {
        int d = idx / 28, c8 = (idx % 28) << 3;
        *(uint4*)&vt[ob + (size_t)d * 224 + c8] = *(const uint4*)&t[d][c8];
    }
}

// ------------- softmax v3: barrier-free, wave-per-row, 28 rows/block --------
// grid (7, Wc*12). S: [z][196][224] bf16 in place; pad keys -> 0.
// bias(n,m) = G2[n][n/14 - m/14 + 13] + G2[n][27 + n%14 - m%14 + 13]
__global__ __launch_bounds__(256) void softmax_rel2(
    u16* __restrict__ S, const u16* __restrict__ G2)
{
    int z = blockIdx.y;
    int wv = threadIdx.x >> 6, lane = threadIdx.x & 63;
    int nbase = blockIdx.x * 28 + wv * 7;        // 7*28 = 196, all valid
    for (int i = 0; i < 7; i++) {
        int n = nbase + i;
        size_t srow = (size_t)z * 196 * 224 + (size_t)n * 224;
        const u16* g2 = G2 + (size_t)z * 196 * 64 + (size_t)n * 64;
        int qh = n / 14, qw = n % 14;
        float s[4];
        for (int c = 0; c < 4; c++) {
            int m = c * 64 + lane;
            if (m < 196) {
                int kk = m / 14, jj = m % 14;
                float bh = bf2f(g2[qh - kk + 13]);
                float bw = bf2f(g2[27 + qw - jj + 13]);
                s[c] = 0.125f * bf2f(S[srow + m]) + bh + bw;
            } else s[c] = -1e30f;
        }
        float mx = fmaxf(fmaxf(s[0], s[1]), fmaxf(s[2], s[3]));
        for (int o = 32; o > 0; o >>= 1) mx = fmaxf(mx, __shfl_xor(mx, o));
        float e[4], sm = 0.f;
        for (int c = 0; c < 4; c++) {
            int m = c * 64 + lane;
            e[c] = (m < 196) ? expf(s[c] - mx) : 0.f;
            sm += e[c];
        }
        for (int o = 32; o > 0; o >>= 1) sm += __shfl_xor(sm, o);
        float inv = 1.0f / sm;
        for (int c = 0; c < 4; c++) {
            int m = c * 64 + lane;
            if (m < 224) S[srow + m] = f2bf(e[c] * inv);
        }
    }
}

// LDS slot swizzle on the READ side. gload_lds writes LDS linearly; the
// matching permutation is applied to the GLOBAL source column slot
// (slot ^ (row>>1)&3), so LDS[row][s] holds global slot s^xr and the
// reader fetches global slot q at LDS[row][q^xr] == swz_off(row, q*8).
__device__ __forceinline__ int swz_off(int row, int kcElem) {
    return row * 32 + (kcElem ^ (((row >> 1) & 3) << 3));
}

// ---------------- NT-mode MFMA bf16 GEMM, 128x128 tile, BK=32 ----------------
// Mode-specialized K-loop (both variants hardware-proven r8/r9):
//  LONG-K modes (0,3,4,5): 2-buffer + __syncthreads, 32 KB LDS, 4 blocks/CU.
//    (r8: fc1 130 us. The 3-buffer pipeline REGRESSED these: occupancy loss
//     4->3 blocks beat the pipeline gain — r9 measured 169 us.)
//  SHORT-K modes (1,2,6; 2-7 K-steps): 3-buffer counted-vmcnt depth-2
//    pipeline, 48 KB LDS, 3 blocks/CU. (r9 measured ~40 us total gain on
//    these latency-dominated dispatches.)
// MODE 0: qkv = lnw @ qkvT^T + bias              (bf16 out Cb)
// MODE 1: S = q k^T per (window,head), blockIdx.z (bf16 out Cb, ld 224)
// MODE 2: PV: P @ Vt^T -> attn channel block     (bf16 out Cb)
// MODE 3: proj — scatter window-row -> global; Cf[g] = x_fp32[g]+acc+bias (fp32)
// MODE 4: fc1 + bias + exact gelu                (bf16 out Cb)
// MODE 5: fc2 — Cf[idx] = xf[idx]+acc+bias       (fp32 d_out RMW)
// MODE 6: G2 = q @ relT^T per (window,head)      (bf16 out Cb, ld 64)
template <int MODE>
__global__ __launch_bounds__(256, (MODE == 1 || MODE == 2 || MODE == 6) ? 3 : 4)
void gemm_nt(
    const u16* __restrict__ Aall, const u16* __restrict__ Ball,
    const float* __restrict__ bias, const float* xf,
    u16* __restrict__ Cb, float* Cf, int M, int row0)
{
    constexpr int BK = 32;
    constexpr bool DEEP = (MODE == 1 || MODE == 2 || MODE == 6);
    int N, K, lda, ldb;
    size_t aoff = 0, boff = 0, coff = 0;
    if constexpr (MODE == 0) { N = 2304; K = 768; lda = 768; ldb = 768; }
    else if constexpr (MODE == 1) {
        N = 196; K = 64; lda = 2304; ldb = 2304;
        int z = blockIdx.z;
        aoff = (size_t)(z / 12) * 196 * 2304 + (size_t)(z % 12) * 64;  // q
        boff = aoff + 768;                                             // k
        coff = (size_t)z * 196 * 224;
    } else if constexpr (MODE == 2) {
        N = 64; K = 224; lda = 224; ldb = 224;
        int z = blockIdx.z;
        aoff = (size_t)z * 196 * 224;                                  // P
        boff = (size_t)z * 64 * 224;                                   // V^T
        coff = (size_t)(z / 12) * 196 * 768 + (size_t)(z % 12) * 64;   // attn out
    } else if constexpr (MODE == 3) { N = 768; K = 768; lda = 768; ldb = 768; }
    else if constexpr (MODE == 4) { N = 3072; K = 768; lda = 768; ldb = 768; }
    else if constexpr (MODE == 6) {
        N = 64; K = 64; lda = 2304; ldb = 64;
        int z = blockIdx.z;
        aoff = (size_t)(z / 12) * 196 * 2304 + (size_t)(z % 12) * 64;  // q
        boff = 0;                                                      // relT
        coff = (size_t)z * 196 * 64;
    }
    else { N = 768; K = 3072; lda = 3072; ldb = 3072; }

    // Staging buffers of 8192 u16 (As | Bs at +4096) each; epilogue reuses
    // [0, 8704 u16) as C staging.
    constexpr int NBUF = DEEP ? 3 : 2;
    __shared__ __align__(16) u16 smem[NBUF * 8192];

    int tid = threadIdx.x, wid = tid >> 6, lane = tid & 63;
    int quad = lane >> 4, l16 = lane & 15;

    // XCD-aware bijective block swizzle (m204) for single-z modes.
    int bx = blockIdx.x, by = blockIdx.y;
    if constexpr (MODE != 1 && MODE != 2 && MODE != 6) {
        int gX = gridDim.x;
        int nwg = gX * gridDim.y;
        int orig = by * gX + bx;
        int q = nwg >> 3, r = nwg & 7;
        int xcd = orig & 7, idx = orig >> 3;
        int wg = (xcd < r ? xcd * (q + 1) : r * (q + 1) + (xcd - r) * q) + idx;
        bx = wg % gX; by = wg / gX;
    }
    int m_tile = by * 128, n_tile = bx * 128;
    int wm0 = (wid >> 1) * 64, wn0 = (wid & 1) * 64;

    const u16* A = Aall + aoff;
    const u16* B = Ball + boff;

    // staging: wave wid owns rows [wid*32, wid*32+32) of As and Bs.
    // 2 issues per operand; issue j: lane i -> lds row r0 + (i>>2), slot i&3.
    // global column slot pre-swizzled: (i&3) ^ ((row>>1)&3). rows clamped.
    const u16* gA[2]; const u16* gB[2];
    int loff[2];
    {
        int s = lane & 3, rofs = lane >> 2;
        for (int j = 0; j < 2; j++) {
            int r0 = wid * 32 + j * 16;
            int rr = r0 + rofs;
            int xr = (rr >> 1) & 3;
            int colo = ((s ^ xr) << 3);
            int am = m_tile + rr; if (am > M - 1) am = M - 1;
            int bn = n_tile + rr; if (bn > N - 1) bn = N - 1;
            gA[j] = A + (size_t)am * lda + colo;
            gB[j] = B + (size_t)bn * ldb + colo;
            loff[j] = r0 * 32;
        }
    }

    f32x4_t acc[4][4];
    f32x4_t z4 = {0.f, 0.f, 0.f, 0.f};
    for (int mt = 0; mt < 4; mt++)
        for (int nt = 0; nt < 4; nt++) acc[mt][nt] = z4;

    if constexpr (!DEEP) {
        // --- r8-proven: 2-buffer, one __syncthreads per K-step ---
        for (int j = 0; j < 2; j++) {
            gld16(gA[j], smem + loff[j]);
            gld16(gB[j], smem + 4096 + loff[j]);
        }
        int cur = 0;
        for (int k0 = 0; k0 < K; k0 += BK) {
            __syncthreads();   // drains tile-k loads; waves done reading buf^1
            int boffc = cur << 13;
            if (k0 + BK < K) {
                int boffn = boffc ^ 8192;
                for (int j = 0; j < 2; j++) {
                    gld16(gA[j] + k0 + BK, smem + boffn + loff[j]);
                    gld16(gB[j] + k0 + BK, smem + boffn + 4096 + loff[j]);
                }
            }
            const u16* Ac = smem + boffc;
            const u16* Bc = smem + boffc + 4096;
            bf16x8_t af[4], bfv[4];
            for (int t = 0; t < 4; t++) {
                int ar = wm0 + t * 16 + l16;
                int br = wn0 + t * 16 + l16;
                af[t]  = *(const bf16x8_t*)&Ac[swz_off(ar, quad * 8)];
                bfv[t] = *(const bf16x8_t*)&Bc[swz_off(br, quad * 8)];
            }
            for (int mt = 0; mt < 4; mt++)
                for (int nt = 0; nt < 4; nt++)
                    acc[mt][nt] = __builtin_amdgcn_mfma_f32_16x16x32_bf16(
                        af[mt], bfv[nt], acc[mt][nt], 0, 0, 0);
            cur ^= 1;
        }
    } else {
        // --- r9-proven: 3-buffer counted-vmcnt depth-2 pipeline ---
        int nsteps = K / BK;   // 2..7 for DEEP modes
        for (int j = 0; j < 2; j++) {
            gld16(gA[j], smem + loff[j]);
            gld16(gB[j], smem + 4096 + loff[j]);
        }
        for (int j = 0; j < 2; j++) {
            gld16(gA[j] + BK, smem + 8192 + loff[j]);
            gld16(gB[j] + BK, smem + 12288 + loff[j]);
        }
        int cur = 0;
        for (int k = 0; k < nsteps; k++) {
            if (k + 1 < nsteps) {
                asm volatile("s_waitcnt vmcnt(4)" ::: "memory");
            } else {
                asm volatile("s_waitcnt vmcnt(0)" ::: "memory");
            }
            __builtin_amdgcn_sched_barrier(0);
            __builtin_amdgcn_s_barrier();
            __builtin_amdgcn_sched_barrier(0);
            if (k + 2 < nsteps) {
                int nb = cur + 2; if (nb >= 3) nb -= 3;
                u16* dst = smem + nb * 8192;
                int kn = (k + 2) * BK;
                for (int j = 0; j < 2; j++) {
                    gld16(gA[j] + kn, dst + loff[j]);
                    gld16(gB[j] + kn, dst + 4096 + loff[j]);
                }
            }
            const u16* Ac = smem + cur * 8192;
            const u16* Bc = Ac + 4096;
            bf16x8_t af[4], bfv[4];
            for (int t = 0; t < 4; t++) {
                int ar = wm0 + t * 16 + l16;
                int br = wn0 + t * 16 + l16;
                af[t]  = *(const bf16x8_t*)&Ac[swz_off(ar, quad * 8)];
                bfv[t] = *(const bf16x8_t*)&Bc[swz_off(br, quad * 8)];
            }
            for (int mt = 0; mt < 4; mt++)
                for (int nt = 0; nt < 4; nt++)
                    acc[mt][nt] = __builtin_amdgcn_mfma_f32_16x16x32_bf16(
                        af[mt], bfv[nt], acc[mt][nt], 0, 0, 0);
            cur++; if (cur >= 3) cur -= 3;
        }
    }

    // ---- epilogue (C/D frag layout: col=lane&15, row=quad*4+reg) ----
    if constexpr (MODE == 0 || MODE == 1 || MODE == 2 || MODE == 4 || MODE == 6) {
        u16* Cs = smem;   // [64][136] per half
        int ldc = (MODE == 0) ? 2304 : (MODE == 1) ? 224 : (MODE == 2) ? 768
                : (MODE == 6) ? 64 : 3072;
        int colmax = (MODE == 1) ? 224 : N;   // mode-1 pad cols overwritten later
        for (int half = 0; half < 2; half++) {
            __syncthreads();   // K-loop reads (or prev half) done
            if ((wm0 >> 6) == half) {
                for (int mt = 0; mt < 4; mt++) {
                    int rl = mt * 16 + quad * 4;
                    for (int nt = 0; nt < 4; nt++) {
                        int cl = wn0 + nt * 16 + l16;
                        int col = n_tile + cl;
                        for (int rg = 0; rg < 4; rg++) {
                            float v = acc[mt][nt][rg];
                            u16 o;
                            if constexpr (MODE == 0) o = f2bf(v + bias[col]);
                            else if constexpr (MODE == 4) {
                                float g = v + bias[col];
                                o = f2bf(0.5f * g * (1.0f + erff(g * 0.70710678118f)));
                            } else o = f2bf(v);
                            Cs[(rl + rg) * 136 + cl] = o;
                        }
                    }
                }
            }
            __syncthreads();
            for (int it = 0; it < 4; it++) {
                int chunk = tid + it * 256;
                int r = chunk >> 4, c8 = (chunk & 15) << 3;
                int grow = m_tile + half * 64 + r, gcol = n_tile + c8;
                if (grow >= M || gcol >= colmax) continue;
                *(uint4*)&Cb[coff + (size_t)grow * ldc + gcol] =
                    *(const uint4*)&Cs[r * 136 + c8];
            }
        }
    } else {
        // fp32 RMW modes (3, 5): four 32-row quarters through LDS
        float* Cfs = (float*)smem;   // [32][132]
        for (int q = 0; q < 4; q++) {
            __syncthreads();
            if ((wm0 >> 6) == (q >> 1)) {
                for (int mt2 = 0; mt2 < 2; mt2++) {
                    int mt = (q & 1) * 2 + mt2;
                    int rloc = mt2 * 16 + quad * 4;
                    for (int nt = 0; nt < 4; nt++) {
                        int cl = wn0 + nt * 16 + l16;
                        for (int rg = 0; rg < 4; rg++)
                            Cfs[(rloc + rg) * 132 + cl] = acc[mt][nt][rg];
                    }
                }
            }
            __syncthreads();
            for (int it = 0; it < 4; it++) {
                int chunk = tid + it * 256;
                int r = chunk >> 5, c4 = (chunk & 31) << 2;
                int grow = m_tile + q * 32 + r;
                int gcol = n_tile + c4;
                if (grow >= M || gcol >= N) continue;
                f32x4_t v4 = *(const f32x4_t*)&Cfs[r * 132 + c4];
                f32x4_t b4 = *(const f32x4_t*)&bias[gcol];
                if constexpr (MODE == 5) {
                    size_t idx = (size_t)(row0 + grow) * 768 + gcol;
                    f32x4_t x4 = *(const f32x4_t*)&xf[idx];
                    f32x4_t o4;
                    for (int j = 0; j < 4; j++) o4[j] = v4[j] + x4[j] + b4[j];
                    *(f32x4_t*)&Cf[idx] = o4;
                } else {
                    int wr = row0 + grow;
                    int wb2 = wr / 196, t2 = wr % 196;
                    int gh = ((wb2 % 25) / 5) * 14 + t2 / 14;
                    int gw = (wb2 % 5) * 14 + t2 % 14;
                    if (gh < 64 && gw < 64) {
                        size_t g = (size_t)(((wb2 / 25) * 64 + gh) * 64 + gw) * 768 + gcol;
                        f32x4_t x4 = *(const f32x4_t*)&xf[g];
                        f32x4_t o4;
                        for (int j = 0; j < 4; j++) o4[j] = v4[j] + x4[j] + b4[j];
                        *(f32x4_t*)&Cf[g] = o4;
                    }
                }
            }
        }
    }
}

extern "C" void kernel_launch(void* const* d_in, const int* in_sizes, int n_in,
                              void* d_out, int out_size, void* d_ws, size_t ws_size,
                              hipStream_t stream)
{
    (void)in_sizes; (void)n_in; (void)out_size;
    const float* x      = (const float*)d_in[0];
    const float* ln1_w  = (const float*)d_in[1];
    const float* ln1_b  = (const float*)d_in[2];
    const float* qkv_w  = (const float*)d_in[3];
    const float* qkv_b  = (const float*)d_in[4];
    const float* proj_w = (const float*)d_in[5];
    const float* proj_b = (const float*)d_in[6];
    const float* rel_h  = (const float*)d_in[7];
    const float* rel_w  = (const float*)d_in[8];
    const float* ln2_w  = (const float*)d_in[9];
    const float* ln2_b  = (const float*)d_in[10];
    const float* fc1_w  = (const float*)d_in[11];
    const float* fc1_b  = (const float*)d_in[12];
    const float* fc2_w  = (const float*)d_in[13];
    const float* fc2_b  = (const float*)d_in[14];

    // ---- ws layout: weights always at base, scratch above ----
    const size_t WT = 14155776ull + 8192ull;   // 13.5 MB weights + relT (8 KB)
    char* ws = (char*)d_ws;
    u16* qkvT  = (u16*)ws;
    u16* projT = qkvT + 2304 * 768;
    u16* fc1T  = projT + 768 * 768;
    u16* fc2T  = fc1T + 3072 * 768;
    u16* relT  = fc2T + 3072 * 768;            // [64][64] bf16
    char* scratch = ws + WT;
    size_t avail = (ws_size > WT) ? (ws_size - WT) : 0;

    // per-window: lnw 301056 + qkv 903168 + S 1053696 + vt 344064 + attn 301056
    //           + G2 301056  = 3204096
    const size_t perW = 3204096ull;
    static const int wc_cand[8] = {100, 50, 25, 20, 10, 5, 2, 1};
    int Wc = 1;
    for (int i = 0; i < 8; i++) {
        if ((size_t)wc_cand[i] * perW <= avail) { Wc = wc_cand[i]; break; }
    }
    static const int rm_cand[8] = {16384, 8192, 4096, 2048, 1024, 512, 256, 128};
    int Rm = 128;
    for (int i = 0; i < 8; i++) {
        if ((size_t)rm_cand[i] * 7680ull <= avail) { Rm = rm_cand[i]; break; }
    }

    u16* lnwc  = (u16*)scratch;
    u16* qkvc  = (u16*)(scratch + (size_t)Wc * 301056ull);
    u16* Sc    = (u16*)(scratch + (size_t)Wc * 1204224ull);
    u16* vtc   = (u16*)(scratch + (size_t)Wc * 2257920ull);
    u16* attnc = (u16*)(scratch + (size_t)Wc * 2601984ull);
    u16* G2c   = (u16*)(scratch + (size_t)Wc * 2903040ull);
    u16* hbuf  = (u16*)scratch;                               // MLP overlays
    u16* xn2c  = (u16*)(scratch + (size_t)Rm * 6144ull);
    float* dout = (float*)d_out;                              // x1 (fp32)

    transpose_wf<<<dim3(72, 24), 256, 0, stream>>>(qkv_w, qkvT, 768, 2304);
    transpose_wf<<<dim3(24, 24), 256, 0, stream>>>(proj_w, projT, 768, 768);
    transpose_wf<<<dim3(96, 24), 256, 0, stream>>>(fc1_w, fc1T, 768, 3072);
    transpose_wf<<<dim3(24, 96), 256, 0, stream>>>(fc2_w, fc2T, 3072, 768);
    build_relT<<<16, 256, 0, stream>>>(rel_h, rel_w, relT);

    int nch = 100 / Wc;
    int rows = Wc * 196;
    int gy = (rows + 127) / 128;
    for (int c = 0; c < nch; c++) {
        int r0 = c * rows;
        ln1_window<<<rows / 4, 256, 0, stream>>>(x, ln1_w, ln1_b, lnwc, r0);
        gemm_nt<0><<<dim3(18, gy), 256, 0, stream>>>(
            lnwc, qkvT, qkv_b, nullptr, qkvc, nullptr, rows, 0);
        gemm_nt<1><<<dim3(2, 2, Wc * 12), 256, 0, stream>>>(
            qkvc, qkvc, nullptr, nullptr, Sc, nullptr, 196, 0);
        gemm_nt<6><<<dim3(1, 2, Wc * 12), 256, 0, stream>>>(
            qkvc, relT, nullptr, nullptr, G2c, nullptr, 196, 0);
        build_vt<<<Wc * 12, 256, 0, stream>>>(qkvc, vtc);
        softmax_rel2<<<dim3(7, Wc * 12), 256, 0, stream>>>(Sc, G2c);
        gemm_nt<2><<<dim3(1, 2, Wc * 12), 256, 0, stream>>>(
            Sc, vtc, nullptr, nullptr, attnc, nullptr, 196, 0);
        gemm_nt<3><<<dim3(6, gy), 256, 0, stream>>>(
            attnc, projT, proj_b, x, nullptr, dout, rows, r0);
    }

    int nm = 16384 / Rm;
    for (int c = 0; c < nm; c++) {
        int r0 = c * Rm;
        ln2_chunk<<<Rm / 4, 256, 0, stream>>>(dout + (size_t)r0 * 768, ln2_w, ln2_b, xn2c);
        gemm_nt<4><<<dim3(24, Rm / 128), 256, 0, stream>>>(
            xn2c, fc1T, fc1_b, nullptr, hbuf, nullptr, Rm, 0);
        gemm_nt<5><<<dim3(6, Rm / 128), 256, 0, stream>>>(
            hbuf, fc2T, fc2_b, dout, nullptr, dout, Rm, r0);
    }
}